// Round 2
// baseline (2770.878 us; speedup 1.0000x reference)
//
#include <hip/hip_runtime.h>
#include <hip/hip_bf16.h>

#define BN 4
#define DIM 64
#define NHEADS 8
#define HH 256
#define WH 256
#define NP (HH*WH)      // 65536
#define HF 512
#define WF 512

// ---------------- DWT ----------------
__global__ __launch_bounds__(256) void k_dwt(const float* __restrict__ x,
                                             float* __restrict__ LL, float* __restrict__ LH,
                                             float* __restrict__ HL, float* __restrict__ HHo) {
    int idx = blockIdx.x * 256 + threadIdx.x;          // over BN*DIM*NP
    int j = idx & (WH - 1);
    int i = (idx >> 8) & (HH - 1);
    int bc = idx >> 16;
    const float2* row0 = (const float2*)(x + (size_t)bc * HF * WF + (size_t)(2 * i) * WF);
    const float2* row1 = (const float2*)(x + (size_t)bc * HF * WF + (size_t)(2 * i + 1) * WF);
    float2 e = row0[j];
    float2 o = row1[j];
    float a = e.x, b = e.y, c = o.x, d = o.y;
    LL[idx]  = ( a + b + c + d) * 0.5f;
    LH[idx]  = (-a - b + c + d) * 0.5f;
    HL[idx]  = (-a + b - c + d) * 0.5f;
    HHo[idx] = ( a - b - c + d) * 0.5f;
}

// ---------------- grouped 3x3 conv (+relu), direct, 64 in-ch per group ----------------
// grid.x = 256 spatial tiles (16x16 of 16x16 px), grid.y = OC/16 (g = octile/4), grid.z = BN
__global__ __launch_bounds__(256) void k_gconv3x3(const float* __restrict__ s0,
                                                  const float* __restrict__ s1,
                                                  const float* __restrict__ s2,
                                                  const float* __restrict__ w,
                                                  float* __restrict__ out, int OC) {
    __shared__ float tile[18 * 18];
    int tid = threadIdx.x;
    int tx = tid & 15, ty = tid >> 4;
    int x0 = (blockIdx.x & 15) * 16, y0 = (blockIdx.x >> 4) * 16;
    int octile = blockIdx.y;
    int g = octile >> 2;                 // 4 oc-tiles of 16 per 64-out group
    int oc0 = octile * 16;
    int b = blockIdx.z;
    const float* in = (g == 0) ? s0 : (g == 1) ? s1 : s2;
    in += (size_t)b * DIM * NP;
    const float* wbase = w + (size_t)oc0 * DIM * 9;

    float acc[16];
#pragma unroll
    for (int o = 0; o < 16; ++o) acc[o] = 0.f;

    int y = y0 + ty, xx = x0 + tx;
    for (int ic = 0; ic < DIM; ++ic) {
        const float* inc = in + (size_t)ic * NP;
        for (int l = tid; l < 18 * 18; l += 256) {
            int ly = l / 18, lx = l - ly * 18;
            int gy = y0 + ly - 1, gx = x0 + lx - 1;
            float v = 0.f;
            if (gy >= 0 && gy < HH && gx >= 0 && gx < WH) v = inc[gy * WH + gx];
            tile[l] = v;
        }
        __syncthreads();
        float tv[9];
#pragma unroll
        for (int dy = 0; dy < 3; ++dy)
#pragma unroll
            for (int dx = 0; dx < 3; ++dx)
                tv[dy * 3 + dx] = tile[(ty + dy) * 18 + (tx + dx)];
        const float* wic = wbase + ic * 9;
#pragma unroll
        for (int o = 0; o < 16; ++o) {
#pragma unroll
            for (int t = 0; t < 9; ++t)
                acc[o] = fmaf(tv[t], wic[(size_t)o * DIM * 9 + t], acc[o]);
        }
        __syncthreads();
    }
    size_t obase = ((size_t)b * OC + oc0) * NP + (size_t)y * WH + xx;
#pragma unroll
    for (int o = 0; o < 16; ++o) out[obase + (size_t)o * NP] = fmaxf(acc[o], 0.f);
}

// ---------------- 1x1 conv, 64-out chunk ----------------
template <int CIN, bool RELU>
__global__ __launch_bounds__(256) void k_conv1x1(const float* __restrict__ in,
                                                 const float* __restrict__ w,
                                                 float* __restrict__ out, int OCtot) {
    int p = blockIdx.x * 256 + threadIdx.x;
    int b = blockIdx.y;
    int oc0 = blockIdx.z * 64;
    float acc[64];
#pragma unroll
    for (int o = 0; o < 64; ++o) acc[o] = 0.f;
    const float* inp = in + (size_t)b * CIN * NP + p;
    const float* wb = w + (size_t)oc0 * CIN;
    for (int ic = 0; ic < CIN; ++ic) {
        float v = inp[(size_t)ic * NP];
#pragma unroll
        for (int o = 0; o < 64; ++o) acc[o] = fmaf(v, wb[(size_t)o * CIN + ic], acc[o]);
    }
    float* op = out + ((size_t)b * OCtot + oc0) * NP + p;
#pragma unroll
    for (int o = 0; o < 64; ++o) {
        float r = acc[o];
        if (RELU) r = fmaxf(r, 0.f);
        op[(size_t)o * NP] = r;
    }
}

// ---------------- depthwise 3x3 + fused v-filter ----------------
__global__ __launch_bounds__(256) void k_dwconv(const float* __restrict__ in,
                                                const float* __restrict__ w,
                                                const float* __restrict__ filt,
                                                float* __restrict__ out) {
    int p = blockIdx.x * 256 + threadIdx.x;
    int bc = blockIdx.y;                 // 0..BN*192
    int c = bc % 192, b = bc / 192;
    int x = p & (WH - 1), y = p >> 8;
    const float* inp = in + (size_t)bc * NP;
    const float* wc = w + c * 9;
    float s = 0.f;
#pragma unroll
    for (int dy = -1; dy <= 1; ++dy) {
        int yy = y + dy;
        if (yy < 0 || yy >= HH) continue;
#pragma unroll
        for (int dx = -1; dx <= 1; ++dx) {
            int xx = x + dx;
            if (xx < 0 || xx >= WH) continue;
            s = fmaf(inp[yy * WH + xx], wc[(dy + 1) * 3 + (dx + 1)], s);
        }
    }
    if (c >= 128) {
        float f = filt[((size_t)b * DIM + (c - 128)) * NP + p];
        s = fmaf(s, f, s);               // s * (1 + f)
    }
    out[(size_t)bc * NP + p] = s;
}

// ---------------- row L2 norms for q,k ----------------
__global__ __launch_bounds__(256) void k_norms(const float* __restrict__ qkv,
                                               float* __restrict__ norms) {
    int bx = blockIdx.x;                 // [0, BN*128): c<64 => q, else k
    int b = bx >> 7, c = bx & 127;
    const float* row = qkv + ((size_t)b * 192 + c) * NP;
    float s = 0.f;
    for (int i = threadIdx.x; i < NP; i += 256) {
        float v = row[i];
        s = fmaf(v, v, s);
    }
#pragma unroll
    for (int off = 32; off; off >>= 1) s += __shfl_down(s, off);
    __shared__ float wsum[4];
    if ((threadIdx.x & 63) == 0) wsum[threadIdx.x >> 6] = s;
    __syncthreads();
    if (threadIdx.x == 0)
        norms[bx] = fmaxf(sqrtf(wsum[0] + wsum[1] + wsum[2] + wsum[3]), 1e-12f);
}

// ---------------- attention dots (stage 1, split over n) ----------------
__global__ __launch_bounds__(256) void k_attn_dot(const float* __restrict__ qkv,
                                                  float* __restrict__ praw) {
    int bhd = blockIdx.x, sp = blockIdx.y;   // grid (32, 8)
    int b = bhd >> 3, hd = bhd & 7;
    const float* qb = qkv + ((size_t)b * 192 + hd * 8) * NP;
    const float* kb = qkv + ((size_t)b * 192 + 64 + hd * 8) * NP;
    float acc[64];
#pragma unroll
    for (int i = 0; i < 64; ++i) acc[i] = 0.f;
    int n0 = sp * (NP / 8);
    for (int n = n0 + threadIdx.x; n < n0 + NP / 8; n += 256) {
        float qv[8], kv[8];
#pragma unroll
        for (int c2 = 0; c2 < 8; ++c2) qv[c2] = qb[(size_t)c2 * NP + n];
#pragma unroll
        for (int d2 = 0; d2 < 8; ++d2) kv[d2] = kb[(size_t)d2 * NP + n];
#pragma unroll
        for (int c2 = 0; c2 < 8; ++c2)
#pragma unroll
            for (int d2 = 0; d2 < 8; ++d2)
                acc[c2 * 8 + d2] = fmaf(qv[c2], kv[d2], acc[c2 * 8 + d2]);
    }
    __shared__ float red[4][64];
#pragma unroll
    for (int i = 0; i < 64; ++i) {
        float v = acc[i];
#pragma unroll
        for (int off = 32; off; off >>= 1) v += __shfl_down(v, off);
        if ((threadIdx.x & 63) == 0) red[threadIdx.x >> 6][i] = v;
    }
    __syncthreads();
    if (threadIdx.x < 64)
        praw[((size_t)sp * 32 + bhd) * 64 + threadIdx.x] =
            red[0][threadIdx.x] + red[1][threadIdx.x] + red[2][threadIdx.x] + red[3][threadIdx.x];
}

// ---------------- scale + softmax (stage 2) ----------------
__global__ __launch_bounds__(64) void k_attn_soft(const float* __restrict__ praw,
                                                  const float* __restrict__ norms,
                                                  const float* __restrict__ temp,
                                                  float* __restrict__ attn) {
    int bhd = blockIdx.x;                // 32 blocks, 64 threads
    int b = bhd >> 3, hd = bhd & 7;
    int t = threadIdx.x, c = t >> 3, d = t & 7;
    float s = 0.f;
    for (int sp = 0; sp < 8; ++sp) s += praw[((size_t)sp * 32 + bhd) * 64 + t];
    float nq = norms[b * 128 + hd * 8 + c];
    float nk = norms[b * 128 + 64 + hd * 8 + d];
    s = s / (nq * nk) * temp[hd];
    __shared__ float sm[64];
    __shared__ float se[64];
    sm[t] = s;
    __syncthreads();
    float mx = -1e30f;
#pragma unroll
    for (int dd = 0; dd < 8; ++dd) mx = fmaxf(mx, sm[c * 8 + dd]);
    float e = __expf(s - mx);
    se[t] = e;
    __syncthreads();
    float sum = 0.f;
#pragma unroll
    for (int dd = 0; dd < 8; ++dd) sum += se[c * 8 + dd];
    attn[(size_t)bhd * 64 + t] = e / sum;
}

// ---------------- attn*v fused with 1x1 proj ----------------
__global__ __launch_bounds__(256) void k_attnout_proj(const float* __restrict__ qkv,
                                                      const float* __restrict__ attn,
                                                      const float* __restrict__ wproj,
                                                      float* __restrict__ proj) {
    int p = blockIdx.x * 256 + threadIdx.x;
    int b = blockIdx.y;
    float o64[64];
    const float* vb = qkv + ((size_t)b * 192 + 128) * NP + p;
#pragma unroll
    for (int hd = 0; hd < 8; ++hd) {
        float vv[8];
#pragma unroll
        for (int d = 0; d < 8; ++d) vv[d] = vb[(size_t)(hd * 8 + d) * NP];
        const float* A = attn + (size_t)(b * 8 + hd) * 64;
#pragma unroll
        for (int c2 = 0; c2 < 8; ++c2) {
            float s = 0.f;
#pragma unroll
            for (int d = 0; d < 8; ++d) s = fmaf(A[c2 * 8 + d], vv[d], s);
            o64[hd * 8 + c2] = s;
        }
    }
    float* op = proj + (size_t)b * DIM * NP + p;
    for (int oc = 0; oc < 64; ++oc) {
        float s = 0.f;
#pragma unroll
        for (int ic = 0; ic < 64; ++ic) s = fmaf(o64[ic], wproj[(size_t)oc * 64 + ic], s);
        op[(size_t)oc * NP] = s;
    }
}

// ---------------- IDWT + fp32 store ----------------
__global__ __launch_bounds__(256) void k_idwt(const float* __restrict__ ll,
                                              const float* __restrict__ yh,
                                              float* __restrict__ out) {
    int idx = blockIdx.x * 256 + threadIdx.x;  // over BN*DIM*NP
    int j = idx & 255, i = (idx >> 8) & 255;
    int bc = idx >> 16;
    int b = bc >> 6, c = bc & 63;
    size_t sp = (size_t)i * WH + j;
    float LLv = ll[idx];
    float LHv = yh[((size_t)b * 192 + c) * NP + sp];
    float HLv = yh[((size_t)b * 192 + 64 + c) * NP + sp];
    float HHv = yh[((size_t)b * 192 + 128 + c) * NP + sp];
    float av = (LLv - LHv - HLv + HHv) * 0.5f;
    float bv = (LLv - LHv + HLv - HHv) * 0.5f;
    float cv = (LLv + LHv - HLv - HHv) * 0.5f;
    float dv = (LLv + LHv + HLv + HHv) * 0.5f;
    float* base = out + (size_t)bc * HF * WF;
    *(float2*)(base + (size_t)(2 * i) * WF + 2 * j)     = make_float2(av, bv);
    *(float2*)(base + (size_t)(2 * i + 1) * WF + 2 * j) = make_float2(cv, dv);
}

extern "C" void kernel_launch(void* const* d_in, const int* in_sizes, int n_in,
                              void* d_out, int out_size, void* d_ws, size_t ws_size,
                              hipStream_t stream) {
    const float* x      = (const float*)d_in[0];
    const float* w_hc1  = (const float*)d_in[1];
    const float* w_hc2  = (const float*)d_in[2];
    const float* w_ho   = (const float*)d_in[3];
    const float* w_qkv  = (const float*)d_in[4];
    const float* w_dw   = (const float*)d_in[5];
    const float* w_proj = (const float*)d_in[6];
    const float* temp   = (const float*)d_in[7];
    float* out = (float*)d_out;

    float* ws = (float*)d_ws;
    const size_t SB = (size_t)BN * DIM * NP;   // 16.78M floats (64 MiB)
    // Slot map (10 x SB + epsilon), tight liveness:
    //  s0:LL  s1:LH  s2:HL  (dead after steps 5/3/3 -> reused as QKV s0-2)
    //  s3:HH  (dead after step 2 -> reused as filter_hv)
    //  s4-6:YH (live to end)
    //  s7-8:t1 (dead after step 4) ; s7-9:qkv0 (dead after step 6) ; s7: proj
    float* LL   = ws;
    float* LH   = ws + SB;
    float* HL   = ws + 2 * SB;
    float* HHb  = ws + 3 * SB;     // -> filter_hv
    float* YH   = ws + 4 * SB;     // 3 slots
    float* T1   = ws + 7 * SB;     // 2 slots
    float* QKV0 = ws + 7 * SB;     // 3 slots (after T1 dead)
    float* QKV  = ws;              // 3 slots (after LL/LH/HL dead)
    float* PROJ = ws + 7 * SB;     // 1 slot (after QKV0 dead)
    float* PRAW = ws + 10 * SB;    // 16384
    float* NORM = PRAW + 8 * 32 * 64;  // 512
    float* ATTN = NORM + 512;          // 2048

    // 1. DWT
    k_dwt<<<(BN * DIM * NP) / 256, 256, 0, stream>>>(x, LL, LH, HL, HHb);
    // 2. yh = relu(gconv3x3(concat(LH,HL,HH), w_ho, groups=3))
    k_gconv3x3<<<dim3(256, 12, BN), 256, 0, stream>>>(LH, HL, HHb, w_ho, YH, 192);
    // 3. t1 = relu(gconv3x3(concat(LH,HL), w_hc1, groups=2))
    k_gconv3x3<<<dim3(256, 8, BN), 256, 0, stream>>>(LH, HL, nullptr, w_hc1, T1, 128);
    // 4. filter_hv = relu(1x1(t1, w_hc2)) -> HH slot
    k_conv1x1<128, true><<<dim3(NP / 256, BN, 1), 256, 0, stream>>>(T1, w_hc2, HHb, 64);
    // 5. qkv0 = 1x1(LL, w_qkv)
    k_conv1x1<64, false><<<dim3(NP / 256, BN, 3), 256, 0, stream>>>(LL, w_qkv, QKV0, 192);
    // 6. qkv = dw3x3(qkv0), v-channels scaled by (1+filter)
    k_dwconv<<<dim3(NP / 256, BN * 192), 256, 0, stream>>>(QKV0, w_dw, HHb, QKV);
    // 7. q,k row norms
    k_norms<<<BN * 128, 256, 0, stream>>>(QKV, NORM);
    // 8-9. attention scores + softmax
    k_attn_dot<<<dim3(32, 8), 256, 0, stream>>>(QKV, PRAW);
    k_attn_soft<<<32, 64, 0, stream>>>(PRAW, NORM, temp, ATTN);
    // 10. out = attn*v, fused 1x1 proj
    k_attnout_proj<<<dim3(NP / 256, BN), 256, 0, stream>>>(QKV, ATTN, w_proj, PROJ);
    // 11. IDWT -> fp32 out
    k_idwt<<<(BN * DIM * NP) / 256, 256, 0, stream>>>(PROJ, YH, out);
}

// Round 3
// 1622.876 us; speedup vs baseline: 1.7074x; 1.7074x over previous
//
#include <hip/hip_runtime.h>
#include <hip/hip_bf16.h>

#define BN 4
#define DIM 64
#define NHEADS 8
#define HH 256
#define WH 256
#define NP (HH*WH)      // 65536
#define HF 512
#define WF 512

typedef __attribute__((ext_vector_type(8))) short bfx8;   // 8 bf16 (4 VGPR)
typedef __attribute__((ext_vector_type(4))) float f32x4;  // MFMA C/D frag

static __device__ __forceinline__ short f2bf(float f) {
    unsigned u = __float_as_uint(f);
    unsigned r = (u + 0x7FFFu + ((u >> 16) & 1u)) >> 16;   // RNE
    return (short)r;
}

// ---------------- DWT ----------------
__global__ __launch_bounds__(256) void k_dwt(const float* __restrict__ x,
                                             float* __restrict__ LL, float* __restrict__ LH,
                                             float* __restrict__ HL, float* __restrict__ HHo) {
    int idx = blockIdx.x * 256 + threadIdx.x;          // over BN*DIM*NP
    int j = idx & (WH - 1);
    int i = (idx >> 8) & (HH - 1);
    int bc = idx >> 16;
    const float2* row0 = (const float2*)(x + (size_t)bc * HF * WF + (size_t)(2 * i) * WF);
    const float2* row1 = (const float2*)(x + (size_t)bc * HF * WF + (size_t)(2 * i + 1) * WF);
    float2 e = row0[j];
    float2 o = row1[j];
    float a = e.x, b = e.y, c = o.x, d = o.y;
    LL[idx]  = ( a + b + c + d) * 0.5f;
    LH[idx]  = (-a - b + c + d) * 0.5f;
    HL[idx]  = (-a + b - c + d) * 0.5f;
    HHo[idx] = ( a - b - c + d) * 0.5f;
}

// ---------------- weight repack: OIHW fp32 -> [g][tap][icb][oc][8] bf16 ----------------
__global__ __launch_bounds__(256) void k_repack(const float* __restrict__ w,
                                                short* __restrict__ wrep, int total) {
    int t = blockIdx.x * 256 + threadIdx.x;
    if (t >= total) return;
    unsigned g   = (unsigned)t / 36864u;
    unsigned r1  = (unsigned)t % 36864u;
    unsigned tap = r1 / 4096u;
    unsigned r2  = r1 % 4096u;
    unsigned icb = r2 / 512u;
    unsigned r3  = r2 % 512u;
    unsigned oc  = r3 >> 3;
    unsigned j   = r3 & 7u;
    unsigned ic  = icb * 8u + j;
    wrep[t] = f2bf(w[(((size_t)g * 64 + oc) * 64 + ic) * 9 + tap]);
}

// ---------------- grouped 3x3 conv (+relu) via bf16 MFMA implicit GEMM ----------------
// grid: (256 tiles of 16x16, G groups, BN). block 256 = 4 waves.
// in_base: G contiguous tensors [BN][64][NP] fp32. out: [BN][G*64][NP].
__global__ __launch_bounds__(256) void k_gconv3x3_mfma(const float* __restrict__ in_base,
                                                       const bfx8* __restrict__ wr,
                                                       float* __restrict__ out, int OC) {
    __shared__ short lds_in[324 * 64] __attribute__((aligned(16)));
    const int tid = threadIdx.x;
    const int l = tid & 63, wv = tid >> 6;
    const int x0 = (blockIdx.x & 15) * 16, y0 = (blockIdx.x >> 4) * 16;
    const int g = blockIdx.y, b = blockIdx.z;
    const float* in = in_base + (size_t)g * ((size_t)BN * DIM * NP) + (size_t)b * DIM * NP;

    // ---- stage input halo tile (18x18 x 64ic) as bf16, swizzled [hp][ic] ----
#pragma unroll 3
    for (int it = 0; it < 81; ++it) {
        unsigned e = (unsigned)(tid + it * 256);   // 0..20735
        unsigned ic = e / 324u;
        unsigned hp = e - ic * 324u;
        unsigned hy = hp / 18u;
        unsigned hx = hp - hy * 18u;
        int gy = y0 - 1 + (int)hy, gx = x0 - 1 + (int)hx;
        float v = 0.f;
        if ((unsigned)gy < (unsigned)HH && (unsigned)gx < (unsigned)WH)
            v = in[(size_t)ic * NP + gy * WH + gx];
        lds_in[hp * 64 + ((((ic >> 3) + hp) & 7u) << 3) + (ic & 7u)] = f2bf(v);
    }
    __syncthreads();

    f32x4 acc[4][4];
#pragma unroll
    for (int i = 0; i < 4; ++i)
#pragma unroll
        for (int j = 0; j < 4; ++j) acc[i][j] = (f32x4){0.f, 0.f, 0.f, 0.f};

    const int lx = l & 15, lq = l >> 4;
#pragma unroll
    for (int c = 0; c < 2; ++c) {
        const int icb = c * 4 + lq;
#pragma unroll
        for (int tap = 0; tap < 9; ++tap) {
            const int dy = tap / 3, dx = tap % 3;
            const size_t wbase = ((size_t)(g * 9 + tap) * 8 + icb) * 64 + lx;
            bfx8 b0 = wr[wbase];
            bfx8 b1 = wr[wbase + 16];
            bfx8 b2 = wr[wbase + 32];
            bfx8 b3 = wr[wbase + 48];
#pragma unroll
            for (int pg = 0; pg < 4; ++pg) {
                int hp = (wv * 4 + pg + dy) * 18 + lx + dx;
                const bfx8* ap = (const bfx8*)&lds_in[hp * 64 + (((icb + hp) & 7) << 3)];
                bfx8 a = *ap;
                acc[pg][0] = __builtin_amdgcn_mfma_f32_16x16x32_bf16(a, b0, acc[pg][0], 0, 0, 0);
                acc[pg][1] = __builtin_amdgcn_mfma_f32_16x16x32_bf16(a, b1, acc[pg][1], 0, 0, 0);
                acc[pg][2] = __builtin_amdgcn_mfma_f32_16x16x32_bf16(a, b2, acc[pg][2], 0, 0, 0);
                acc[pg][3] = __builtin_amdgcn_mfma_f32_16x16x32_bf16(a, b3, acc[pg][3], 0, 0, 0);
            }
        }
    }

    // ---- store: D col=lane&15 -> oc, row=(lane>>4)*4+r -> px ----
#pragma unroll
    for (int pg = 0; pg < 4; ++pg) {
#pragma unroll
        for (int ocg = 0; ocg < 4; ++ocg) {
            float* op = out + ((size_t)b * OC + g * 64 + ocg * 16 + lx) * NP
                            + (size_t)(y0 + wv * 4 + pg) * WH + x0 + lq * 4;
            f32x4 v = acc[pg][ocg];
            *(float4*)op = make_float4(fmaxf(v.x, 0.f), fmaxf(v.y, 0.f),
                                       fmaxf(v.z, 0.f), fmaxf(v.w, 0.f));
        }
    }
}

// ---------------- 1x1 conv, 64-out chunk ----------------
template <int CIN, bool RELU>
__global__ __launch_bounds__(256) void k_conv1x1(const float* __restrict__ in,
                                                 const float* __restrict__ w,
                                                 float* __restrict__ out, int OCtot) {
    int p = blockIdx.x * 256 + threadIdx.x;
    int b = blockIdx.y;
    int oc0 = blockIdx.z * 64;
    float acc[64];
#pragma unroll
    for (int o = 0; o < 64; ++o) acc[o] = 0.f;
    const float* inp = in + (size_t)b * CIN * NP + p;
    const float* wb = w + (size_t)oc0 * CIN;
    for (int ic = 0; ic < CIN; ++ic) {
        float v = inp[(size_t)ic * NP];
#pragma unroll
        for (int o = 0; o < 64; ++o) acc[o] = fmaf(v, wb[(size_t)o * CIN + ic], acc[o]);
    }
    float* op = out + ((size_t)b * OCtot + oc0) * NP + p;
#pragma unroll
    for (int o = 0; o < 64; ++o) {
        float r = acc[o];
        if (RELU) r = fmaxf(r, 0.f);
        op[(size_t)o * NP] = r;
    }
}

// ---------------- depthwise 3x3 + fused v-filter ----------------
__global__ __launch_bounds__(256) void k_dwconv(const float* __restrict__ in,
                                                const float* __restrict__ w,
                                                const float* __restrict__ filt,
                                                float* __restrict__ out) {
    int p = blockIdx.x * 256 + threadIdx.x;
    int bc = blockIdx.y;                 // 0..BN*192
    int c = bc % 192, b = bc / 192;
    int x = p & (WH - 1), y = p >> 8;
    const float* inp = in + (size_t)bc * NP;
    const float* wc = w + c * 9;
    float s = 0.f;
#pragma unroll
    for (int dy = -1; dy <= 1; ++dy) {
        int yy = y + dy;
        if (yy < 0 || yy >= HH) continue;
#pragma unroll
        for (int dx = -1; dx <= 1; ++dx) {
            int xx = x + dx;
            if (xx < 0 || xx >= WH) continue;
            s = fmaf(inp[yy * WH + xx], wc[(dy + 1) * 3 + (dx + 1)], s);
        }
    }
    if (c >= 128) {
        float f = filt[((size_t)b * DIM + (c - 128)) * NP + p];
        s = fmaf(s, f, s);               // s * (1 + f)
    }
    out[(size_t)bc * NP + p] = s;
}

// ---------------- row L2 norms for q,k ----------------
__global__ __launch_bounds__(256) void k_norms(const float* __restrict__ qkv,
                                               float* __restrict__ norms) {
    int bx = blockIdx.x;                 // [0, BN*128): c<64 => q, else k
    int b = bx >> 7, c = bx & 127;
    const float* row = qkv + ((size_t)b * 192 + c) * NP;
    float s = 0.f;
    for (int i = threadIdx.x; i < NP; i += 256) {
        float v = row[i];
        s = fmaf(v, v, s);
    }
#pragma unroll
    for (int off = 32; off; off >>= 1) s += __shfl_down(s, off);
    __shared__ float wsum[4];
    if ((threadIdx.x & 63) == 0) wsum[threadIdx.x >> 6] = s;
    __syncthreads();
    if (threadIdx.x == 0)
        norms[bx] = fmaxf(sqrtf(wsum[0] + wsum[1] + wsum[2] + wsum[3]), 1e-12f);
}

// ---------------- attention dots (stage 1, split over n) ----------------
__global__ __launch_bounds__(256) void k_attn_dot(const float* __restrict__ qkv,
                                                  float* __restrict__ praw) {
    int bhd = blockIdx.x, sp = blockIdx.y;   // grid (32, 8)
    int b = bhd >> 3, hd = bhd & 7;
    const float* qb = qkv + ((size_t)b * 192 + hd * 8) * NP;
    const float* kb = qkv + ((size_t)b * 192 + 64 + hd * 8) * NP;
    float acc[64];
#pragma unroll
    for (int i = 0; i < 64; ++i) acc[i] = 0.f;
    int n0 = sp * (NP / 8);
    for (int n = n0 + threadIdx.x; n < n0 + NP / 8; n += 256) {
        float qv[8], kv[8];
#pragma unroll
        for (int c2 = 0; c2 < 8; ++c2) qv[c2] = qb[(size_t)c2 * NP + n];
#pragma unroll
        for (int d2 = 0; d2 < 8; ++d2) kv[d2] = kb[(size_t)d2 * NP + n];
#pragma unroll
        for (int c2 = 0; c2 < 8; ++c2)
#pragma unroll
            for (int d2 = 0; d2 < 8; ++d2)
                acc[c2 * 8 + d2] = fmaf(qv[c2], kv[d2], acc[c2 * 8 + d2]);
    }
    __shared__ float red[4][64];
#pragma unroll
    for (int i = 0; i < 64; ++i) {
        float v = acc[i];
#pragma unroll
        for (int off = 32; off; off >>= 1) v += __shfl_down(v, off);
        if ((threadIdx.x & 63) == 0) red[threadIdx.x >> 6][i] = v;
    }
    __syncthreads();
    if (threadIdx.x < 64)
        praw[((size_t)sp * 32 + bhd) * 64 + threadIdx.x] =
            red[0][threadIdx.x] + red[1][threadIdx.x] + red[2][threadIdx.x] + red[3][threadIdx.x];
}

// ---------------- scale + softmax (stage 2) ----------------
__global__ __launch_bounds__(64) void k_attn_soft(const float* __restrict__ praw,
                                                  const float* __restrict__ norms,
                                                  const float* __restrict__ temp,
                                                  float* __restrict__ attn) {
    int bhd = blockIdx.x;                // 32 blocks, 64 threads
    int b = bhd >> 3, hd = bhd & 7;
    int t = threadIdx.x, c = t >> 3, d = t & 7;
    float s = 0.f;
    for (int sp = 0; sp < 8; ++sp) s += praw[((size_t)sp * 32 + bhd) * 64 + t];
    float nq = norms[b * 128 + hd * 8 + c];
    float nk = norms[b * 128 + 64 + hd * 8 + d];
    s = s / (nq * nk) * temp[hd];
    __shared__ float sm[64];
    __shared__ float se[64];
    sm[t] = s;
    __syncthreads();
    float mx = -1e30f;
#pragma unroll
    for (int dd = 0; dd < 8; ++dd) mx = fmaxf(mx, sm[c * 8 + dd]);
    float e = __expf(s - mx);
    se[t] = e;
    __syncthreads();
    float sum = 0.f;
#pragma unroll
    for (int dd = 0; dd < 8; ++dd) sum += se[c * 8 + dd];
    attn[(size_t)bhd * 64 + t] = e / sum;
}

// ---------------- attn*v fused with 1x1 proj ----------------
__global__ __launch_bounds__(256) void k_attnout_proj(const float* __restrict__ qkv,
                                                      const float* __restrict__ attn,
                                                      const float* __restrict__ wproj,
                                                      float* __restrict__ proj) {
    int p = blockIdx.x * 256 + threadIdx.x;
    int b = blockIdx.y;
    float o64[64];
    const float* vb = qkv + ((size_t)b * 192 + 128) * NP + p;
#pragma unroll
    for (int hd = 0; hd < 8; ++hd) {
        float vv[8];
#pragma unroll
        for (int d = 0; d < 8; ++d) vv[d] = vb[(size_t)(hd * 8 + d) * NP];
        const float* A = attn + (size_t)(b * 8 + hd) * 64;
#pragma unroll
        for (int c2 = 0; c2 < 8; ++c2) {
            float s = 0.f;
#pragma unroll
            for (int d = 0; d < 8; ++d) s = fmaf(A[c2 * 8 + d], vv[d], s);
            o64[hd * 8 + c2] = s;
        }
    }
    float* op = proj + (size_t)b * DIM * NP + p;
    for (int oc = 0; oc < 64; ++oc) {
        float s = 0.f;
#pragma unroll
        for (int ic = 0; ic < 64; ++ic) s = fmaf(o64[ic], wproj[(size_t)oc * 64 + ic], s);
        op[(size_t)oc * NP] = s;
    }
}

// ---------------- IDWT + fp32 store ----------------
__global__ __launch_bounds__(256) void k_idwt(const float* __restrict__ ll,
                                              const float* __restrict__ yh,
                                              float* __restrict__ out) {
    int idx = blockIdx.x * 256 + threadIdx.x;  // over BN*DIM*NP
    int j = idx & 255, i = (idx >> 8) & 255;
    int bc = idx >> 16;
    int b = bc >> 6, c = bc & 63;
    size_t sp = (size_t)i * WH + j;
    float LLv = ll[idx];
    float LHv = yh[((size_t)b * 192 + c) * NP + sp];
    float HLv = yh[((size_t)b * 192 + 64 + c) * NP + sp];
    float HHv = yh[((size_t)b * 192 + 128 + c) * NP + sp];
    float av = (LLv - LHv - HLv + HHv) * 0.5f;
    float bv = (LLv - LHv + HLv - HHv) * 0.5f;
    float cv = (LLv + LHv - HLv - HHv) * 0.5f;
    float dv = (LLv + LHv + HLv + HHv) * 0.5f;
    float* base = out + (size_t)bc * HF * WF;
    *(float2*)(base + (size_t)(2 * i) * WF + 2 * j)     = make_float2(av, bv);
    *(float2*)(base + (size_t)(2 * i + 1) * WF + 2 * j) = make_float2(cv, dv);
}

extern "C" void kernel_launch(void* const* d_in, const int* in_sizes, int n_in,
                              void* d_out, int out_size, void* d_ws, size_t ws_size,
                              hipStream_t stream) {
    const float* x      = (const float*)d_in[0];
    const float* w_hc1  = (const float*)d_in[1];
    const float* w_hc2  = (const float*)d_in[2];
    const float* w_ho   = (const float*)d_in[3];
    const float* w_qkv  = (const float*)d_in[4];
    const float* w_dw   = (const float*)d_in[5];
    const float* w_proj = (const float*)d_in[6];
    const float* temp   = (const float*)d_in[7];
    float* out = (float*)d_out;

    float* ws = (float*)d_ws;
    const size_t SB = (size_t)BN * DIM * NP;   // 16.78M floats (64 MiB)
    float* LL   = ws;
    float* LH   = ws + SB;         // LH,HL,HH contiguous => gconv group base
    float* HL   = ws + 2 * SB;
    float* HHb  = ws + 3 * SB;     // -> filter_hv
    float* YH   = ws + 4 * SB;     // 3 slots
    float* T1   = ws + 7 * SB;     // 2 slots
    float* QKV0 = ws + 7 * SB;     // 3 slots (after T1 dead)
    float* QKV  = ws;              // 3 slots (after LL/LH/HL dead)
    float* PROJ = ws + 7 * SB;     // 1 slot (after QKV0 dead)
    float* PRAW = ws + 10 * SB;    // 16384
    float* NORM = PRAW + 8 * 32 * 64;  // 512
    float* ATTN = NORM + 512;          // 2048
    short* WREP_HO  = (short*)(ws + 10 * SB + 32768);       // 110592 bf16
    short* WREP_HC1 = WREP_HO + 3 * 36864;                  // 73728 bf16

    // 0. repack conv weights to bf16 [g][tap][icb][oc][8]
    k_repack<<<(3 * 36864 + 255) / 256, 256, 0, stream>>>(w_ho, WREP_HO, 3 * 36864);
    k_repack<<<(2 * 36864 + 255) / 256, 256, 0, stream>>>(w_hc1, WREP_HC1, 2 * 36864);
    // 1. DWT
    k_dwt<<<(BN * DIM * NP) / 256, 256, 0, stream>>>(x, LL, LH, HL, HHb);
    // 2. yh = relu(gconv3x3(concat(LH,HL,HH), w_ho, groups=3))  [MFMA]
    k_gconv3x3_mfma<<<dim3(256, 3, BN), 256, 0, stream>>>(LH, (const bfx8*)WREP_HO, YH, 192);
    // 3. t1 = relu(gconv3x3(concat(LH,HL), w_hc1, groups=2))    [MFMA]
    k_gconv3x3_mfma<<<dim3(256, 2, BN), 256, 0, stream>>>(LH, (const bfx8*)WREP_HC1, T1, 128);
    // 4. filter_hv = relu(1x1(t1, w_hc2)) -> HH slot
    k_conv1x1<128, true><<<dim3(NP / 256, BN, 1), 256, 0, stream>>>(T1, w_hc2, HHb, 64);
    // 5. qkv0 = 1x1(LL, w_qkv)
    k_conv1x1<64, false><<<dim3(NP / 256, BN, 3), 256, 0, stream>>>(LL, w_qkv, QKV0, 192);
    // 6. qkv = dw3x3(qkv0), v-channels scaled by (1+filter)
    k_dwconv<<<dim3(NP / 256, BN * 192), 256, 0, stream>>>(QKV0, w_dw, HHb, QKV);
    // 7. q,k row norms
    k_norms<<<BN * 128, 256, 0, stream>>>(QKV, NORM);
    // 8-9. attention scores + softmax
    k_attn_dot<<<dim3(32, 8), 256, 0, stream>>>(QKV, PRAW);
    k_attn_soft<<<32, 64, 0, stream>>>(PRAW, NORM, temp, ATTN);
    // 10. out = attn*v, fused 1x1 proj
    k_attnout_proj<<<dim3(NP / 256, BN), 256, 0, stream>>>(QKV, ATTN, w_proj, PROJ);
    // 11. IDWT -> fp32 out
    k_idwt<<<(BN * DIM * NP) / 256, 256, 0, stream>>>(PROJ, YH, out);
}

// Round 4
// 1326.671 us; speedup vs baseline: 2.0886x; 1.2233x over previous
//
#include <hip/hip_runtime.h>
#include <hip/hip_bf16.h>

#define BN 4
#define DIM 64
#define NHEADS 8
#define HH 256
#define WH 256
#define NP (HH*WH)      // 65536
#define HF 512
#define WF 512

typedef __attribute__((ext_vector_type(8))) short bfx8;   // 8 bf16 (4 VGPR)
typedef __attribute__((ext_vector_type(4))) float f32x4;  // MFMA C/D frag

static __device__ __forceinline__ short f2bf(float f) {
    unsigned u = __float_as_uint(f);
    unsigned r = (u + 0x7FFFu + ((u >> 16) & 1u)) >> 16;   // RNE
    return (short)r;
}
static __device__ __forceinline__ float ldf(const float* p) { return *p; }
static __device__ __forceinline__ float ldf(const unsigned short* p) {
    return __uint_as_float((unsigned)(*p) << 16);
}
static __device__ __forceinline__ void stf(float* p, float v) { *p = v; }
static __device__ __forceinline__ void stf(unsigned short* p, float v) {
    *p = (unsigned short)f2bf(v);
}

// ---------------- DWT -> LL fp32 [ic][px]  +  LH/HL/HH bf16 tiled-halo layout ----------------
// tiled[b][plane][tile(256)][hp(324)][swz-ic(64)] bf16 — exactly the gconv LDS image.
__global__ __launch_bounds__(256) void k_dwt_t(const float* __restrict__ x,
                                               float* __restrict__ LL,
                                               unsigned short* __restrict__ tiled) {
    __shared__ short lds[3][324 * 64] __attribute__((aligned(16)));
    const int tid = threadIdx.x;
    const int tile = blockIdx.x, b = blockIdx.y;
    const int x0 = (tile & 15) * 16, y0 = (tile >> 4) * 16;

    for (int it = 0; it < 81; ++it) {
        unsigned e = (unsigned)(tid + it * 256);  // 0..20735
        unsigned ic = e / 324u;
        unsigned hp = e - ic * 324u;
        unsigned hy = hp / 18u, hx = hp - hy * 18u;
        int gy = y0 - 1 + (int)hy, gx = x0 - 1 + (int)hx;
        bool inb = ((unsigned)gy < 256u) && ((unsigned)gx < 256u);
        float a = 0.f, bb = 0.f, c = 0.f, d = 0.f;
        if (inb) {
            const float* px = x + (((size_t)(b * 64 + ic) * HF) + 2 * gy) * WF + 2 * gx;
            float2 e0 = *(const float2*)px;
            float2 e1 = *(const float2*)(px + WF);
            a = e0.x; bb = e0.y; c = e1.x; d = e1.y;
        }
        unsigned sw = hp * 64 + ((((ic >> 3) + hp) & 7u) << 3) + (ic & 7u);
        lds[0][sw] = f2bf((-a - bb + c + d) * 0.5f);   // LH
        lds[1][sw] = f2bf((-a + bb - c + d) * 0.5f);   // HL
        lds[2][sw] = f2bf(( a - bb - c + d) * 0.5f);   // HH
        if (inb && hy >= 1u && hy < 17u && hx >= 1u && hx < 17u)
            LL[(size_t)(b * 64 + ic) * NP + (size_t)gy * WH + gx] = (a + bb + c + d) * 0.5f;
    }
    __syncthreads();
    // linear copy LDS -> global (swizzle already baked in)
#pragma unroll
    for (int p = 0; p < 3; ++p) {
        char* gb = (char*)(tiled + (((size_t)(b * 3 + p) * 256 + tile) * 324) * 64);
        const char* lb = (const char*)lds[p];
#pragma unroll
        for (int it = 0; it < 10; ++it) {
            int cc = tid + it * 256;
            *(uint4*)(gb + (size_t)cc * 16) = *(const uint4*)(lb + (size_t)cc * 16);
        }
        if (tid < 32) {
            int cc = 2560 + tid;
            *(uint4*)(gb + (size_t)cc * 16) = *(const uint4*)(lb + (size_t)cc * 16);
        }
    }
}

// ---------------- weight repack: OIHW fp32 -> [g][tap][icb][oc][8] bf16 ----------------
__global__ __launch_bounds__(256) void k_repack(const float* __restrict__ w,
                                                short* __restrict__ wrep, int total) {
    int t = blockIdx.x * 256 + threadIdx.x;
    if (t >= total) return;
    unsigned g   = (unsigned)t / 36864u;
    unsigned r1  = (unsigned)t % 36864u;
    unsigned tap = r1 / 4096u;
    unsigned r2  = r1 % 4096u;
    unsigned icb = r2 / 512u;
    unsigned r3  = r2 % 512u;
    unsigned oc  = r3 >> 3;
    unsigned j   = r3 & 7u;
    unsigned ic  = icb * 8u + j;
    wrep[t] = f2bf(w[(((size_t)g * 64 + oc) * 64 + ic) * 9 + tap]);
}

// ---------------- grouped 3x3 conv (+relu) via bf16 MFMA, tiled bf16 input ----------------
// grid: (256 tiles, G groups, BN). block 256 = 4 waves. out: bf16 [b][OC][px].
__global__ __launch_bounds__(256) void k_gconv3x3_mfma(const unsigned short* __restrict__ tiled,
                                                       const bfx8* __restrict__ wr,
                                                       unsigned short* __restrict__ out, int OC) {
    __shared__ short lds_in[324 * 64] __attribute__((aligned(16)));
    const int tid = threadIdx.x;
    const int l = tid & 63, wv = tid >> 6;
    const int tile = blockIdx.x;
    const int x0 = (tile & 15) * 16, y0 = (tile >> 4) * 16;
    const int g = blockIdx.y, b = blockIdx.z;
    const unsigned short* src = tiled + (((size_t)(b * 3 + g) * 256 + tile) * 324) * 64;

    // stage 41472 B: 40 wave-groups of 1024 B via global_load_lds + 32-chunk tail
#pragma unroll
    for (int it = 0; it < 10; ++it) {
        int gv = it * 4 + wv;            // 0..39, wave-uniform
        __builtin_amdgcn_global_load_lds(
            (const __attribute__((address_space(1))) void*)(src + (size_t)gv * 512 + l * 8),
            (__attribute__((address_space(3))) void*)((short*)lds_in + gv * 512),
            16, 0, 0);
    }
    if (tid < 32) {
        int cc = 2560 + tid;
        *(uint4*)((char*)lds_in + (size_t)cc * 16) =
            *(const uint4*)((const char*)src + (size_t)cc * 16);
    }
    __syncthreads();

    f32x4 acc[4][4];
#pragma unroll
    for (int i = 0; i < 4; ++i)
#pragma unroll
        for (int j = 0; j < 4; ++j) acc[i][j] = (f32x4){0.f, 0.f, 0.f, 0.f};

    const int lx = l & 15, lq = l >> 4;
#pragma unroll
    for (int c = 0; c < 2; ++c) {
        const int icb = c * 4 + lq;
#pragma unroll
        for (int tap = 0; tap < 9; ++tap) {
            const int dy = tap / 3, dx = tap % 3;
            const size_t wbase = ((size_t)(g * 9 + tap) * 8 + icb) * 64 + lx;
            bfx8 b0 = wr[wbase];
            bfx8 b1 = wr[wbase + 16];
            bfx8 b2 = wr[wbase + 32];
            bfx8 b3 = wr[wbase + 48];
#pragma unroll
            for (int pg = 0; pg < 4; ++pg) {
                int hp = (wv * 4 + pg + dy) * 18 + lx + dx;
                const bfx8* ap = (const bfx8*)&lds_in[hp * 64 + (((icb + hp) & 7) << 3)];
                bfx8 a = *ap;
                acc[pg][0] = __builtin_amdgcn_mfma_f32_16x16x32_bf16(a, b0, acc[pg][0], 0, 0, 0);
                acc[pg][1] = __builtin_amdgcn_mfma_f32_16x16x32_bf16(a, b1, acc[pg][1], 0, 0, 0);
                acc[pg][2] = __builtin_amdgcn_mfma_f32_16x16x32_bf16(a, b2, acc[pg][2], 0, 0, 0);
                acc[pg][3] = __builtin_amdgcn_mfma_f32_16x16x32_bf16(a, b3, acc[pg][3], 0, 0, 0);
            }
        }
    }

    // store bf16: D col=lane&15 -> oc, row=(lane>>4)*4+r -> px-x
#pragma unroll
    for (int pg = 0; pg < 4; ++pg) {
#pragma unroll
        for (int ocg = 0; ocg < 4; ++ocg) {
            unsigned short* op = out + ((size_t)b * OC + g * 64 + ocg * 16 + lx) * NP
                                     + (size_t)(y0 + wv * 4 + pg) * WH + x0 + lq * 4;
            f32x4 v = acc[pg][ocg];
            ushort4 s4;
            s4.x = (unsigned short)f2bf(fmaxf(v.x, 0.f));
            s4.y = (unsigned short)f2bf(fmaxf(v.y, 0.f));
            s4.z = (unsigned short)f2bf(fmaxf(v.z, 0.f));
            s4.w = (unsigned short)f2bf(fmaxf(v.w, 0.f));
            *(ushort4*)op = s4;
        }
    }
}

// ---------------- 1x1 conv, 64-out chunk ----------------
template <int CIN, bool RELU, typename IT, typename OT>
__global__ __launch_bounds__(256) void k_conv1x1(const IT* __restrict__ in,
                                                 const float* __restrict__ w,
                                                 OT* __restrict__ out, int OCtot) {
    int p = blockIdx.x * 256 + threadIdx.x;
    int b = blockIdx.y;
    int oc0 = blockIdx.z * 64;
    float acc[64];
#pragma unroll
    for (int o = 0; o < 64; ++o) acc[o] = 0.f;
    const IT* inp = in + (size_t)b * CIN * NP + p;
    const float* wb = w + (size_t)oc0 * CIN;
    for (int ic = 0; ic < CIN; ++ic) {
        float v = ldf(inp + (size_t)ic * NP);
#pragma unroll
        for (int o = 0; o < 64; ++o) acc[o] = fmaf(v, wb[(size_t)o * CIN + ic], acc[o]);
    }
    OT* op = out + ((size_t)b * OCtot + oc0) * NP + p;
#pragma unroll
    for (int o = 0; o < 64; ++o) {
        float r = acc[o];
        if (RELU) r = fmaxf(r, 0.f);
        stf(op + (size_t)o * NP, r);
    }
}

// ---------------- depthwise 3x3 + fused v-filter (bf16 in/out) ----------------
__global__ __launch_bounds__(256) void k_dwconv(const unsigned short* __restrict__ in,
                                                const float* __restrict__ w,
                                                const float* __restrict__ filt,
                                                unsigned short* __restrict__ out) {
    int p = blockIdx.x * 256 + threadIdx.x;
    int bc = blockIdx.y;                 // 0..BN*192
    int c = bc % 192, b = bc / 192;
    int x = p & (WH - 1), y = p >> 8;
    const unsigned short* inp = in + (size_t)bc * NP;
    const float* wc = w + c * 9;
    float s = 0.f;
#pragma unroll
    for (int dy = -1; dy <= 1; ++dy) {
        int yy = y + dy;
        if (yy < 0 || yy >= HH) continue;
#pragma unroll
        for (int dx = -1; dx <= 1; ++dx) {
            int xx = x + dx;
            if (xx < 0 || xx >= WH) continue;
            s = fmaf(ldf(inp + yy * WH + xx), wc[(dy + 1) * 3 + (dx + 1)], s);
        }
    }
    if (c >= 128) {
        float f = filt[((size_t)b * DIM + (c - 128)) * NP + p];
        s = fmaf(s, f, s);               // s * (1 + f)
    }
    out[(size_t)bc * NP + p] = (unsigned short)f2bf(s);
}

// ---------------- row L2 norms for q,k ----------------
__global__ __launch_bounds__(256) void k_norms(const unsigned short* __restrict__ qkv,
                                               float* __restrict__ norms) {
    int bx = blockIdx.x;                 // [0, BN*128): c<64 => q, else k
    int b = bx >> 7, c = bx & 127;
    const unsigned short* row = qkv + ((size_t)b * 192 + c) * NP;
    float s = 0.f;
    for (int i = threadIdx.x; i < NP; i += 256) {
        float v = ldf(row + i);
        s = fmaf(v, v, s);
    }
#pragma unroll
    for (int off = 32; off; off >>= 1) s += __shfl_down(s, off);
    __shared__ float wsum[4];
    if ((threadIdx.x & 63) == 0) wsum[threadIdx.x >> 6] = s;
    __syncthreads();
    if (threadIdx.x == 0)
        norms[bx] = fmaxf(sqrtf(wsum[0] + wsum[1] + wsum[2] + wsum[3]), 1e-12f);
}

// ---------------- attention dots (stage 1, split over n) ----------------
__global__ __launch_bounds__(256) void k_attn_dot(const unsigned short* __restrict__ qkv,
                                                  float* __restrict__ praw) {
    int bhd = blockIdx.x, sp = blockIdx.y;   // grid (32, 8)
    int b = bhd >> 3, hd = bhd & 7;
    const unsigned short* qb = qkv + ((size_t)b * 192 + hd * 8) * NP;
    const unsigned short* kb = qkv + ((size_t)b * 192 + 64 + hd * 8) * NP;
    float acc[64];
#pragma unroll
    for (int i = 0; i < 64; ++i) acc[i] = 0.f;
    int n0 = sp * (NP / 8);
    for (int n = n0 + threadIdx.x; n < n0 + NP / 8; n += 256) {
        float qv[8], kv[8];
#pragma unroll
        for (int c2 = 0; c2 < 8; ++c2) qv[c2] = ldf(qb + (size_t)c2 * NP + n);
#pragma unroll
        for (int d2 = 0; d2 < 8; ++d2) kv[d2] = ldf(kb + (size_t)d2 * NP + n);
#pragma unroll
        for (int c2 = 0; c2 < 8; ++c2)
#pragma unroll
            for (int d2 = 0; d2 < 8; ++d2)
                acc[c2 * 8 + d2] = fmaf(qv[c2], kv[d2], acc[c2 * 8 + d2]);
    }
    __shared__ float red[4][64];
#pragma unroll
    for (int i = 0; i < 64; ++i) {
        float v = acc[i];
#pragma unroll
        for (int off = 32; off; off >>= 1) v += __shfl_down(v, off);
        if ((threadIdx.x & 63) == 0) red[threadIdx.x >> 6][i] = v;
    }
    __syncthreads();
    if (threadIdx.x < 64)
        praw[((size_t)sp * 32 + bhd) * 64 + threadIdx.x] =
            red[0][threadIdx.x] + red[1][threadIdx.x] + red[2][threadIdx.x] + red[3][threadIdx.x];
}

// ---------------- scale + softmax (stage 2) ----------------
__global__ __launch_bounds__(64) void k_attn_soft(const float* __restrict__ praw,
                                                  const float* __restrict__ norms,
                                                  const float* __restrict__ temp,
                                                  float* __restrict__ attn) {
    int bhd = blockIdx.x;                // 32 blocks, 64 threads
    int b = bhd >> 3, hd = bhd & 7;
    int t = threadIdx.x, c = t >> 3, d = t & 7;
    float s = 0.f;
    for (int sp = 0; sp < 8; ++sp) s += praw[((size_t)sp * 32 + bhd) * 64 + t];
    float nq = norms[b * 128 + hd * 8 + c];
    float nk = norms[b * 128 + 64 + hd * 8 + d];
    s = s / (nq * nk) * temp[hd];
    __shared__ float sm[64];
    __shared__ float se[64];
    sm[t] = s;
    __syncthreads();
    float mx = -1e30f;
#pragma unroll
    for (int dd = 0; dd < 8; ++dd) mx = fmaxf(mx, sm[c * 8 + dd]);
    float e = __expf(s - mx);
    se[t] = e;
    __syncthreads();
    float sum = 0.f;
#pragma unroll
    for (int dd = 0; dd < 8; ++dd) sum += se[c * 8 + dd];
    attn[(size_t)bhd * 64 + t] = e / sum;
}

// ---------------- attn*v fused with 1x1 proj ----------------
__global__ __launch_bounds__(256) void k_attnout_proj(const unsigned short* __restrict__ qkv,
                                                      const float* __restrict__ attn,
                                                      const float* __restrict__ wproj,
                                                      float* __restrict__ proj) {
    int p = blockIdx.x * 256 + threadIdx.x;
    int b = blockIdx.y;
    float o64[64];
    const unsigned short* vb = qkv + ((size_t)b * 192 + 128) * NP + p;
#pragma unroll
    for (int hd = 0; hd < 8; ++hd) {
        float vv[8];
#pragma unroll
        for (int d = 0; d < 8; ++d) vv[d] = ldf(vb + (size_t)(hd * 8 + d) * NP);
        const float* A = attn + (size_t)(b * 8 + hd) * 64;
#pragma unroll
        for (int c2 = 0; c2 < 8; ++c2) {
            float s = 0.f;
#pragma unroll
            for (int d = 0; d < 8; ++d) s = fmaf(A[c2 * 8 + d], vv[d], s);
            o64[hd * 8 + c2] = s;
        }
    }
    float* op = proj + (size_t)b * DIM * NP + p;
    for (int oc = 0; oc < 64; ++oc) {
        float s = 0.f;
#pragma unroll
        for (int ic = 0; ic < 64; ++ic) s = fmaf(o64[ic], wproj[(size_t)oc * 64 + ic], s);
        op[(size_t)oc * NP] = s;
    }
}

// ---------------- IDWT + fp32 store ----------------
__global__ __launch_bounds__(256) void k_idwt(const float* __restrict__ ll,
                                              const unsigned short* __restrict__ yh,
                                              float* __restrict__ out) {
    int idx = blockIdx.x * 256 + threadIdx.x;  // over BN*DIM*NP
    int j = idx & 255, i = (idx >> 8) & 255;
    int bc = idx >> 16;
    int b = bc >> 6, c = bc & 63;
    size_t sp = (size_t)i * WH + j;
    float LLv = ll[idx];
    float LHv = ldf(yh + ((size_t)b * 192 + c) * NP + sp);
    float HLv = ldf(yh + ((size_t)b * 192 + 64 + c) * NP + sp);
    float HHv = ldf(yh + ((size_t)b * 192 + 128 + c) * NP + sp);
    float av = (LLv - LHv - HLv + HHv) * 0.5f;
    float bv = (LLv - LHv + HLv - HHv) * 0.5f;
    float cv = (LLv + LHv - HLv - HHv) * 0.5f;
    float dv = (LLv + LHv + HLv + HHv) * 0.5f;
    float* base = out + (size_t)bc * HF * WF;
    *(float2*)(base + (size_t)(2 * i) * WF + 2 * j)     = make_float2(av, bv);
    *(float2*)(base + (size_t)(2 * i + 1) * WF + 2 * j) = make_float2(cv, dv);
}

extern "C" void kernel_launch(void* const* d_in, const int* in_sizes, int n_in,
                              void* d_out, int out_size, void* d_ws, size_t ws_size,
                              hipStream_t stream) {
    const float* x      = (const float*)d_in[0];
    const float* w_hc1  = (const float*)d_in[1];
    const float* w_hc2  = (const float*)d_in[2];
    const float* w_ho   = (const float*)d_in[3];
    const float* w_qkv  = (const float*)d_in[4];
    const float* w_dw   = (const float*)d_in[5];
    const float* w_proj = (const float*)d_in[6];
    const float* temp   = (const float*)d_in[7];
    float* out = (float*)d_out;

    char* base = (char*)d_ws;
    // byte layout (total ~506 MiB)
    float*          LL    = (float*)(base + 0);                  //  64 MiB fp32
    unsigned short* TILED = (unsigned short*)(base + 67108864ULL);   // 121.5 MiB bf16 tiled-halo
    unsigned short* YH    = (unsigned short*)(base + 194510848ULL);  //  96 MiB bf16 [b][192][px]
    unsigned short* T1    = (unsigned short*)(base + 295174144ULL);  //  64 MiB bf16 [b][128][px]
    float*          FILT  = (float*)(base + 362283008ULL);           //  64 MiB fp32 [b][64][px]
    unsigned short* QKV0  = (unsigned short*)(base + 429391872ULL);  //  96 MiB bf16 [b][192][px]
    unsigned short* QKV   = (unsigned short*)(base + 0);             //  96 MiB bf16 (reuse LL+TILED)
    float*          PROJ  = (float*)(base + 295174144ULL);           //  64 MiB fp32 (reuse T1)
    float*          PRAW  = (float*)(base + 530055168ULL);
    float*          NORM  = (float*)(base + 530120704ULL);
    float*          ATTN  = (float*)(base + 530122752ULL);
    short*          WREP_HO  = (short*)(base + 530130944ULL);
    short*          WREP_HC1 = (short*)(base + 530352128ULL);

    // 0. repack conv weights to bf16 [g][tap][icb][oc][8]
    k_repack<<<(3 * 36864 + 255) / 256, 256, 0, stream>>>(w_ho, WREP_HO, 3 * 36864);
    k_repack<<<(2 * 36864 + 255) / 256, 256, 0, stream>>>(w_hc1, WREP_HC1, 2 * 36864);
    // 1. DWT -> LL fp32 + tiled bf16 LH/HL/HH
    k_dwt_t<<<dim3(256, BN), 256, 0, stream>>>(x, LL, TILED);
    // 2. yh = relu(gconv3x3(LH,HL,HH; w_ho, groups=3))  [MFMA] -> bf16
    k_gconv3x3_mfma<<<dim3(256, 3, BN), 256, 0, stream>>>(TILED, (const bfx8*)WREP_HO, YH, 192);
    // 3. t1 = relu(gconv3x3(LH,HL; w_hc1, groups=2))    [MFMA] -> bf16
    k_gconv3x3_mfma<<<dim3(256, 2, BN), 256, 0, stream>>>(TILED, (const bfx8*)WREP_HC1, T1, 128);
    // 4. filter_hv = relu(1x1(t1, w_hc2)) -> fp32
    k_conv1x1<128, true, unsigned short, float><<<dim3(NP / 256, BN, 1), 256, 0, stream>>>(T1, w_hc2, FILT, 64);
    // 5. qkv0 = 1x1(LL, w_qkv) -> bf16
    k_conv1x1<64, false, float, unsigned short><<<dim3(NP / 256, BN, 3), 256, 0, stream>>>(LL, w_qkv, QKV0, 192);
    // 6. qkv = dw3x3(qkv0), v-channels scaled by (1+filter) -> bf16
    k_dwconv<<<dim3(NP / 256, BN * 192), 256, 0, stream>>>(QKV0, w_dw, FILT, QKV);
    // 7. q,k row norms
    k_norms<<<BN * 128, 256, 0, stream>>>(QKV, NORM);
    // 8-9. attention scores + softmax
    k_attn_dot<<<dim3(32, 8), 256, 0, stream>>>(QKV, PRAW);
    k_attn_soft<<<32, 64, 0, stream>>>(PRAW, NORM, temp, ATTN);
    // 10. out = attn*v, fused 1x1 proj -> fp32
    k_attnout_proj<<<dim3(NP / 256, BN), 256, 0, stream>>>(QKV, ATTN, w_proj, PROJ);
    // 11. IDWT -> fp32 out
    k_idwt<<<(BN * DIM * NP) / 256, 256, 0, stream>>>(PROJ, YH, out);
}

// Round 5
// 909.742 us; speedup vs baseline: 3.0458x; 1.4583x over previous
//
#include <hip/hip_runtime.h>
#include <hip/hip_bf16.h>

#define BN 4
#define DIM 64
#define NHEADS 8
#define HH 256
#define WH 256
#define NP (HH*WH)      // 65536
#define HF 512
#define WF 512

#define PD 258                       // padded dim
#define PROW (PD*64)                 // shorts per padded row
#define PPLANE ((size_t)PD*PD*64)    // shorts per padded plane

typedef __attribute__((ext_vector_type(8))) short bfx8;           // 8 bf16
typedef __attribute__((ext_vector_type(8))) unsigned short u16x8; // 8 bf16 bits
typedef __attribute__((ext_vector_type(4))) float f32x4;          // MFMA C/D frag

static __device__ __forceinline__ short f2bf(float f) {
    unsigned u = __float_as_uint(f);
    unsigned r = (u + 0x7FFFu + ((u >> 16) & 1u)) >> 16;   // RNE
    return (short)r;
}
static __device__ __forceinline__ float bfu(unsigned short u) {
    return __uint_as_float((unsigned)u << 16);
}
static __device__ __forceinline__ float ldf(const float* p) { return *p; }
static __device__ __forceinline__ float ldf(const unsigned short* p) { return bfu(*p); }
static __device__ __forceinline__ void stf(float* p, float v) { *p = v; }
static __device__ __forceinline__ void stf(unsigned short* p, float v) {
    *p = (unsigned short)f2bf(v);
}

// ---------------- zero the pad ring of the tiled planes ----------------
__global__ __launch_bounds__(256) void k_ring(unsigned short* __restrict__ tiled) {
    int plane = blockIdx.x;          // 12 = BN*3
    char* base = (char*)(tiled + (size_t)plane * PPLANE);
    const int ROWB = PROW * 2;       // 33024 bytes
    for (int k = threadIdx.x; k < 8224; k += 256) {
        char* dst;
        if (k < 2064) dst = base + (size_t)k * 16;                            // row 0
        else if (k < 4128) dst = base + (size_t)257 * ROWB + (size_t)(k - 2064) * 16; // row 257
        else if (k < 6176) { int r = (k - 4128) >> 3, s = (k - 4128) & 7;     // col 0
            dst = base + (size_t)(r + 1) * ROWB + (size_t)s * 16; }
        else { int r = (k - 6176) >> 3, s = (k - 6176) & 7;                   // col 257
            dst = base + (size_t)(r + 1) * ROWB + 257 * 128 + (size_t)s * 16; }
        *(uint4*)dst = (uint4){0, 0, 0, 0};
    }
}

// ---------------- DWT -> LL fp32 [ic][px] + LH/HL/HH bf16 padded-swizzled [y][x][ic] ----------------
// block: 8x16 px patch x 64 ic. LDS 48 KB -> 3 blocks/CU.
__global__ __launch_bounds__(256) void k_dwt(const float* __restrict__ x,
                                             float* __restrict__ LL,
                                             unsigned short* __restrict__ tiled) {
    __shared__ unsigned short lds[3 * 128 * 64] __attribute__((aligned(16)));
    const int tid = threadIdx.x;
    const int pid = blockIdx.x;              // 512 = 32 y-patches x 16 x-patches
    const int b = blockIdx.y;
    const int y0 = (pid >> 4) * 8, x0 = (pid & 15) * 16;
    const int quad = tid & 127;
    const int qy = quad >> 4, qx = quad & 15;
    const int gy = y0 + qy, gx = x0 + qx;
    const int ich = tid >> 7;                // 0/1

#pragma unroll 4
    for (int it = 0; it < 16; ++it) {
        int ic = it * 4 + ich * 2;           // handle ic, ic+1 (pair => b32 LDS writes)
        unsigned g = (((unsigned)(ic >> 3)) + (unsigned)gx + 2u * (unsigned)gy) & 7u;
        unsigned swz = (unsigned)quad * 64 + (g << 3) + (unsigned)(ic & 7);  // even
        unsigned pk[3];
#pragma unroll
        for (int s = 0; s < 2; ++s) {
            const float* px = x + (((size_t)(b * 64 + ic + s) * HF) + 2 * gy) * WF + 2 * gx;
            float2 e0 = *(const float2*)px;
            float2 e1 = *(const float2*)(px + WF);
            float a = e0.x, bb = e0.y, c = e1.x, d = e1.y;
            LL[(size_t)(b * 64 + ic + s) * NP + (size_t)gy * WH + gx] = (a + bb + c + d) * 0.5f;
            unsigned lh = (unsigned short)f2bf((-a - bb + c + d) * 0.5f);
            unsigned hl = (unsigned short)f2bf((-a + bb - c + d) * 0.5f);
            unsigned hh = (unsigned short)f2bf(( a - bb - c + d) * 0.5f);
            if (s == 0) { pk[0] = lh; pk[1] = hl; pk[2] = hh; }
            else { pk[0] |= lh << 16; pk[1] |= hl << 16; pk[2] |= hh << 16; }
        }
        *(unsigned*)&lds[swz]          = pk[0];
        *(unsigned*)&lds[8192 + swz]   = pk[1];
        *(unsigned*)&lds[16384 + swz]  = pk[2];
    }
    __syncthreads();
    // linear LDS -> padded global rows (swizzle baked in)
#pragma unroll
    for (int it = 0; it < 12; ++it) {
        int cch = tid + it * 256;            // 0..3071 (uint4 chunks)
        int p = cch >> 10, rem = cch & 1023;
        int row = rem >> 7, col = rem & 127;
        unsigned short* dst = tiled + ((size_t)(b * 3 + p) * PD + (y0 + row + 1)) * PROW
                                    + (size_t)(x0 + 1) * 64 + (size_t)col * 8;
        *(uint4*)dst = *(const uint4*)((const char*)lds + (size_t)cch * 16);
    }
}

// ---------------- weight repack: OIHW fp32 -> [g][tap][icb][oc][8] bf16 ----------------
__global__ __launch_bounds__(256) void k_repack(const float* __restrict__ w,
                                                short* __restrict__ wrep, int total) {
    int t = blockIdx.x * 256 + threadIdx.x;
    if (t >= total) return;
    unsigned g   = (unsigned)t / 36864u;
    unsigned r1  = (unsigned)t % 36864u;
    unsigned tap = r1 / 4096u;
    unsigned r2  = r1 % 4096u;
    unsigned icb = r2 / 512u;
    unsigned r3  = r2 % 512u;
    unsigned oc  = r3 >> 3;
    unsigned j   = r3 & 7u;
    unsigned ic  = icb * 8u + j;
    wrep[t] = f2bf(w[(((size_t)g * 64 + oc) * 64 + ic) * 9 + tap]);
}

// ---------------- grouped 3x3 conv (+relu) via bf16 MFMA, padded-layout input ----------------
// grid: (256 tiles, G groups, BN). block 256 = 4 waves. out bf16 [b][OC][px].
__global__ __launch_bounds__(256) void k_gconv3x3_mfma(const unsigned short* __restrict__ tiled,
                                                       const bfx8* __restrict__ wr,
                                                       unsigned short* __restrict__ out, int OC) {
    __shared__ short lds_in[324 * 64] __attribute__((aligned(16)));
    const int tid = threadIdx.x;
    const int l = tid & 63, wv = tid >> 6;
    const int tile = blockIdx.x;
    const int x0 = (tile & 15) * 16, y0 = (tile >> 4) * 16;
    const int g = blockIdx.y, b = blockIdx.z;
    const unsigned short* src = tiled + (size_t)(b * 3 + g) * PPLANE;

    // stage 18 rows x 2304 B (contiguous each): 2592 uint4 chunks
#pragma unroll
    for (int it = 0; it < 10; ++it) {
        int cch = it * 256 + tid;
        unsigned row = (unsigned)cch / 144u, col = (unsigned)cch % 144u;
        const unsigned short* ga = src + (size_t)(y0 + row) * PROW + (size_t)x0 * 64 + (size_t)col * 8;
        __builtin_amdgcn_global_load_lds(
            (const __attribute__((address_space(1))) void*)ga,
            (__attribute__((address_space(3))) void*)((char*)lds_in + (size_t)(it * 256 + wv * 64) * 16),
            16, 0, 0);
    }
    if (tid < 32) {
        int cch = 2560 + tid;
        unsigned row = (unsigned)cch / 144u, col = (unsigned)cch % 144u;
        const unsigned short* ga = src + (size_t)(y0 + row) * PROW + (size_t)x0 * 64 + (size_t)col * 8;
        *(uint4*)((char*)lds_in + (size_t)cch * 16) = *(const uint4*)ga;
    }
    __syncthreads();

    f32x4 acc[4][4];
#pragma unroll
    for (int i = 0; i < 4; ++i)
#pragma unroll
        for (int j = 0; j < 4; ++j) acc[i][j] = (f32x4){0.f, 0.f, 0.f, 0.f};

    const int lx = l & 15, lq = l >> 4;
#pragma unroll
    for (int c = 0; c < 2; ++c) {
        const int icb = c * 4 + lq;
#pragma unroll
        for (int tap = 0; tap < 9; ++tap) {
            const int dy = tap / 3, dx = tap % 3;
            const size_t wbase = ((size_t)(g * 9 + tap) * 8 + icb) * 64 + lx;
            bfx8 b0 = wr[wbase];
            bfx8 b1 = wr[wbase + 16];
            bfx8 b2 = wr[wbase + 32];
            bfx8 b3 = wr[wbase + 48];
#pragma unroll
            for (int pg = 0; pg < 4; ++pg) {
                int hy = wv * 4 + pg + dy, hx = lx + dx;
                int hp = hy * 18 + hx;
                const bfx8* ap = (const bfx8*)&lds_in[hp * 64 + (((icb + hx + 2 * hy + 5) & 7) << 3)];
                bfx8 a = *ap;
                acc[pg][0] = __builtin_amdgcn_mfma_f32_16x16x32_bf16(a, b0, acc[pg][0], 0, 0, 0);
                acc[pg][1] = __builtin_amdgcn_mfma_f32_16x16x32_bf16(a, b1, acc[pg][1], 0, 0, 0);
                acc[pg][2] = __builtin_amdgcn_mfma_f32_16x16x32_bf16(a, b2, acc[pg][2], 0, 0, 0);
                acc[pg][3] = __builtin_amdgcn_mfma_f32_16x16x32_bf16(a, b3, acc[pg][3], 0, 0, 0);
            }
        }
    }

#pragma unroll
    for (int pg = 0; pg < 4; ++pg) {
#pragma unroll
        for (int ocg = 0; ocg < 4; ++ocg) {
            unsigned short* op = out + ((size_t)b * OC + g * 64 + ocg * 16 + lx) * NP
                                     + (size_t)(y0 + wv * 4 + pg) * WH + x0 + lq * 4;
            f32x4 v = acc[pg][ocg];
            ushort4 s4;
            s4.x = (unsigned short)f2bf(fmaxf(v.x, 0.f));
            s4.y = (unsigned short)f2bf(fmaxf(v.y, 0.f));
            s4.z = (unsigned short)f2bf(fmaxf(v.z, 0.f));
            s4.w = (unsigned short)f2bf(fmaxf(v.w, 0.f));
            *(ushort4*)op = s4;
        }
    }
}

// ---------------- 1x1 conv, 64-out chunk ----------------
template <int CIN, bool RELU, typename IT, typename OT>
__global__ __launch_bounds__(256) void k_conv1x1(const IT* __restrict__ in,
                                                 const float* __restrict__ w,
                                                 OT* __restrict__ out, int OCtot) {
    int p = blockIdx.x * 256 + threadIdx.x;
    int b = blockIdx.y;
    int oc0 = blockIdx.z * 64;
    float acc[64];
#pragma unroll
    for (int o = 0; o < 64; ++o) acc[o] = 0.f;
    const IT* inp = in + (size_t)b * CIN * NP + p;
    const float* wb = w + (size_t)oc0 * CIN;
    for (int ic = 0; ic < CIN; ++ic) {
        float v = ldf(inp + (size_t)ic * NP);
#pragma unroll
        for (int o = 0; o < 64; ++o) acc[o] = fmaf(v, wb[(size_t)o * CIN + ic], acc[o]);
    }
    OT* op = out + ((size_t)b * OCtot + oc0) * NP + p;
#pragma unroll
    for (int o = 0; o < 64; ++o) {
        float r = acc[o];
        if (RELU) r = fmaxf(r, 0.f);
        stf(op + (size_t)o * NP, r);
    }
}

// ---------------- depthwise 3x3 + fused v-filter, vectorized 8 px/thread ----------------
__global__ __launch_bounds__(256) void k_dwconv(const unsigned short* __restrict__ in,
                                                const float* __restrict__ w,
                                                const float* __restrict__ filt,
                                                unsigned short* __restrict__ out) {
    int p8 = blockIdx.x * 256 + threadIdx.x;   // grid.x = NP/2048 = 32
    int bc = blockIdx.y;                       // 0..BN*192
    int c = bc % 192, b = bc / 192;
    int y = p8 >> 5, x0 = (p8 & 31) * 8;
    const unsigned short* ip = in + (size_t)bc * NP;
    float wv[9];
#pragma unroll
    for (int t = 0; t < 9; ++t) wv[t] = w[c * 9 + t];

    float f[3][10];
#pragma unroll
    for (int r = 0; r < 3; ++r) {
        int yy = y + r - 1;
        if (yy < 0 || yy >= HH) {
#pragma unroll
            for (int k = 0; k < 10; ++k) f[r][k] = 0.f;
        } else {
            const unsigned short* rp = ip + (size_t)yy * WH;
            u16x8 C = *(const u16x8*)(rp + x0);
#pragma unroll
            for (int k = 0; k < 8; ++k) f[r][k + 1] = bfu(C[k]);
            f[r][0] = (x0 > 0) ? bfu(rp[x0 - 1]) : 0.f;
            f[r][9] = (x0 < 248) ? bfu(rp[x0 + 8]) : 0.f;
        }
    }
    float o[8];
#pragma unroll
    for (int k = 0; k < 8; ++k) {
        float s = 0.f;
#pragma unroll
        for (int r = 0; r < 3; ++r)
#pragma unroll
            for (int dx = 0; dx < 3; ++dx)
                s = fmaf(f[r][k + dx], wv[r * 3 + dx], s);
        o[k] = s;
    }
    if (c >= 128) {
        const float* fp = filt + ((size_t)b * 64 + (c - 128)) * NP + (size_t)y * WH + x0;
        float4 f0 = *(const float4*)fp;
        float4 f1 = *(const float4*)(fp + 4);
        o[0] = fmaf(o[0], f0.x, o[0]); o[1] = fmaf(o[1], f0.y, o[1]);
        o[2] = fmaf(o[2], f0.z, o[2]); o[3] = fmaf(o[3], f0.w, o[3]);
        o[4] = fmaf(o[4], f1.x, o[4]); o[5] = fmaf(o[5], f1.y, o[5]);
        o[6] = fmaf(o[6], f1.z, o[6]); o[7] = fmaf(o[7], f1.w, o[7]);
    }
    u16x8 s8;
#pragma unroll
    for (int k = 0; k < 8; ++k) s8[k] = (unsigned short)f2bf(o[k]);
    *(u16x8*)(out + (size_t)bc * NP + (size_t)y * WH + x0) = s8;
}

// ---------------- row L2 norms for q,k (vectorized) ----------------
__global__ __launch_bounds__(256) void k_norms(const unsigned short* __restrict__ qkv,
                                               float* __restrict__ norms) {
    int bx = blockIdx.x;                 // [0, BN*128): c<64 => q, else k
    int b = bx >> 7, c = bx & 127;
    const unsigned short* row = qkv + ((size_t)b * 192 + c) * NP;
    float s = 0.f;
    for (int i = threadIdx.x * 8; i < NP; i += 2048) {
        u16x8 v8 = *(const u16x8*)(row + i);
#pragma unroll
        for (int k = 0; k < 8; ++k) {
            float v = bfu(v8[k]);
            s = fmaf(v, v, s);
        }
    }
#pragma unroll
    for (int off = 32; off; off >>= 1) s += __shfl_down(s, off);
    __shared__ float wsum[4];
    if ((threadIdx.x & 63) == 0) wsum[threadIdx.x >> 6] = s;
    __syncthreads();
    if (threadIdx.x == 0)
        norms[bx] = fmaxf(sqrtf(wsum[0] + wsum[1] + wsum[2] + wsum[3]), 1e-12f);
}

// ---------------- attention dots (stage 1, split over n) ----------------
__global__ __launch_bounds__(256) void k_attn_dot(const unsigned short* __restrict__ qkv,
                                                  float* __restrict__ praw) {
    int bhd = blockIdx.x, sp = blockIdx.y;   // grid (32, 8)
    int b = bhd >> 3, hd = bhd & 7;
    const unsigned short* qb = qkv + ((size_t)b * 192 + hd * 8) * NP;
    const unsigned short* kb = qkv + ((size_t)b * 192 + 64 + hd * 8) * NP;
    float acc[64];
#pragma unroll
    for (int i = 0; i < 64; ++i) acc[i] = 0.f;
    int n0 = sp * (NP / 8);
    for (int n = n0 + threadIdx.x; n < n0 + NP / 8; n += 256) {
        float qv[8], kv[8];
#pragma unroll
        for (int c2 = 0; c2 < 8; ++c2) qv[c2] = ldf(qb + (size_t)c2 * NP + n);
#pragma unroll
        for (int d2 = 0; d2 < 8; ++d2) kv[d2] = ldf(kb + (size_t)d2 * NP + n);
#pragma unroll
        for (int c2 = 0; c2 < 8; ++c2)
#pragma unroll
            for (int d2 = 0; d2 < 8; ++d2)
                acc[c2 * 8 + d2] = fmaf(qv[c2], kv[d2], acc[c2 * 8 + d2]);
    }
    __shared__ float red[4][64];
#pragma unroll
    for (int i = 0; i < 64; ++i) {
        float v = acc[i];
#pragma unroll
        for (int off = 32; off; off >>= 1) v += __shfl_down(v, off);
        if ((threadIdx.x & 63) == 0) red[threadIdx.x >> 6][i] = v;
    }
    __syncthreads();
    if (threadIdx.x < 64)
        praw[((size_t)sp * 32 + bhd) * 64 + threadIdx.x] =
            red[0][threadIdx.x] + red[1][threadIdx.x] + red[2][threadIdx.x] + red[3][threadIdx.x];
}

// ---------------- scale + softmax (stage 2) ----------------
__global__ __launch_bounds__(64) void k_attn_soft(const float* __restrict__ praw,
                                                  const float* __restrict__ norms,
                                                  const float* __restrict__ temp,
                                                  float* __restrict__ attn) {
    int bhd = blockIdx.x;                // 32 blocks, 64 threads
    int b = bhd >> 3, hd = bhd & 7;
    int t = threadIdx.x, c = t >> 3, d = t & 7;
    float s = 0.f;
    for (int sp = 0; sp < 8; ++sp) s += praw[((size_t)sp * 32 + bhd) * 64 + t];
    float nq = norms[b * 128 + hd * 8 + c];
    float nk = norms[b * 128 + 64 + hd * 8 + d];
    s = s / (nq * nk) * temp[hd];
    __shared__ float sm[64];
    __shared__ float se[64];
    sm[t] = s;
    __syncthreads();
    float mx = -1e30f;
#pragma unroll
    for (int dd = 0; dd < 8; ++dd) mx = fmaxf(mx, sm[c * 8 + dd]);
    float e = __expf(s - mx);
    se[t] = e;
    __syncthreads();
    float sum = 0.f;
#pragma unroll
    for (int dd = 0; dd < 8; ++dd) sum += se[c * 8 + dd];
    attn[(size_t)bhd * 64 + t] = e / sum;
}

// ---------------- attn*v fused with 1x1 proj ----------------
__global__ __launch_bounds__(256) void k_attnout_proj(const unsigned short* __restrict__ qkv,
                                                      const float* __restrict__ attn,
                                                      const float* __restrict__ wproj,
                                                      float* __restrict__ proj) {
    int p = blockIdx.x * 256 + threadIdx.x;
    int b = blockIdx.y;
    float o64[64];
    const unsigned short* vb = qkv + ((size_t)b * 192 + 128) * NP + p;
#pragma unroll
    for (int hd = 0; hd < 8; ++hd) {
        float vv[8];
#pragma unroll
        for (int d = 0; d < 8; ++d) vv[d] = ldf(vb + (size_t)(hd * 8 + d) * NP);
        const float* A = attn + (size_t)(b * 8 + hd) * 64;
#pragma unroll
        for (int c2 = 0; c2 < 8; ++c2) {
            float s = 0.f;
#pragma unroll
            for (int d = 0; d < 8; ++d) s = fmaf(A[c2 * 8 + d], vv[d], s);
            o64[hd * 8 + c2] = s;
        }
    }
    float* op = proj + (size_t)b * DIM * NP + p;
    for (int oc = 0; oc < 64; ++oc) {
        float s = 0.f;
#pragma unroll
        for (int ic = 0; ic < 64; ++ic) s = fmaf(o64[ic], wproj[(size_t)oc * 64 + ic], s);
        op[(size_t)oc * NP] = s;
    }
}

// ---------------- IDWT (vectorized 8 half-px / thread) + fp32 store ----------------
__global__ __launch_bounds__(256) void k_idwt(const float* __restrict__ ll,
                                              const unsigned short* __restrict__ yh,
                                              float* __restrict__ out) {
    int t = blockIdx.x * 256 + threadIdx.x;    // over BN*DIM*NP/8
    int j8 = t & 31;
    int i  = (t >> 5) & 255;
    int bc = t >> 13;
    int b = bc >> 6, c = bc & 63;
    size_t sp = (size_t)i * WH + j8 * 8;
    float la[8];
    const float4* llp = (const float4*)(ll + (size_t)bc * NP + sp);
    *(float4*)&la[0] = llp[0];
    *(float4*)&la[4] = llp[1];
    u16x8 lh8 = *(const u16x8*)(yh + ((size_t)b * 192 + c) * NP + sp);
    u16x8 hl8 = *(const u16x8*)(yh + ((size_t)b * 192 + 64 + c) * NP + sp);
    u16x8 hh8 = *(const u16x8*)(yh + ((size_t)b * 192 + 128 + c) * NP + sp);
    float e0[16], e1[16];
#pragma unroll
    for (int k = 0; k < 8; ++k) {
        float LLv = la[k];
        float LHv = bfu(lh8[k]);
        float HLv = bfu(hl8[k]);
        float HHv = bfu(hh8[k]);
        e0[2 * k]     = (LLv - LHv - HLv + HHv) * 0.5f;
        e0[2 * k + 1] = (LLv - LHv + HLv - HHv) * 0.5f;
        e1[2 * k]     = (LLv + LHv - HLv - HHv) * 0.5f;
        e1[2 * k + 1] = (LLv + LHv + HLv + HHv) * 0.5f;
    }
    float* o0 = out + (size_t)bc * HF * WF + (size_t)(2 * i) * WF + j8 * 16;
    float* o1 = o0 + WF;
#pragma unroll
    for (int q = 0; q < 4; ++q) {
        *(float4*)(o0 + 4 * q) = *(const float4*)&e0[4 * q];
        *(float4*)(o1 + 4 * q) = *(const float4*)&e1[4 * q];
    }
}

extern "C" void kernel_launch(void* const* d_in, const int* in_sizes, int n_in,
                              void* d_out, int out_size, void* d_ws, size_t ws_size,
                              hipStream_t stream) {
    const float* x      = (const float*)d_in[0];
    const float* w_hc1  = (const float*)d_in[1];
    const float* w_hc2  = (const float*)d_in[2];
    const float* w_ho   = (const float*)d_in[3];
    const float* w_qkv  = (const float*)d_in[4];
    const float* w_dw   = (const float*)d_in[5];
    const float* w_proj = (const float*)d_in[6];
    const float* temp   = (const float*)d_in[7];
    float* out = (float*)d_out;

    char* base = (char*)d_ws;
    float*          LL    = (float*)(base + 0);                      //  64 MiB fp32
    unsigned short* TILED = (unsigned short*)(base + 67108864ULL);   // 102.2 MB padded bf16
    unsigned short* YH    = (unsigned short*)(base + 194510848ULL);  //  96 MiB bf16 [b][192][px]
    unsigned short* T1    = (unsigned short*)(base + 295174144ULL);  //  64 MiB bf16 [b][128][px]
    float*          FILT  = (float*)(base + 362283008ULL);           //  64 MiB fp32 [b][64][px]
    unsigned short* QKV0  = (unsigned short*)(base + 429391872ULL);  //  96 MiB bf16 [b][192][px]
    unsigned short* QKV   = (unsigned short*)(base + 0);             //  96 MiB bf16 (reuse LL+TILED)
    float*          PROJ  = (float*)(base + 295174144ULL);           //  64 MiB fp32 (reuse T1)
    float*          PRAW  = (float*)(base + 530055168ULL);
    float*          NORM  = (float*)(base + 530120704ULL);
    float*          ATTN  = (float*)(base + 530122752ULL);
    short*          WREP_HO  = (short*)(base + 530130944ULL);
    short*          WREP_HC1 = (short*)(base + 530352128ULL);

    // 0. pad-ring zero + weight repack
    k_ring<<<12, 256, 0, stream>>>(TILED);
    k_repack<<<(3 * 36864 + 255) / 256, 256, 0, stream>>>(w_ho, WREP_HO, 3 * 36864);
    k_repack<<<(2 * 36864 + 255) / 256, 256, 0, stream>>>(w_hc1, WREP_HC1, 2 * 36864);
    // 1. DWT -> LL fp32 + padded-swizzled bf16 LH/HL/HH
    k_dwt<<<dim3(512, BN), 256, 0, stream>>>(x, LL, TILED);
    // 2. yh = relu(gconv3x3(LH,HL,HH; w_ho, groups=3))  [MFMA] -> bf16
    k_gconv3x3_mfma<<<dim3(256, 3, BN), 256, 0, stream>>>(TILED, (const bfx8*)WREP_HO, YH, 192);
    // 3. t1 = relu(gconv3x3(LH,HL; w_hc1, groups=2))    [MFMA] -> bf16
    k_gconv3x3_mfma<<<dim3(256, 2, BN), 256, 0, stream>>>(TILED, (const bfx8*)WREP_HC1, T1, 128);
    // 4. filter_hv = relu(1x1(t1, w_hc2)) -> fp32
    k_conv1x1<128, true, unsigned short, float><<<dim3(NP / 256, BN, 1), 256, 0, stream>>>(T1, w_hc2, FILT, 64);
    // 5. qkv0 = 1x1(LL, w_qkv) -> bf16
    k_conv1x1<64, false, float, unsigned short><<<dim3(NP / 256, BN, 3), 256, 0, stream>>>(LL, w_qkv, QKV0, 192);
    // 6. qkv = dw3x3(qkv0), v-channels scaled by (1+filter) -> bf16
    k_dwconv<<<dim3(32, BN * 192), 256, 0, stream>>>(QKV0, w_dw, FILT, QKV);
    // 7. q,k row norms
    k_norms<<<BN * 128, 256, 0, stream>>>(QKV, NORM);
    // 8-9. attention scores + softmax
    k_attn_dot<<<dim3(32, 8), 256, 0, stream>>>(QKV, PRAW);
    k_attn_soft<<<32, 64, 0, stream>>>(PRAW, NORM, temp, ATTN);
    // 10. out = attn*v, fused 1x1 proj -> fp32
    k_attnout_proj<<<dim3(NP / 256, BN), 256, 0, stream>>>(QKV, ATTN, w_proj, PROJ);
    // 11. IDWT -> fp32 out
    k_idwt<<<8192, 256, 0, stream>>>(PROJ, YH, out);
}

// Round 6
// 642.517 us; speedup vs baseline: 4.3125x; 1.4159x over previous
//
#include <hip/hip_runtime.h>
#include <hip/hip_bf16.h>

#define BN 4
#define DIM 64
#define NHEADS 8
#define HH 256
#define WH 256
#define NP (HH*WH)      // 65536
#define HF 512
#define WF 512

#define PD 258                       // padded dim
#define PROW (PD*64)                 // shorts per padded row
#define PPLANE ((size_t)PD*PD*64)    // shorts per padded plane

typedef __attribute__((ext_vector_type(8))) short bfx8;           // 8 bf16
typedef __attribute__((ext_vector_type(8))) unsigned short u16x8; // 8 bf16 bits
typedef __attribute__((ext_vector_type(4))) float f32x4;          // MFMA C/D frag

static __device__ __forceinline__ short f2bf(float f) {
    unsigned u = __float_as_uint(f);
    unsigned r = (u + 0x7FFFu + ((u >> 16) & 1u)) >> 16;   // RNE
    return (short)r;
}
static __device__ __forceinline__ float bfu(unsigned short u) {
    return __uint_as_float((unsigned)u << 16);
}

// ---------------- zero the pad ring of the tiled planes ----------------
__global__ __launch_bounds__(256) void k_ring(unsigned short* __restrict__ tiled) {
    int plane = blockIdx.x;          // 12 = BN*3
    char* base = (char*)(tiled + (size_t)plane * PPLANE);
    const int ROWB = PROW * 2;       // 33024 bytes
    for (int k = threadIdx.x; k < 8224; k += 256) {
        char* dst;
        if (k < 2064) dst = base + (size_t)k * 16;                            // row 0
        else if (k < 4128) dst = base + (size_t)257 * ROWB + (size_t)(k - 2064) * 16; // row 257
        else if (k < 6176) { int r = (k - 4128) >> 3, s = (k - 4128) & 7;     // col 0
            dst = base + (size_t)(r + 1) * ROWB + (size_t)s * 16; }
        else { int r = (k - 6176) >> 3, s = (k - 6176) & 7;                   // col 257
            dst = base + (size_t)(r + 1) * ROWB + 257 * 128 + (size_t)s * 16; }
        *(uint4*)dst = (uint4){0, 0, 0, 0};
    }
}

// ---------------- DWT -> LL bf16 tiled [b][tile][256][64swz] + LH/HL/HH padded bf16 ----------------
__global__ __launch_bounds__(256) void k_dwt(const float* __restrict__ x,
                                             unsigned short* __restrict__ LLT,
                                             unsigned short* __restrict__ tiled) {
    __shared__ unsigned short lds[3 * 128 * 64] __attribute__((aligned(16)));
    const int tid = threadIdx.x;
    const int pid = blockIdx.x;              // 512 = 32 y-patches x 16 x-patches
    const int b = blockIdx.y;
    const int y0 = (pid >> 4) * 8, x0 = (pid & 15) * 16;
    const int quad = tid & 127;
    const int qy = quad >> 4, qx = quad & 15;
    const int gy = y0 + qy, gx = x0 + qx;
    const int ich = tid >> 7;                // 0/1
    const int tile_ll = (y0 >> 4) * 16 + (x0 >> 4);      // block-uniform
    const int inner = ((gy & 15) << 4) + (gx & 15);
    unsigned short* llbase = LLT + ((size_t)(b * 256 + tile_ll) * 256 + inner) * 64;

#pragma unroll 4
    for (int it = 0; it < 16; ++it) {
        int ic = it * 4 + ich * 2;           // handle ic, ic+1 (pair => b32 writes)
        unsigned g = (((unsigned)(ic >> 3)) + (unsigned)gx + 2u * (unsigned)gy) & 7u;
        unsigned swz = (unsigned)quad * 64 + (g << 3) + (unsigned)(ic & 7);
        unsigned pk[3], pll;
#pragma unroll
        for (int s = 0; s < 2; ++s) {
            const float* px = x + (((size_t)(b * 64 + ic + s) * HF) + 2 * gy) * WF + 2 * gx;
            float2 e0 = *(const float2*)px;
            float2 e1 = *(const float2*)(px + WF);
            float a = e0.x, bb = e0.y, c = e1.x, d = e1.y;
            unsigned ll = (unsigned short)f2bf(( a + bb + c + d) * 0.5f);
            unsigned lh = (unsigned short)f2bf((-a - bb + c + d) * 0.5f);
            unsigned hl = (unsigned short)f2bf((-a + bb - c + d) * 0.5f);
            unsigned hh = (unsigned short)f2bf(( a - bb - c + d) * 0.5f);
            if (s == 0) { pll = ll; pk[0] = lh; pk[1] = hl; pk[2] = hh; }
            else { pll |= ll << 16; pk[0] |= lh << 16; pk[1] |= hl << 16; pk[2] |= hh << 16; }
        }
        *(unsigned*)&lds[swz]          = pk[0];
        *(unsigned*)&lds[8192 + swz]   = pk[1];
        *(unsigned*)&lds[16384 + swz]  = pk[2];
        unsigned gll = (((unsigned)(ic >> 3)) + (unsigned)inner) & 7u;
        *(unsigned*)&llbase[(gll << 3) + (unsigned)(ic & 7)] = pll;
    }
    __syncthreads();
#pragma unroll
    for (int it = 0; it < 12; ++it) {
        int cch = tid + it * 256;            // 0..3071 (uint4 chunks)
        int p = cch >> 10, rem = cch & 1023;
        int row = rem >> 7, col = rem & 127;
        unsigned short* dst = tiled + ((size_t)(b * 3 + p) * PD + (y0 + row + 1)) * PROW
                                    + (size_t)(x0 + 1) * 64 + (size_t)col * 8;
        *(uint4*)dst = *(const uint4*)((const char*)lds + (size_t)cch * 16);
    }
}

// ---------------- weight repack: OIHW fp32 -> [g][tap][icb][oc][8] bf16 (3x3) ----------------
__global__ __launch_bounds__(256) void k_repack(const float* __restrict__ w,
                                                short* __restrict__ wrep, int total) {
    int t = blockIdx.x * 256 + threadIdx.x;
    if (t >= total) return;
    unsigned g   = (unsigned)t / 36864u;
    unsigned r1  = (unsigned)t % 36864u;
    unsigned tap = r1 / 4096u;
    unsigned r2  = r1 % 4096u;
    unsigned icb = r2 / 512u;
    unsigned r3  = r2 % 512u;
    unsigned oc  = r3 >> 3;
    unsigned j   = r3 & 7u;
    unsigned ic  = icb * 8u + j;
    wrep[t] = f2bf(w[(((size_t)g * 64 + oc) * 64 + ic) * 9 + tap]);
}

// ---------------- weight repack 1x1: [OC][CIN] fp32 -> [oct][icb][oc16][8] bf16 ----------------
template <int CIN, int OC>
__global__ __launch_bounds__(256) void k_repack1(const float* __restrict__ w,
                                                 short* __restrict__ wrep) {
    int t = blockIdx.x * 256 + threadIdx.x;
    if (t >= CIN * OC) return;
    constexpr int KB = CIN / 8;
    int j = t & 7;
    int gr = t >> 3;
    int o16 = gr & 15;
    int X = gr >> 4;
    int icb = X % KB;
    int oct = X / KB;
    int oc = oct * 16 + o16, ic = icb * 8 + j;
    wrep[t] = f2bf(w[(size_t)oc * CIN + ic]);
}

// ---------------- grouped 3x3 conv (+relu) via bf16 MFMA ----------------
// LAYOUT 0: planar [b][OC][NP].  LAYOUT 1: tiled-interleaved [b][tile][256][128swz].
template <int LAYOUT>
__global__ __launch_bounds__(256) void k_gconv3x3_mfma(const unsigned short* __restrict__ tiled,
                                                       const bfx8* __restrict__ wr,
                                                       unsigned short* __restrict__ out, int OC) {
    __shared__ short lds_in[324 * 64] __attribute__((aligned(16)));
    const int tid = threadIdx.x;
    const int l = tid & 63, wv = tid >> 6;
    const int tile = blockIdx.x;
    const int x0 = (tile & 15) * 16, y0 = (tile >> 4) * 16;
    const int g = blockIdx.y, b = blockIdx.z;
    const unsigned short* src = tiled + (size_t)(b * 3 + g) * PPLANE;

#pragma unroll
    for (int it = 0; it < 10; ++it) {
        int cch = it * 256 + tid;
        unsigned row = (unsigned)cch / 144u, col = (unsigned)cch % 144u;
        const unsigned short* ga = src + (size_t)(y0 + row) * PROW + (size_t)x0 * 64 + (size_t)col * 8;
        __builtin_amdgcn_global_load_lds(
            (const __attribute__((address_space(1))) void*)ga,
            (__attribute__((address_space(3))) void*)((char*)lds_in + (size_t)(it * 256 + wv * 64) * 16),
            16, 0, 0);
    }
    if (tid < 32) {
        int cch = 2560 + tid;
        unsigned row = (unsigned)cch / 144u, col = (unsigned)cch % 144u;
        const unsigned short* ga = src + (size_t)(y0 + row) * PROW + (size_t)x0 * 64 + (size_t)col * 8;
        *(uint4*)((char*)lds_in + (size_t)cch * 16) = *(const uint4*)ga;
    }
    __syncthreads();

    f32x4 acc[4][4];
#pragma unroll
    for (int i = 0; i < 4; ++i)
#pragma unroll
        for (int j = 0; j < 4; ++j) acc[i][j] = (f32x4){0.f, 0.f, 0.f, 0.f};

    const int lx = l & 15, lq = l >> 4;
#pragma unroll
    for (int c = 0; c < 2; ++c) {
        const int icb = c * 4 + lq;
#pragma unroll
        for (int tap = 0; tap < 9; ++tap) {
            const int dy = tap / 3, dx = tap % 3;
            const size_t wbase = ((size_t)(g * 9 + tap) * 8 + icb) * 64 + lx;
            bfx8 b0 = wr[wbase];
            bfx8 b1 = wr[wbase + 16];
            bfx8 b2 = wr[wbase + 32];
            bfx8 b3 = wr[wbase + 48];
#pragma unroll
            for (int pg = 0; pg < 4; ++pg) {
                int hy = wv * 4 + pg + dy, hx = lx + dx;
                int hp = hy * 18 + hx;
                const bfx8* ap = (const bfx8*)&lds_in[hp * 64 + (((icb + hx + 2 * hy + 5) & 7) << 3)];
                bfx8 a = *ap;
                acc[pg][0] = __builtin_amdgcn_mfma_f32_16x16x32_bf16(a, b0, acc[pg][0], 0, 0, 0);
                acc[pg][1] = __builtin_amdgcn_mfma_f32_16x16x32_bf16(a, b1, acc[pg][1], 0, 0, 0);
                acc[pg][2] = __builtin_amdgcn_mfma_f32_16x16x32_bf16(a, b2, acc[pg][2], 0, 0, 0);
                acc[pg][3] = __builtin_amdgcn_mfma_f32_16x16x32_bf16(a, b3, acc[pg][3], 0, 0, 0);
            }
        }
    }

#pragma unroll
    for (int pg = 0; pg < 4; ++pg) {
#pragma unroll
        for (int ocg = 0; ocg < 4; ++ocg) {
            f32x4 v = acc[pg][ocg];
            if (LAYOUT == 0) {
                unsigned short* op = out + ((size_t)b * OC + g * 64 + ocg * 16 + lx) * NP
                                         + (size_t)(y0 + wv * 4 + pg) * WH + x0 + lq * 4;
                ushort4 s4;
                s4.x = (unsigned short)f2bf(fmaxf(v.x, 0.f));
                s4.y = (unsigned short)f2bf(fmaxf(v.y, 0.f));
                s4.z = (unsigned short)f2bf(fmaxf(v.z, 0.f));
                s4.w = (unsigned short)f2bf(fmaxf(v.w, 0.f));
                *(ushort4*)op = s4;
            } else {
                int icT = g * 64 + ocg * 16 + lx;
                int g16 = icT >> 3;
                unsigned short* tb = out + ((size_t)(b * 256 + tile) * 256) * 128;
                int innerb = (wv * 4 + pg) * 16 + lq * 4;
                float vr[4] = {v.x, v.y, v.z, v.w};
#pragma unroll
                for (int r = 0; r < 4; ++r) {
                    int inn = innerb + r;
                    tb[(size_t)inn * 128 + (((g16 + inn) & 15) << 3) + (icT & 7)] =
                        (unsigned short)f2bf(fmaxf(vr[r], 0.f));
                }
            }
        }
    }
}

// ---------------- 1x1 conv via bf16 MFMA from tiled input ----------------
// inT: [b][tile][256px][CIN swz] bf16. out: planar bf16 [b][OC][NP].
template <int CIN, int OC, bool RELU>
__global__ __launch_bounds__(256) void k_conv1x1_mfma(const unsigned short* __restrict__ inT,
                                                      const bfx8* __restrict__ wr,
                                                      unsigned short* __restrict__ out) {
    constexpr int KB = CIN / 8;          // 16B k-granules
    constexpr int KC = CIN / 32;         // MFMA K-chunks
    constexpr int NOCT = OC / 16;
    __shared__ short ldsA[256 * CIN] __attribute__((aligned(16)));
    const int tid = threadIdx.x;
    const int l = tid & 63, wv = tid >> 6;
    const int tile = blockIdx.x, b = blockIdx.y;
    const unsigned short* src = inT + ((size_t)(b * 256 + tile) * 256) * CIN;
    constexpr int ITER = (256 * CIN / 8) / 256;
#pragma unroll
    for (int it = 0; it < ITER; ++it) {
        int cc = it * 256 + tid;
        __builtin_amdgcn_global_load_lds(
            (const __attribute__((address_space(1))) void*)(src + (size_t)cc * 8),
            (__attribute__((address_space(3))) void*)((char*)ldsA + (size_t)(it * 256 + wv * 64) * 16),
            16, 0, 0);
    }
    __syncthreads();

    const int lx = l & 15, lq = l >> 4;
    const int x0 = (tile & 15) * 16, y0 = (tile >> 4) * 16;
#pragma unroll
    for (int o4 = 0; o4 < NOCT / 4; ++o4) {
        f32x4 acc[4][4];
#pragma unroll
        for (int i = 0; i < 4; ++i)
#pragma unroll
            for (int j = 0; j < 4; ++j) acc[i][j] = (f32x4){0.f, 0.f, 0.f, 0.f};
#pragma unroll
        for (int c = 0; c < KC; ++c) {
            const int icb = c * 4 + lq;
            bfx8 bf[4];
#pragma unroll
            for (int ot = 0; ot < 4; ++ot)
                bf[ot] = wr[(size_t)(((o4 * 4 + ot) * KB + icb) * 16) + lx];
#pragma unroll
            for (int pg = 0; pg < 4; ++pg) {
                int inner = (wv * 4 + pg) * 16 + lx;
                const bfx8* ap = (const bfx8*)&ldsA[inner * CIN + (((icb + inner) & (KB - 1)) << 3)];
                bfx8 a = *ap;
                acc[pg][0] = __builtin_amdgcn_mfma_f32_16x16x32_bf16(a, bf[0], acc[pg][0], 0, 0, 0);
                acc[pg][1] = __builtin_amdgcn_mfma_f32_16x16x32_bf16(a, bf[1], acc[pg][1], 0, 0, 0);
                acc[pg][2] = __builtin_amdgcn_mfma_f32_16x16x32_bf16(a, bf[2], acc[pg][2], 0, 0, 0);
                acc[pg][3] = __builtin_amdgcn_mfma_f32_16x16x32_bf16(a, bf[3], acc[pg][3], 0, 0, 0);
            }
        }
#pragma unroll
        for (int pg = 0; pg < 4; ++pg)
#pragma unroll
            for (int ot = 0; ot < 4; ++ot) {
                int oc = (o4 * 4 + ot) * 16 + lx;
                unsigned short* op = out + ((size_t)b * OC + oc) * NP
                                         + (size_t)(y0 + wv * 4 + pg) * WH + x0 + lq * 4;
                f32x4 v = acc[pg][ot];
                ushort4 s4;
                s4.x = (unsigned short)f2bf(RELU ? fmaxf(v.x, 0.f) : v.x);
                s4.y = (unsigned short)f2bf(RELU ? fmaxf(v.y, 0.f) : v.y);
                s4.z = (unsigned short)f2bf(RELU ? fmaxf(v.z, 0.f) : v.z);
                s4.w = (unsigned short)f2bf(RELU ? fmaxf(v.w, 0.f) : v.w);
                *(ushort4*)op = s4;
            }
    }
}

// ---------------- depthwise 3x3 + fused v-filter (bf16), 8 px/thread ----------------
__global__ __launch_bounds__(256) void k_dwconv(const unsigned short* __restrict__ in,
                                                const float* __restrict__ w,
                                                const unsigned short* __restrict__ filt,
                                                unsigned short* __restrict__ out) {
    int p8 = blockIdx.x * 256 + threadIdx.x;   // grid.x = 32
    int bc = blockIdx.y;                       // 0..BN*192
    int c = bc % 192, b = bc / 192;
    int y = p8 >> 5, x0 = (p8 & 31) * 8;
    const unsigned short* ip = in + (size_t)bc * NP;
    float wv[9];
#pragma unroll
    for (int t = 0; t < 9; ++t) wv[t] = w[c * 9 + t];

    float f[3][10];
#pragma unroll
    for (int r = 0; r < 3; ++r) {
        int yy = y + r - 1;
        if (yy < 0 || yy >= HH) {
#pragma unroll
            for (int k = 0; k < 10; ++k) f[r][k] = 0.f;
        } else {
            const unsigned short* rp = ip + (size_t)yy * WH;
            u16x8 C = *(const u16x8*)(rp + x0);
#pragma unroll
            for (int k = 0; k < 8; ++k) f[r][k + 1] = bfu(C[k]);
            f[r][0] = (x0 > 0) ? bfu(rp[x0 - 1]) : 0.f;
            f[r][9] = (x0 < 248) ? bfu(rp[x0 + 8]) : 0.f;
        }
    }
    float o[8];
#pragma unroll
    for (int k = 0; k < 8; ++k) {
        float s = 0.f;
#pragma unroll
        for (int r = 0; r < 3; ++r)
#pragma unroll
            for (int dx = 0; dx < 3; ++dx)
                s = fmaf(f[r][k + dx], wv[r * 3 + dx], s);
        o[k] = s;
    }
    if (c >= 128) {
        const unsigned short* fp = filt + ((size_t)b * 64 + (c - 128)) * NP + (size_t)y * WH + x0;
        u16x8 f8 = *(const u16x8*)fp;
#pragma unroll
        for (int k = 0; k < 8; ++k) o[k] = fmaf(o[k], bfu(f8[k]), o[k]);
    }
    u16x8 s8;
#pragma unroll
    for (int k = 0; k < 8; ++k) s8[k] = (unsigned short)f2bf(o[k]);
    *(u16x8*)(out + (size_t)bc * NP + (size_t)y * WH + x0) = s8;
}

// ---------------- attention dots + sum-of-squares (stage 1, split over n) ----------------
__global__ __launch_bounds__(256) void k_attn_dot(const unsigned short* __restrict__ qkv,
                                                  float* __restrict__ praw,
                                                  float* __restrict__ praw2) {
    int bhd = blockIdx.x, sp = blockIdx.y;   // grid (32, 8)
    int b = bhd >> 3, hd = bhd & 7;
    const unsigned short* qb = qkv + ((size_t)b * 192 + hd * 8) * NP;
    const unsigned short* kb = qkv + ((size_t)b * 192 + 64 + hd * 8) * NP;
    float acc[64], acc2[16];
#pragma unroll
    for (int i = 0; i < 64; ++i) acc[i] = 0.f;
#pragma unroll
    for (int i = 0; i < 16; ++i) acc2[i] = 0.f;
    int n0 = sp * (NP / 8);
    for (int n = n0 + threadIdx.x; n < n0 + NP / 8; n += 256) {
        float qv[8], kv[8];
#pragma unroll
        for (int c2 = 0; c2 < 8; ++c2) qv[c2] = bfu(qb[(size_t)c2 * NP + n]);
#pragma unroll
        for (int d2 = 0; d2 < 8; ++d2) kv[d2] = bfu(kb[(size_t)d2 * NP + n]);
#pragma unroll
        for (int c2 = 0; c2 < 8; ++c2) {
            acc2[c2] = fmaf(qv[c2], qv[c2], acc2[c2]);
#pragma unroll
            for (int d2 = 0; d2 < 8; ++d2)
                acc[c2 * 8 + d2] = fmaf(qv[c2], kv[d2], acc[c2 * 8 + d2]);
        }
#pragma unroll
        for (int d2 = 0; d2 < 8; ++d2) acc2[8 + d2] = fmaf(kv[d2], kv[d2], acc2[8 + d2]);
    }
    __shared__ float red[4][64];
#pragma unroll
    for (int i = 0; i < 64; ++i) {
        float v = acc[i];
#pragma unroll
        for (int off = 32; off; off >>= 1) v += __shfl_down(v, off);
        if ((threadIdx.x & 63) == 0) red[threadIdx.x >> 6][i] = v;
    }
    __syncthreads();
    if (threadIdx.x < 64)
        praw[((size_t)sp * 32 + bhd) * 64 + threadIdx.x] =
            red[0][threadIdx.x] + red[1][threadIdx.x] + red[2][threadIdx.x] + red[3][threadIdx.x];
    __syncthreads();
#pragma unroll
    for (int i = 0; i < 16; ++i) {
        float v = acc2[i];
#pragma unroll
        for (int off = 32; off; off >>= 1) v += __shfl_down(v, off);
        if ((threadIdx.x & 63) == 0) red[threadIdx.x >> 6][i] = v;
    }
    __syncthreads();
    if (threadIdx.x < 16)
        praw2[((size_t)sp * 32 + bhd) * 16 + threadIdx.x] =
            red[0][threadIdx.x] + red[1][threadIdx.x] + red[2][threadIdx.x] + red[3][threadIdx.x];
}

// ---------------- scale (incl. l2norm) + softmax (stage 2) ----------------
__global__ __launch_bounds__(64) void k_attn_soft(const float* __restrict__ praw,
                                                  const float* __restrict__ praw2,
                                                  const float* __restrict__ temp,
                                                  float* __restrict__ attn) {
    int bhd = blockIdx.x;                // 32 blocks, 64 threads
    int hd = bhd & 7;
    int t = threadIdx.x, c = t >> 3, d = t & 7;
    float s = 0.f, sq = 0.f, sk = 0.f;
    for (int sp = 0; sp < 8; ++sp) {
        s  += praw[((size_t)sp * 32 + bhd) * 64 + t];
        sq += praw2[((size_t)sp * 32 + bhd) * 16 + c];
        sk += praw2[((size_t)sp * 32 + bhd) * 16 + 8 + d];
    }
    float nq = fmaxf(sqrtf(sq), 1e-12f);
    float nk = fmaxf(sqrtf(sk), 1e-12f);
    s = s / (nq * nk) * temp[hd];
    __shared__ float sm[64];
    __shared__ float se[64];
    sm[t] = s;
    __syncthreads();
    float mx = -1e30f;
#pragma unroll
    for (int dd = 0; dd < 8; ++dd) mx = fmaxf(mx, sm[c * 8 + dd]);
    float e = __expf(s - mx);
    se[t] = e;
    __syncthreads();
    float sum = 0.f;
#pragma unroll
    for (int dd = 0; dd < 8; ++dd) sum += se[c * 8 + dd];
    attn[(size_t)bhd * 64 + t] = e / sum;
}

// ---------------- fused attn*v + 1x1 proj + IDWT -> fp32 out ----------------
__global__ __launch_bounds__(256) void k_attnout_idwt(const unsigned short* __restrict__ qkv,
                                                      const float* __restrict__ attn,
                                                      const float* __restrict__ wproj,
                                                      const unsigned short* __restrict__ yh,
                                                      float* __restrict__ out) {
    __shared__ float wsh[64 * 64];
    __shared__ float ash[512];
    const int tid = threadIdx.x;
    const int b = blockIdx.y;
    const int p = blockIdx.x * 256 + tid;
#pragma unroll
    for (int it = 0; it < 16; ++it) wsh[tid + it * 256] = wproj[tid + it * 256];
#pragma unroll
    for (int it = 0; it < 2; ++it) ash[tid + it * 256] = attn[(size_t)b * 512 + tid + it * 256];
    __syncthreads();

    float av[64];
    const unsigned short* vb = qkv + ((size_t)b * 192 + 128) * NP + p;
#pragma unroll
    for (int hd = 0; hd < 8; ++hd) {
        float vv[8];
#pragma unroll
        for (int d = 0; d < 8; ++d) vv[d] = bfu(vb[(size_t)(hd * 8 + d) * NP]);
#pragma unroll
        for (int c2 = 0; c2 < 8; ++c2) {
            float s = 0.f;
#pragma unroll
            for (int d = 0; d < 8; ++d) s = fmaf(ash[hd * 64 + c2 * 8 + d], vv[d], s);
            av[hd * 8 + c2] = s;
        }
    }
    const int i = p >> 8, j = p & 255;
    const unsigned short* yb = yh + (size_t)b * 192 * NP + p;
    float* ob = out + ((size_t)b * 64 * HF + 2 * i) * WF + 2 * j;
    for (int c = 0; c < 64; ++c) {          // runtime c: no dynamic reg indexing
        float s = 0.f;
#pragma unroll
        for (int ic = 0; ic < 64; ++ic) s = fmaf(av[ic], wsh[c * 64 + ic], s);
        float LHv = bfu(yb[(size_t)c * NP]);
        float HLv = bfu(yb[(size_t)(c + 64) * NP]);
        float HHv = bfu(yb[(size_t)(c + 128) * NP]);
        float* oc_ = ob + (size_t)c * HF * WF;
        *(float2*)oc_        = make_float2((s - LHv - HLv + HHv) * 0.5f, (s - LHv + HLv - HHv) * 0.5f);
        *(float2*)(oc_ + WF) = make_float2((s + LHv - HLv - HHv) * 0.5f, (s + LHv + HLv + HHv) * 0.5f);
    }
}

extern "C" void kernel_launch(void* const* d_in, const int* in_sizes, int n_in,
                              void* d_out, int out_size, void* d_ws, size_t ws_size,
                              hipStream_t stream) {
    const float* x      = (const float*)d_in[0];
    const float* w_hc1  = (const float*)d_in[1];
    const float* w_hc2  = (const float*)d_in[2];
    const float* w_ho   = (const float*)d_in[3];
    const float* w_qkv  = (const float*)d_in[4];
    const float* w_dw   = (const float*)d_in[5];
    const float* w_proj = (const float*)d_in[6];
    const float* temp   = (const float*)d_in[7];
    float* out = (float*)d_out;

    char* base = (char*)d_ws;
    unsigned short* TILED = (unsigned short*)(base + 0);             // 102.2 MB padded bf16
    unsigned short* LLT   = (unsigned short*)(base + 102242304ULL);  // 33.5 MB LL tiled bf16
    unsigned short* YH    = (unsigned short*)(base + 135796736ULL);  // 100.7 MB bf16 [b][192][NP]
    unsigned short* T1T   = (unsigned short*)(base + 236460032ULL);  // 67.1 MB bf16 tiled [..][128]
    unsigned short* FILT  = (unsigned short*)(base + 303568896ULL);  // 33.5 MB bf16 [b][64][NP]
    unsigned short* QKV0  = (unsigned short*)(base + 337123328ULL);  // 100.7 MB bf16 [b][192][NP]
    unsigned short* QKV   = (unsigned short*)(base + 437786624ULL);  // 100.7 MB bf16 [b][192][NP]
    float*          PRAW  = (float*)(base + 538449920ULL);           // 8*32*64
    float*          PRAW2 = (float*)(base + 538515456ULL);           // 8*32*16
    float*          ATTN  = (float*)(base + 538531840ULL);           // 32*64
    short* WREP_HO  = (short*)(base + 538540032ULL);                 // 110592
    short* WREP_HC1 = (short*)(base + 538761216ULL);                 // 73728
    short* WREP_HC2 = (short*)(base + 538908672ULL);                 // 8192
    short* WREP_QKV = (short*)(base + 538925056ULL);                 // 12288

    // 0. pad-ring zero + weight repacks
    k_ring<<<12, 256, 0, stream>>>(TILED);
    k_repack<<<(3 * 36864 + 255) / 256, 256, 0, stream>>>(w_ho, WREP_HO, 3 * 36864);
    k_repack<<<(2 * 36864 + 255) / 256, 256, 0, stream>>>(w_hc1, WREP_HC1, 2 * 36864);
    k_repack1<128, 64><<<32, 256, 0, stream>>>(w_hc2, WREP_HC2);
    k_repack1<64, 192><<<48, 256, 0, stream>>>(w_qkv, WREP_QKV);
    // 1. DWT -> LLT bf16 tiled + padded bf16 LH/HL/HH
    k_dwt<<<dim3(512, BN), 256, 0, stream>>>(x, LLT, TILED);
    // 2. yh = relu(gconv3x3(LH,HL,HH; w_ho, groups=3)) -> planar bf16
    k_gconv3x3_mfma<0><<<dim3(256, 3, BN), 256, 0, stream>>>(TILED, (const bfx8*)WREP_HO, YH, 192);
    // 3. t1 = relu(gconv3x3(LH,HL; w_hc1, groups=2)) -> tiled-interleaved bf16
    k_gconv3x3_mfma<1><<<dim3(256, 2, BN), 256, 0, stream>>>(TILED, (const bfx8*)WREP_HC1, T1T, 128);
    // 4. filter_hv = relu(1x1(t1, w_hc2)) -> planar bf16
    k_conv1x1_mfma<128, 64, true><<<dim3(256, BN), 256, 0, stream>>>(T1T, (const bfx8*)WREP_HC2, FILT);
    // 5. qkv0 = 1x1(LL, w_qkv) -> planar bf16
    k_conv1x1_mfma<64, 192, false><<<dim3(256, BN), 256, 0, stream>>>(LLT, (const bfx8*)WREP_QKV, QKV0);
    // 6. qkv = dw3x3(qkv0), v-channels scaled by (1+filter)
    k_dwconv<<<dim3(32, BN * 192), 256, 0, stream>>>(QKV0, w_dw, FILT, QKV);
    // 7-8. attention scores (+sumsq) + softmax (incl. l2norm)
    k_attn_dot<<<dim3(32, 8), 256, 0, stream>>>(QKV, PRAW, PRAW2);
    k_attn_soft<<<32, 64, 0, stream>>>(PRAW, PRAW2, temp, ATTN);
    // 9. fused attn*v + proj + IDWT -> fp32 out
    k_attnout_idwt<<<dim3(256, BN), 256, 0, stream>>>(QKV, ATTN, w_proj, YH, out);
}

// Round 7
// 613.477 us; speedup vs baseline: 4.5167x; 1.0473x over previous
//
#include <hip/hip_runtime.h>
#include <hip/hip_bf16.h>

#define BN 4
#define DIM 64
#define NHEADS 8
#define HH 256
#define WH 256
#define NP (HH*WH)      // 65536
#define HF 512
#define WF 512

#define PD 258                       // padded dim
#define PROW (PD*64)                 // shorts per padded row
#define PPLANE ((size_t)PD*PD*64)    // shorts per padded plane

typedef __attribute__((ext_vector_type(8))) short bfx8;           // 8 bf16
typedef __attribute__((ext_vector_type(8))) unsigned short u16x8; // 8 bf16 bits
typedef __attribute__((ext_vector_type(4))) float f32x4;          // MFMA C/D frag

static __device__ __forceinline__ short f2bf(float f) {
    unsigned u = __float_as_uint(f);
    unsigned r = (u + 0x7FFFu + ((u >> 16) & 1u)) >> 16;   // RNE
    return (short)r;
}
static __device__ __forceinline__ float bfu(unsigned short u) {
    return __uint_as_float((unsigned)u << 16);
}

// ---------------- merged setup: ring-zero 16 planes + all weight repacks ----------------
__global__ __launch_bounds__(256) void k_setup(unsigned short* __restrict__ tiled16,
                                               const float* __restrict__ w_ho,
                                               const float* __restrict__ w_hc1,
                                               const float* __restrict__ w_hc2,
                                               const float* __restrict__ w_qkv,
                                               short* __restrict__ wrHO,
                                               short* __restrict__ wrHC1,
                                               short* __restrict__ wrHC2,
                                               short* __restrict__ wrQKV) {
    int bx = blockIdx.x, tid = threadIdx.x;
    if (bx < 16) {                        // pad-ring zero, 16 planes (12 TILED + 4 LLP)
        char* base = (char*)(tiled16 + (size_t)bx * PPLANE);
        const int ROWB = PROW * 2;
        for (int k = tid; k < 8224; k += 256) {
            char* dst;
            if (k < 2064) dst = base + (size_t)k * 16;
            else if (k < 4128) dst = base + (size_t)257 * ROWB + (size_t)(k - 2064) * 16;
            else if (k < 6176) { int r = (k - 4128) >> 3, s = (k - 4128) & 7;
                dst = base + (size_t)(r + 1) * ROWB + (size_t)s * 16; }
            else { int r = (k - 6176) >> 3, s = (k - 6176) & 7;
                dst = base + (size_t)(r + 1) * ROWB + 257 * 128 + (size_t)s * 16; }
            *(uint4*)dst = (uint4){0, 0, 0, 0};
        }
        return;
    }
    if (bx < 16 + 432 + 288) {            // 3x3 repacks: OIHW -> [g][tap][icb][oc][8]
        const float* w = (bx < 448) ? w_ho : w_hc1;
        short* wrep = (bx < 448) ? wrHO : wrHC1;
        int t = (bx - ((bx < 448) ? 16 : 448)) * 256 + tid;
        unsigned g   = (unsigned)t / 36864u;
        unsigned r1  = (unsigned)t % 36864u;
        unsigned tap = r1 / 4096u;
        unsigned r2  = r1 % 4096u;
        unsigned icb = r2 / 512u;
        unsigned r3  = r2 % 512u;
        unsigned oc  = r3 >> 3;
        unsigned j   = r3 & 7u;
        wrep[t] = f2bf(w[(((size_t)g * 64 + oc) * 64 + icb * 8u + j) * 9 + tap]);
        return;
    }
    if (bx < 16 + 432 + 288 + 32) {       // w_hc2 [64][128] -> [oct][icb][oc16][8]
        int t = (bx - 736) * 256 + tid;
        int j = t & 7, gr = t >> 3, o16 = gr & 15, X = gr >> 4;
        int icb = X % 16, oct = X / 16;
        wrHC2[t] = f2bf(w_hc2[(size_t)(oct * 16 + o16) * 128 + icb * 8 + j]);
        return;
    }
    {                                     // w_qkv [192][64] -> [oct][icb][oc16][8]
        int t = (bx - 768) * 256 + tid;
        int j = t & 7, gr = t >> 3, o16 = gr & 15, X = gr >> 4;
        int icb = X % 8, oct = X / 8;
        wrQKV[t] = f2bf(w_qkv[(size_t)(oct * 16 + o16) * 64 + icb * 8 + j]);
    }
}

// ---------------- DWT -> 4 padded-swizzled bf16 planes (LH/HL/HH in TILED, LL in LLP) ----------------
__global__ __launch_bounds__(256) void k_dwt(const float* __restrict__ x,
                                             unsigned short* __restrict__ tiled,
                                             unsigned short* __restrict__ llp) {
    __shared__ unsigned short lds[3 * 128 * 64] __attribute__((aligned(16)));
    const int tid = threadIdx.x;
    const int pid = blockIdx.x;              // 512 = 32 y-patches x 16 x-patches
    const int b = blockIdx.y;
    const int y0 = (pid >> 4) * 8, x0 = (pid & 15) * 16;
    const int quad = tid & 127;
    const int qy = quad >> 4, qx = quad & 15;
    const int gy = y0 + qy, gx = x0 + qx;
    const int ich = tid >> 7;                // 0/1
    unsigned short* llb = llp + (size_t)b * PPLANE + ((size_t)(gy + 1) * PD + (gx + 1)) * 64;

#pragma unroll 4
    for (int it = 0; it < 16; ++it) {
        int ic = it * 4 + ich * 2;           // handle ic, ic+1 (pair => b32 writes)
        unsigned g = (((unsigned)(ic >> 3)) + (unsigned)gx + 2u * (unsigned)gy) & 7u;
        unsigned swz = (unsigned)quad * 64 + (g << 3) + (unsigned)(ic & 7);
        unsigned pk[3], pll;
#pragma unroll
        for (int s = 0; s < 2; ++s) {
            const float* px = x + (((size_t)(b * 64 + ic + s) * HF) + 2 * gy) * WF + 2 * gx;
            float2 e0 = *(const float2*)px;
            float2 e1 = *(const float2*)(px + WF);
            float a = e0.x, bb = e0.y, c = e1.x, d = e1.y;
            unsigned ll = (unsigned short)f2bf(( a + bb + c + d) * 0.5f);
            unsigned lh = (unsigned short)f2bf((-a - bb + c + d) * 0.5f);
            unsigned hl = (unsigned short)f2bf((-a + bb - c + d) * 0.5f);
            unsigned hh = (unsigned short)f2bf(( a - bb - c + d) * 0.5f);
            if (s == 0) { pll = ll; pk[0] = lh; pk[1] = hl; pk[2] = hh; }
            else { pll |= ll << 16; pk[0] |= lh << 16; pk[1] |= hl << 16; pk[2] |= hh << 16; }
        }
        *(unsigned*)&lds[swz]          = pk[0];
        *(unsigned*)&lds[8192 + swz]   = pk[1];
        *(unsigned*)&lds[16384 + swz]  = pk[2];
        *(unsigned*)&llb[(g << 3) + (unsigned)(ic & 7)] = pll;
    }
    __syncthreads();
#pragma unroll
    for (int it = 0; it < 12; ++it) {
        int cch = tid + it * 256;            // 0..3071 (uint4 chunks)
        int p = cch >> 10, rem = cch & 1023;
        int row = rem >> 7, col = rem & 127;
        unsigned short* dst = tiled + ((size_t)(b * 3 + p) * PD + (y0 + row + 1)) * PROW
                                    + (size_t)(x0 + 1) * 64 + (size_t)col * 8;
        *(uint4*)dst = *(const uint4*)((const char*)lds + (size_t)cch * 16);
    }
}

// ---------------- grouped 3x3 conv (+relu) via bf16 MFMA, padded-layout input ----------------
template <int LAYOUT>
__global__ __launch_bounds__(256) void k_gconv3x3_mfma(const unsigned short* __restrict__ tiled,
                                                       const bfx8* __restrict__ wr,
                                                       unsigned short* __restrict__ out, int OC) {
    __shared__ short lds_in[324 * 64] __attribute__((aligned(16)));
    const int tid = threadIdx.x;
    const int l = tid & 63, wv = tid >> 6;
    const int tile = blockIdx.x;
    const int x0 = (tile & 15) * 16, y0 = (tile >> 4) * 16;
    const int g = blockIdx.y, b = blockIdx.z;
    const unsigned short* src = tiled + (size_t)(b * 3 + g) * PPLANE;

#pragma unroll
    for (int it = 0; it < 10; ++it) {
        int cch = it * 256 + tid;
        unsigned row = (unsigned)cch / 144u, col = (unsigned)cch % 144u;
        const unsigned short* ga = src + (size_t)(y0 + row) * PROW + (size_t)x0 * 64 + (size_t)col * 8;
        __builtin_amdgcn_global_load_lds(
            (const __attribute__((address_space(1))) void*)ga,
            (__attribute__((address_space(3))) void*)((char*)lds_in + (size_t)(it * 256 + wv * 64) * 16),
            16, 0, 0);
    }
    if (tid < 32) {
        int cch = 2560 + tid;
        unsigned row = (unsigned)cch / 144u, col = (unsigned)cch % 144u;
        const unsigned short* ga = src + (size_t)(y0 + row) * PROW + (size_t)x0 * 64 + (size_t)col * 8;
        *(uint4*)((char*)lds_in + (size_t)cch * 16) = *(const uint4*)ga;
    }
    __syncthreads();

    f32x4 acc[4][4];
#pragma unroll
    for (int i = 0; i < 4; ++i)
#pragma unroll
        for (int j = 0; j < 4; ++j) acc[i][j] = (f32x4){0.f, 0.f, 0.f, 0.f};

    const int lx = l & 15, lq = l >> 4;
#pragma unroll
    for (int c = 0; c < 2; ++c) {
        const int icb = c * 4 + lq;
#pragma unroll
        for (int tap = 0; tap < 9; ++tap) {
            const int dy = tap / 3, dx = tap % 3;
            const size_t wbase = ((size_t)(g * 9 + tap) * 8 + icb) * 64 + lx;
            bfx8 b0 = wr[wbase];
            bfx8 b1 = wr[wbase + 16];
            bfx8 b2 = wr[wbase + 32];
            bfx8 b3 = wr[wbase + 48];
#pragma unroll
            for (int pg = 0; pg < 4; ++pg) {
                int hy = wv * 4 + pg + dy, hx = lx + dx;
                int hp = hy * 18 + hx;
                const bfx8* ap = (const bfx8*)&lds_in[hp * 64 + (((icb + hx + 2 * hy + 5) & 7) << 3)];
                bfx8 a = *ap;
                acc[pg][0] = __builtin_amdgcn_mfma_f32_16x16x32_bf16(a, b0, acc[pg][0], 0, 0, 0);
                acc[pg][1] = __builtin_amdgcn_mfma_f32_16x16x32_bf16(a, b1, acc[pg][1], 0, 0, 0);
                acc[pg][2] = __builtin_amdgcn_mfma_f32_16x16x32_bf16(a, b2, acc[pg][2], 0, 0, 0);
                acc[pg][3] = __builtin_amdgcn_mfma_f32_16x16x32_bf16(a, b3, acc[pg][3], 0, 0, 0);
            }
        }
    }

#pragma unroll
    for (int pg = 0; pg < 4; ++pg) {
#pragma unroll
        for (int ocg = 0; ocg < 4; ++ocg) {
            f32x4 v = acc[pg][ocg];
            if (LAYOUT == 0) {
                unsigned short* op = out + ((size_t)b * OC + g * 64 + ocg * 16 + lx) * NP
                                         + (size_t)(y0 + wv * 4 + pg) * WH + x0 + lq * 4;
                ushort4 s4;
                s4.x = (unsigned short)f2bf(fmaxf(v.x, 0.f));
                s4.y = (unsigned short)f2bf(fmaxf(v.y, 0.f));
                s4.z = (unsigned short)f2bf(fmaxf(v.z, 0.f));
                s4.w = (unsigned short)f2bf(fmaxf(v.w, 0.f));
                *(ushort4*)op = s4;
            } else {
                int icT = g * 64 + ocg * 16 + lx;
                int g16 = icT >> 3;
                unsigned short* tb = out + ((size_t)(b * 256 + tile) * 256) * 128;
                int innerb = (wv * 4 + pg) * 16 + lq * 4;
                float vr[4] = {v.x, v.y, v.z, v.w};
#pragma unroll
                for (int r = 0; r < 4; ++r) {
                    int inn = innerb + r;
                    tb[(size_t)inn * 128 + (((g16 + inn) & 15) << 3) + (icT & 7)] =
                        (unsigned short)f2bf(fmaxf(vr[r], 0.f));
                }
            }
        }
    }
}

// ---------------- 1x1 conv via bf16 MFMA from tiled input (FILT path) ----------------
template <int CIN, int OC, bool RELU>
__global__ __launch_bounds__(256) void k_conv1x1_mfma(const unsigned short* __restrict__ inT,
                                                      const bfx8* __restrict__ wr,
                                                      unsigned short* __restrict__ out) {
    constexpr int KB = CIN / 8;
    constexpr int KC = CIN / 32;
    constexpr int NOCT = OC / 16;
    __shared__ short ldsA[256 * CIN] __attribute__((aligned(16)));
    const int tid = threadIdx.x;
    const int l = tid & 63, wv = tid >> 6;
    const int tile = blockIdx.x, b = blockIdx.y;
    const unsigned short* src = inT + ((size_t)(b * 256 + tile) * 256) * CIN;
    constexpr int ITER = (256 * CIN / 8) / 256;
#pragma unroll
    for (int it = 0; it < ITER; ++it) {
        int cc = it * 256 + tid;
        __builtin_amdgcn_global_load_lds(
            (const __attribute__((address_space(1))) void*)(src + (size_t)cc * 8),
            (__attribute__((address_space(3))) void*)((char*)ldsA + (size_t)(it * 256 + wv * 64) * 16),
            16, 0, 0);
    }
    __syncthreads();

    const int lx = l & 15, lq = l >> 4;
    const int x0 = (tile & 15) * 16, y0 = (tile >> 4) * 16;
#pragma unroll
    for (int o4 = 0; o4 < NOCT / 4; ++o4) {
        f32x4 acc[4][4];
#pragma unroll
        for (int i = 0; i < 4; ++i)
#pragma unroll
            for (int j = 0; j < 4; ++j) acc[i][j] = (f32x4){0.f, 0.f, 0.f, 0.f};
#pragma unroll
        for (int c = 0; c < KC; ++c) {
            const int icb = c * 4 + lq;
            bfx8 bf[4];
#pragma unroll
            for (int ot = 0; ot < 4; ++ot)
                bf[ot] = wr[(size_t)(((o4 * 4 + ot) * KB + icb) * 16) + lx];
#pragma unroll
            for (int pg = 0; pg < 4; ++pg) {
                int inner = (wv * 4 + pg) * 16 + lx;
                const bfx8* ap = (const bfx8*)&ldsA[inner * CIN + (((icb + inner) & (KB - 1)) << 3)];
                bfx8 a = *ap;
                acc[pg][0] = __builtin_amdgcn_mfma_f32_16x16x32_bf16(a, bf[0], acc[pg][0], 0, 0, 0);
                acc[pg][1] = __builtin_amdgcn_mfma_f32_16x16x32_bf16(a, bf[1], acc[pg][1], 0, 0, 0);
                acc[pg][2] = __builtin_amdgcn_mfma_f32_16x16x32_bf16(a, bf[2], acc[pg][2], 0, 0, 0);
                acc[pg][3] = __builtin_amdgcn_mfma_f32_16x16x32_bf16(a, bf[3], acc[pg][3], 0, 0, 0);
            }
        }
#pragma unroll
        for (int pg = 0; pg < 4; ++pg)
#pragma unroll
            for (int ot = 0; ot < 4; ++ot) {
                int oc = (o4 * 4 + ot) * 16 + lx;
                unsigned short* op = out + ((size_t)b * OC + oc) * NP
                                         + (size_t)(y0 + wv * 4 + pg) * WH + x0 + lq * 4;
                f32x4 v = acc[pg][ot];
                ushort4 s4;
                s4.x = (unsigned short)f2bf(RELU ? fmaxf(v.x, 0.f) : v.x);
                s4.y = (unsigned short)f2bf(RELU ? fmaxf(v.y, 0.f) : v.y);
                s4.z = (unsigned short)f2bf(RELU ? fmaxf(v.z, 0.f) : v.z);
                s4.w = (unsigned short)f2bf(RELU ? fmaxf(v.w, 0.f) : v.w);
                *(ushort4*)op = s4;
            }
    }
}

// ---------------- fused 1x1-qkv + depthwise 3x3 + v-filter -> planar QKV bf16 ----------------
// per block: 16x16 tile. qkv0 computed on 18x18 halo via MFMA (M=324 of 336), LDS-resident.
__global__ __launch_bounds__(256) void k_qkv_fused(const unsigned short* __restrict__ llp,
                                                   const bfx8* __restrict__ wrq,
                                                   const float* __restrict__ wdw,
                                                   const unsigned short* __restrict__ filt,
                                                   unsigned short* __restrict__ qkv) {
    __shared__ short ldsA[336 * 64] __attribute__((aligned(16)));   // halo in, then qkv0 per group
    __shared__ float ldsW[192 * 9];
    const int tid = threadIdx.x;
    const int l = tid & 63, wv = tid >> 6;
    const int tile = blockIdx.x, b = blockIdx.y;
    const int x0 = (tile & 15) * 16, y0 = (tile >> 4) * 16;
    const unsigned short* src = llp + (size_t)b * PPLANE;

    // stage 18x18x64 halo (like gconv): 2592 uint4 chunks
#pragma unroll
    for (int it = 0; it < 10; ++it) {
        int cch = it * 256 + tid;
        unsigned row = (unsigned)cch / 144u, col = (unsigned)cch % 144u;
        const unsigned short* ga = src + (size_t)(y0 + row) * PROW + (size_t)x0 * 64 + (size_t)col * 8;
        __builtin_amdgcn_global_load_lds(
            (const __attribute__((address_space(1))) void*)ga,
            (__attribute__((address_space(3))) void*)((char*)ldsA + (size_t)(it * 256 + wv * 64) * 16),
            16, 0, 0);
    }
    if (tid < 32) {
        int cch = 2560 + tid;
        unsigned row = (unsigned)cch / 144u, col = (unsigned)cch % 144u;
        const unsigned short* ga = src + (size_t)(y0 + row) * PROW + (size_t)x0 * 64 + (size_t)col * 8;
        *(uint4*)((char*)ldsA + (size_t)cch * 16) = *(const uint4*)ga;
    }
    for (int k = tid; k < 1728; k += 256) ldsW[k] = wdw[k];
    __syncthreads();

    // hoist A-frags for my M-tiles into regs (static indexing)
    const int lx = l & 15, lq = l >> 4;
    bfx8 af[6][2];
#pragma unroll
    for (int m = 0; m < 6; ++m) {
        int mt = wv + 4 * m;
        if (mt < 21) {
            int hp = mt * 16 + lx;
            int hy = hp / 18, hx = hp - hy * 18;
#pragma unroll
            for (int kc = 0; kc < 2; ++kc) {
                int icb = kc * 4 + lq;
                af[m][kc] = *(const bfx8*)&ldsA[hp * 64 + (((icb + hx + 2 * hy + 5) & 7) << 3)];
            }
        }
    }
    __syncthreads();   // all input reads done before overwrite

    for (int g3 = 0; g3 < 3; ++g3) {
        // B-frags for this 64-oc group (L2-resident weights)
        bfx8 bw[2][4];
#pragma unroll
        for (int kc = 0; kc < 2; ++kc)
#pragma unroll
            for (int nt = 0; nt < 4; ++nt)
                bw[kc][nt] = wrq[(size_t)(((g3 * 4 + nt) * 8) + kc * 4 + lq) * 16 + lx];
        // MFMA + write qkv0 to LDS [hp][64 swz]
#pragma unroll
        for (int m = 0; m < 6; ++m) {
            int mt = wv + 4 * m;
            if (mt < 21) {
                f32x4 acc[4];
#pragma unroll
                for (int nt = 0; nt < 4; ++nt) acc[nt] = (f32x4){0.f, 0.f, 0.f, 0.f};
#pragma unroll
                for (int kc = 0; kc < 2; ++kc) {
                    bfx8 a = af[m][kc];
#pragma unroll
                    for (int nt = 0; nt < 4; ++nt)
                        acc[nt] = __builtin_amdgcn_mfma_f32_16x16x32_bf16(a, bw[kc][nt], acc[nt], 0, 0, 0);
                }
#pragma unroll
                for (int nt = 0; nt < 4; ++nt) {
                    int ocl = nt * 16 + lx;
                    float vr[4] = {acc[nt].x, acc[nt].y, acc[nt].z, acc[nt].w};
#pragma unroll
                    for (int r = 0; r < 4; ++r) {
                        int hp2 = mt * 16 + lq * 4 + r;
                        int hy2 = hp2 / 18, hx2 = hp2 - hy2 * 18;
                        ldsA[hp2 * 64 + ((((ocl >> 3) + hx2 + 2 * hy2) & 7) << 3) + (ocl & 7)] =
                            f2bf(vr[r]);
                    }
                }
            }
        }
        __syncthreads();
        // depthwise 3x3 (+filt for v): lane = ch, wave = 4-row segment
        {
            const int ch = l, chg = g3 * 64 + ch;
            float w9[9];
#pragma unroll
            for (int t = 0; t < 9; ++t) w9[t] = ldsW[chg * 9 + t];
#pragma unroll
            for (int yy = 0; yy < 4; ++yy) {
                int y = wv * 4 + yy;
                float ln[3][18];
#pragma unroll
                for (int hr = 0; hr < 3; ++hr) {
                    int hy = y + hr;
#pragma unroll
                    for (int hx = 0; hx < 18; ++hx)
                        ln[hr][hx] = bfu((unsigned short)ldsA[(hy * 18 + hx) * 64 +
                                         ((((ch >> 3) + hx + 2 * hy) & 7) << 3) + (ch & 7)]);
                }
                float ox[16];
#pragma unroll
                for (int xx = 0; xx < 16; ++xx) {
                    float s = 0.f;
#pragma unroll
                    for (int hr = 0; hr < 3; ++hr)
#pragma unroll
                        for (int dx = 0; dx < 3; ++dx)
                            s = fmaf(ln[hr][xx + dx], w9[hr * 3 + dx], s);
                    ox[xx] = s;
                }
                if (g3 == 2) {
                    const unsigned short* fp = filt + ((size_t)b * 64 + ch) * NP
                                                    + (size_t)(y0 + y) * WH + x0;
                    u16x8 f0 = *(const u16x8*)fp;
                    u16x8 f1 = *(const u16x8*)(fp + 8);
#pragma unroll
                    for (int k = 0; k < 8; ++k) ox[k]     = fmaf(ox[k],     bfu(f0[k]), ox[k]);
#pragma unroll
                    for (int k = 0; k < 8; ++k) ox[8 + k] = fmaf(ox[8 + k], bfu(f1[k]), ox[8 + k]);
                }
                u16x8 s0, s1;
#pragma unroll
                for (int k = 0; k < 8; ++k) { s0[k] = (unsigned short)f2bf(ox[k]);
                                              s1[k] = (unsigned short)f2bf(ox[8 + k]); }
                unsigned short* op = qkv + ((size_t)b * 192 + chg) * NP + (size_t)(y0 + y) * WH + x0;
                *(u16x8*)op = s0;
                *(u16x8*)(op + 8) = s1;
            }
        }
        __syncthreads();
    }
}

// ---------------- attention dots + sum-of-squares (stage 1, split over n) ----------------
__global__ __launch_bounds__(256) void k_attn_dot(const unsigned short* __restrict__ qkv,
                                                  float* __restrict__ praw,
                                                  float* __restrict__ praw2) {
    int bhd = blockIdx.x, sp = blockIdx.y;   // grid (32, 8)
    int b = bhd >> 3, hd = bhd & 7;
    const unsigned short* qb = qkv + ((size_t)b * 192 + hd * 8) * NP;
    const unsigned short* kb = qkv + ((size_t)b * 192 + 64 + hd * 8) * NP;
    float acc[64], acc2[16];
#pragma unroll
    for (int i = 0; i < 64; ++i) acc[i] = 0.f;
#pragma unroll
    for (int i = 0; i < 16; ++i) acc2[i] = 0.f;
    int n0 = sp * (NP / 8);
    for (int n = n0 + threadIdx.x; n < n0 + NP / 8; n += 256) {
        float qv[8], kv[8];
#pragma unroll
        for (int c2 = 0; c2 < 8; ++c2) qv[c2] = bfu(qb[(size_t)c2 * NP + n]);
#pragma unroll
        for (int d2 = 0; d2 < 8; ++d2) kv[d2] = bfu(kb[(size_t)d2 * NP + n]);
#pragma unroll
        for (int c2 = 0; c2 < 8; ++c2) {
            acc2[c2] = fmaf(qv[c2], qv[c2], acc2[c2]);
#pragma unroll
            for (int d2 = 0; d2 < 8; ++d2)
                acc[c2 * 8 + d2] = fmaf(qv[c2], kv[d2], acc[c2 * 8 + d2]);
        }
#pragma unroll
        for (int d2 = 0; d2 < 8; ++d2) acc2[8 + d2] = fmaf(kv[d2], kv[d2], acc2[8 + d2]);
    }
    __shared__ float red[4][64];
#pragma unroll
    for (int i = 0; i < 64; ++i) {
        float v = acc[i];
#pragma unroll
        for (int off = 32; off; off >>= 1) v += __shfl_down(v, off);
        if ((threadIdx.x & 63) == 0) red[threadIdx.x >> 6][i] = v;
    }
    __syncthreads();
    if (threadIdx.x < 64)
        praw[((size_t)sp * 32 + bhd) * 64 + threadIdx.x] =
            red[0][threadIdx.x] + red[1][threadIdx.x] + red[2][threadIdx.x] + red[3][threadIdx.x];
    __syncthreads();
#pragma unroll
    for (int i = 0; i < 16; ++i) {
        float v = acc2[i];
#pragma unroll
        for (int off = 32; off; off >>= 1) v += __shfl_down(v, off);
        if ((threadIdx.x & 63) == 0) red[threadIdx.x >> 6][i] = v;
    }
    __syncthreads();
    if (threadIdx.x < 16)
        praw2[((size_t)sp * 32 + bhd) * 16 + threadIdx.x] =
            red[0][threadIdx.x] + red[1][threadIdx.x] + red[2][threadIdx.x] + red[3][threadIdx.x];
}

// ---------------- scale (incl. l2norm) + softmax (stage 2) ----------------
__global__ __launch_bounds__(64) void k_attn_soft(const float* __restrict__ praw,
                                                  const float* __restrict__ praw2,
                                                  const float* __restrict__ temp,
                                                  float* __restrict__ attn) {
    int bhd = blockIdx.x;                // 32 blocks, 64 threads
    int hd = bhd & 7;
    int t = threadIdx.x, c = t >> 3, d = t & 7;
    float s = 0.f, sq = 0.f, sk = 0.f;
    for (int sp = 0; sp < 8; ++sp) {
        s  += praw[((size_t)sp * 32 + bhd) * 64 + t];
        sq += praw2[((size_t)sp * 32 + bhd) * 16 + c];
        sk += praw2[((size_t)sp * 32 + bhd) * 16 + 8 + d];
    }
    float nq = fmaxf(sqrtf(sq), 1e-12f);
    float nk = fmaxf(sqrtf(sk), 1e-12f);
    s = s / (nq * nk) * temp[hd];
    __shared__ float sm[64];
    __shared__ float se[64];
    sm[t] = s;
    __syncthreads();
    float mx = -1e30f;
#pragma unroll
    for (int dd = 0; dd < 8; ++dd) mx = fmaxf(mx, sm[c * 8 + dd]);
    float e = __expf(s - mx);
    se[t] = e;
    __syncthreads();
    float sum = 0.f;
#pragma unroll
    for (int dd = 0; dd < 8; ++dd) sum += se[c * 8 + dd];
    attn[(size_t)bhd * 64 + t] = e / sum;
}

// ---------------- fused attn*v + 1x1 proj + IDWT -> fp32 out ----------------
__global__ __launch_bounds__(256) void k_attnout_idwt(const unsigned short* __restrict__ qkv,
                                                      const float* __restrict__ attn,
                                                      const float* __restrict__ wproj,
                                                      const unsigned short* __restrict__ yh,
                                                      float* __restrict__ out) {
    __shared__ float wsh[64 * 64];
    __shared__ float ash[512];
    const int tid = threadIdx.x;
    const int b = blockIdx.y;
    const int p = blockIdx.x * 256 + tid;
#pragma unroll
    for (int it = 0; it < 16; ++it) wsh[tid + it * 256] = wproj[tid + it * 256];
#pragma unroll
    for (int it = 0; it < 2; ++it) ash[tid + it * 256] = attn[(size_t)b * 512 + tid + it * 256];
    __syncthreads();

    float av[64];
    const unsigned short* vb = qkv + ((size_t)b * 192 + 128) * NP + p;
#pragma unroll
    for (int hd = 0; hd < 8; ++hd) {
        float vv[8];
#pragma unroll
        for (int d = 0; d < 8; ++d) vv[d] = bfu(vb[(size_t)(hd * 8 + d) * NP]);
#pragma unroll
        for (int c2 = 0; c2 < 8; ++c2) {
            float s = 0.f;
#pragma unroll
            for (int d = 0; d < 8; ++d) s = fmaf(ash[hd * 64 + c2 * 8 + d], vv[d], s);
            av[hd * 8 + c2] = s;
        }
    }
    const int i = p >> 8, j = p & 255;
    const unsigned short* yb = yh + (size_t)b * 192 * NP + p;
    float* ob = out + ((size_t)b * 64 * HF + 2 * i) * WF + 2 * j;
    for (int c = 0; c < 64; ++c) {          // runtime c: no dynamic reg indexing
        float s = 0.f;
#pragma unroll
        for (int ic = 0; ic < 64; ++ic) s = fmaf(av[ic], wsh[c * 64 + ic], s);
        float LHv = bfu(yb[(size_t)c * NP]);
        float HLv = bfu(yb[(size_t)(c + 64) * NP]);
        float HHv = bfu(yb[(size_t)(c + 128) * NP]);
        float* oc_ = ob + (size_t)c * HF * WF;
        *(float2*)oc_        = make_float2((s - LHv - HLv + HHv) * 0.5f, (s - LHv + HLv - HHv) * 0.5f);
        *(float2*)(oc_ + WF) = make_float2((s + LHv - HLv - HHv) * 0.5f, (s + LHv + HLv + HHv) * 0.5f);
    }
}

extern "C" void kernel_launch(void* const* d_in, const int* in_sizes, int n_in,
                              void* d_out, int out_size, void* d_ws, size_t ws_size,
                              hipStream_t stream) {
    const float* x      = (const float*)d_in[0];
    const float* w_hc1  = (const float*)d_in[1];
    const float* w_hc2  = (const float*)d_in[2];
    const float* w_ho   = (const float*)d_in[3];
    const float* w_qkv  = (const float*)d_in[4];
    const float* w_dw   = (const float*)d_in[5];
    const float* w_proj = (const float*)d_in[6];
    const float* temp   = (const float*)d_in[7];
    float* out = (float*)d_out;

    char* base = (char*)d_ws;
    unsigned short* TILED = (unsigned short*)(base + 0);             // 12 padded planes
    unsigned short* LLP   = (unsigned short*)(base + 102242304ULL);  // 4 padded planes (LL)
    unsigned short* YH    = (unsigned short*)(base + 136323072ULL);  // 96 MiB bf16 [b][192][NP]
    unsigned short* T1T   = (unsigned short*)(base + 236986368ULL);  // 64 MiB bf16 tiled [..][128]
    unsigned short* FILT  = (unsigned short*)(base + 304095232ULL);  // 32 MiB bf16 [b][64][NP]
    unsigned short* QKV   = (unsigned short*)(base + 337649664ULL);  // 96 MiB bf16 [b][192][NP]
    float*          PRAW  = (float*)(base + 438312960ULL);
    float*          PRAW2 = (float*)(base + 438378496ULL);
    float*          ATTN  = (float*)(base + 438394880ULL);
    short* WREP_HO  = (short*)(base + 438403072ULL);
    short* WREP_HC1 = (short*)(base + 438624256ULL);
    short* WREP_HC2 = (short*)(base + 438771712ULL);
    short* WREP_QKV = (short*)(base + 438788096ULL);

    // 0. merged setup: ring-zero 16 planes + all repacks (816 blocks)
    k_setup<<<816, 256, 0, stream>>>(TILED, w_ho, w_hc1, w_hc2, w_qkv,
                                     WREP_HO, WREP_HC1, WREP_HC2, WREP_QKV);
    // 1. DWT -> padded bf16 LH/HL/HH + LL
    k_dwt<<<dim3(512, BN), 256, 0, stream>>>(x, TILED, LLP);
    // 2. yh = relu(gconv3x3(LH,HL,HH; w_ho, groups=3)) -> planar bf16
    k_gconv3x3_mfma<0><<<dim3(256, 3, BN), 256, 0, stream>>>(TILED, (const bfx8*)WREP_HO, YH, 192);
    // 3. t1 = relu(gconv3x3(LH,HL; w_hc1, groups=2)) -> tiled-interleaved bf16
    k_gconv3x3_mfma<1><<<dim3(256, 2, BN), 256, 0, stream>>>(TILED, (const bfx8*)WREP_HC1, T1T, 128);
    // 4. filter_hv = relu(1x1(t1, w_hc2)) -> planar bf16
    k_conv1x1_mfma<128, 64, true><<<dim3(256, BN), 256, 0, stream>>>(T1T, (const bfx8*)WREP_HC2, FILT);
    // 5. qkv = dw3x3(1x1(LL, w_qkv)) with v-filter, fused -> planar bf16
    k_qkv_fused<<<dim3(256, BN), 256, 0, stream>>>(LLP, (const bfx8*)WREP_QKV, w_dw, FILT, QKV);
    // 6-7. attention scores (+sumsq) + softmax (incl. l2norm)
    k_attn_dot<<<dim3(32, 8), 256, 0, stream>>>(QKV, PRAW, PRAW2);
    k_attn_soft<<<32, 64, 0, stream>>>(PRAW, PRAW2, temp, ATTN);
    // 8. fused attn*v + proj + IDWT -> fp32 out
    k_attnout_idwt<<<dim3(256, BN), 256, 0, stream>>>(QKV, ATTN, w_proj, YH, out);
}

// Round 8
// 602.903 us; speedup vs baseline: 4.5959x; 1.0175x over previous
//
#include <hip/hip_runtime.h>
#include <hip/hip_bf16.h>

#define BN 4
#define DIM 64
#define NHEADS 8
#define HH 256
#define WH 256
#define NP (HH*WH)      // 65536
#define HF 512
#define WF 512

#define PD 258                       // padded dim
#define PROW (PD*64)                 // shorts per padded row
#define PPLANE ((size_t)PD*PD*64)    // shorts per padded plane

typedef __attribute__((ext_vector_type(8))) short bfx8;           // 8 bf16
typedef __attribute__((ext_vector_type(8))) unsigned short u16x8; // 8 bf16 bits
typedef __attribute__((ext_vector_type(4))) unsigned short u16x4; // 4 bf16 bits
typedef __attribute__((ext_vector_type(4))) float f32x4;          // MFMA C/D frag

static __device__ __forceinline__ short f2bf(float f) {
    unsigned u = __float_as_uint(f);
    unsigned r = (u + 0x7FFFu + ((u >> 16) & 1u)) >> 16;   // RNE
    return (short)r;
}
static __device__ __forceinline__ float bfu(unsigned short u) {
    return __uint_as_float((unsigned)u << 16);
}

// ---------------- merged setup: ring-zero 16 planes + all weight repacks ----------------
__global__ __launch_bounds__(256) void k_setup(unsigned short* __restrict__ tiled16,
                                               const float* __restrict__ w_ho,
                                               const float* __restrict__ w_hc1,
                                               const float* __restrict__ w_hc2,
                                               const float* __restrict__ w_qkv,
                                               short* __restrict__ wrHO,
                                               short* __restrict__ wrHC1,
                                               short* __restrict__ wrHC2,
                                               short* __restrict__ wrQKV) {
    int bx = blockIdx.x, tid = threadIdx.x;
    if (bx < 16) {                        // pad-ring zero, 16 planes (12 TILED + 4 LLP)
        char* base = (char*)(tiled16 + (size_t)bx * PPLANE);
        const int ROWB = PROW * 2;
        for (int k = tid; k < 8224; k += 256) {
            char* dst;
            if (k < 2064) dst = base + (size_t)k * 16;
            else if (k < 4128) dst = base + (size_t)257 * ROWB + (size_t)(k - 2064) * 16;
            else if (k < 6176) { int r = (k - 4128) >> 3, s = (k - 4128) & 7;
                dst = base + (size_t)(r + 1) * ROWB + (size_t)s * 16; }
            else { int r = (k - 6176) >> 3, s = (k - 6176) & 7;
                dst = base + (size_t)(r + 1) * ROWB + 257 * 128 + (size_t)s * 16; }
            *(uint4*)dst = (uint4){0, 0, 0, 0};
        }
        return;
    }
    if (bx < 16 + 432 + 288) {            // 3x3 repacks: OIHW -> [g][tap][icb][oc][8]
        const float* w = (bx < 448) ? w_ho : w_hc1;
        short* wrep = (bx < 448) ? wrHO : wrHC1;
        int t = (bx - ((bx < 448) ? 16 : 448)) * 256 + tid;
        unsigned g   = (unsigned)t / 36864u;
        unsigned r1  = (unsigned)t % 36864u;
        unsigned tap = r1 / 4096u;
        unsigned r2  = r1 % 4096u;
        unsigned icb = r2 / 512u;
        unsigned r3  = r2 % 512u;
        unsigned oc  = r3 >> 3;
        unsigned j   = r3 & 7u;
        wrep[t] = f2bf(w[(((size_t)g * 64 + oc) * 64 + icb * 8u + j) * 9 + tap]);
        return;
    }
    if (bx < 16 + 432 + 288 + 32) {       // w_hc2 [64][128] -> [oct][icb][oc16][8]
        int t = (bx - 736) * 256 + tid;
        int j = t & 7, gr = t >> 3, o16 = gr & 15, X = gr >> 4;
        int icb = X % 16, oct = X / 16;
        wrHC2[t] = f2bf(w_hc2[(size_t)(oct * 16 + o16) * 128 + icb * 8 + j]);
        return;
    }
    {                                     // w_qkv [192][64] -> [oct][icb][oc16][8]
        int t = (bx - 768) * 256 + tid;
        int j = t & 7, gr = t >> 3, o16 = gr & 15, X = gr >> 4;
        int icb = X % 8, oct = X / 8;
        wrQKV[t] = f2bf(w_qkv[(size_t)(oct * 16 + o16) * 64 + icb * 8 + j]);
    }
}

// ---------------- DWT -> 4 padded-swizzled bf16 planes (LH/HL/HH in TILED, LL in LLP) ----------------
__global__ __launch_bounds__(256) void k_dwt(const float* __restrict__ x,
                                             unsigned short* __restrict__ tiled,
                                             unsigned short* __restrict__ llp) {
    __shared__ unsigned short lds[3 * 128 * 64] __attribute__((aligned(16)));
    const int tid = threadIdx.x;
    const int pid = blockIdx.x;              // 512 = 32 y-patches x 16 x-patches
    const int b = blockIdx.y;
    const int y0 = (pid >> 4) * 8, x0 = (pid & 15) * 16;
    const int quad = tid & 127;
    const int qy = quad >> 4, qx = quad & 15;
    const int gy = y0 + qy, gx = x0 + qx;
    const int ich = tid >> 7;                // 0/1
    unsigned short* llb = llp + (size_t)b * PPLANE + ((size_t)(gy + 1) * PD + (gx + 1)) * 64;

#pragma unroll 4
    for (int it = 0; it < 16; ++it) {
        int ic = it * 4 + ich * 2;           // handle ic, ic+1 (pair => b32 writes)
        unsigned g = (((unsigned)(ic >> 3)) + (unsigned)gx + 2u * (unsigned)gy) & 7u;
        unsigned swz = (unsigned)quad * 64 + (g << 3) + (unsigned)(ic & 7);
        unsigned pk[3], pll;
#pragma unroll
        for (int s = 0; s < 2; ++s) {
            const float* px = x + (((size_t)(b * 64 + ic + s) * HF) + 2 * gy) * WF + 2 * gx;
            float2 e0 = *(const float2*)px;
            float2 e1 = *(const float2*)(px + WF);
            float a = e0.x, bb = e0.y, c = e1.x, d = e1.y;
            unsigned ll = (unsigned short)f2bf(( a + bb + c + d) * 0.5f);
            unsigned lh = (unsigned short)f2bf((-a - bb + c + d) * 0.5f);
            unsigned hl = (unsigned short)f2bf((-a + bb - c + d) * 0.5f);
            unsigned hh = (unsigned short)f2bf(( a - bb - c + d) * 0.5f);
            if (s == 0) { pll = ll; pk[0] = lh; pk[1] = hl; pk[2] = hh; }
            else { pll |= ll << 16; pk[0] |= lh << 16; pk[1] |= hl << 16; pk[2] |= hh << 16; }
        }
        *(unsigned*)&lds[swz]          = pk[0];
        *(unsigned*)&lds[8192 + swz]   = pk[1];
        *(unsigned*)&lds[16384 + swz]  = pk[2];
        *(unsigned*)&llb[(g << 3) + (unsigned)(ic & 7)] = pll;
    }
    __syncthreads();
#pragma unroll
    for (int it = 0; it < 12; ++it) {
        int cch = tid + it * 256;            // 0..3071 (uint4 chunks)
        int p = cch >> 10, rem = cch & 1023;
        int row = rem >> 7, col = rem & 127;
        unsigned short* dst = tiled + ((size_t)(b * 3 + p) * PD + (y0 + row + 1)) * PROW
                                    + (size_t)(x0 + 1) * 64 + (size_t)col * 8;
        *(uint4*)dst = *(const uint4*)((const char*)lds + (size_t)cch * 16);
    }
}

// ---------------- grouped 3x3 conv (+relu) via bf16 MFMA, padded-layout input ----------------
// LAYOUT 0: tile-major [b][tile][OC][256 inner].  LAYOUT 1: tiled-interleaved [b][tile][256][128swz].
template <int LAYOUT>
__global__ __launch_bounds__(256) void k_gconv3x3_mfma(const unsigned short* __restrict__ tiled,
                                                       const bfx8* __restrict__ wr,
                                                       unsigned short* __restrict__ out, int OC) {
    __shared__ short lds_in[324 * 64] __attribute__((aligned(16)));
    const int tid = threadIdx.x;
    const int l = tid & 63, wv = tid >> 6;
    const int tile = blockIdx.x;
    const int x0 = (tile & 15) * 16, y0 = (tile >> 4) * 16;
    const int g = blockIdx.y, b = blockIdx.z;
    const unsigned short* src = tiled + (size_t)(b * 3 + g) * PPLANE;

#pragma unroll
    for (int it = 0; it < 10; ++it) {
        int cch = it * 256 + tid;
        unsigned row = (unsigned)cch / 144u, col = (unsigned)cch % 144u;
        const unsigned short* ga = src + (size_t)(y0 + row) * PROW + (size_t)x0 * 64 + (size_t)col * 8;
        __builtin_amdgcn_global_load_lds(
            (const __attribute__((address_space(1))) void*)ga,
            (__attribute__((address_space(3))) void*)((char*)lds_in + (size_t)(it * 256 + wv * 64) * 16),
            16, 0, 0);
    }
    if (tid < 32) {
        int cch = 2560 + tid;
        unsigned row = (unsigned)cch / 144u, col = (unsigned)cch % 144u;
        const unsigned short* ga = src + (size_t)(y0 + row) * PROW + (size_t)x0 * 64 + (size_t)col * 8;
        *(uint4*)((char*)lds_in + (size_t)cch * 16) = *(const uint4*)ga;
    }
    __syncthreads();

    f32x4 acc[4][4];
#pragma unroll
    for (int i = 0; i < 4; ++i)
#pragma unroll
        for (int j = 0; j < 4; ++j) acc[i][j] = (f32x4){0.f, 0.f, 0.f, 0.f};

    const int lx = l & 15, lq = l >> 4;
#pragma unroll
    for (int c = 0; c < 2; ++c) {
        const int icb = c * 4 + lq;
#pragma unroll
        for (int tap = 0; tap < 9; ++tap) {
            const int dy = tap / 3, dx = tap % 3;
            const size_t wbase = ((size_t)(g * 9 + tap) * 8 + icb) * 64 + lx;
            bfx8 b0 = wr[wbase];
            bfx8 b1 = wr[wbase + 16];
            bfx8 b2 = wr[wbase + 32];
            bfx8 b3 = wr[wbase + 48];
#pragma unroll
            for (int pg = 0; pg < 4; ++pg) {
                int hy = wv * 4 + pg + dy, hx = lx + dx;
                int hp = hy * 18 + hx;
                const bfx8* ap = (const bfx8*)&lds_in[hp * 64 + (((icb + hx + 2 * hy + 5) & 7) << 3)];
                bfx8 a = *ap;
                acc[pg][0] = __builtin_amdgcn_mfma_f32_16x16x32_bf16(a, b0, acc[pg][0], 0, 0, 0);
                acc[pg][1] = __builtin_amdgcn_mfma_f32_16x16x32_bf16(a, b1, acc[pg][1], 0, 0, 0);
                acc[pg][2] = __builtin_amdgcn_mfma_f32_16x16x32_bf16(a, b2, acc[pg][2], 0, 0, 0);
                acc[pg][3] = __builtin_amdgcn_mfma_f32_16x16x32_bf16(a, b3, acc[pg][3], 0, 0, 0);
            }
        }
    }

#pragma unroll
    for (int pg = 0; pg < 4; ++pg) {
#pragma unroll
        for (int ocg = 0; ocg < 4; ++ocg) {
            f32x4 v = acc[pg][ocg];
            if (LAYOUT == 0) {
                // tile-major: [b][tile][oc][inner], inner = (y-y0)*16 + (x-x0)
                unsigned short* op = out + ((size_t)(b * 256 + tile) * OC + g * 64 + ocg * 16 + lx) * 256
                                         + (wv * 4 + pg) * 16 + lq * 4;
                ushort4 s4;
                s4.x = (unsigned short)f2bf(fmaxf(v.x, 0.f));
                s4.y = (unsigned short)f2bf(fmaxf(v.y, 0.f));
                s4.z = (unsigned short)f2bf(fmaxf(v.z, 0.f));
                s4.w = (unsigned short)f2bf(fmaxf(v.w, 0.f));
                *(ushort4*)op = s4;
            } else {
                int icT = g * 64 + ocg * 16 + lx;
                int g16 = icT >> 3;
                unsigned short* tb = out + ((size_t)(b * 256 + tile) * 256) * 128;
                int innerb = (wv * 4 + pg) * 16 + lq * 4;
                float vr[4] = {v.x, v.y, v.z, v.w};
#pragma unroll
                for (int r = 0; r < 4; ++r) {
                    int inn = innerb + r;
                    tb[(size_t)inn * 128 + (((g16 + inn) & 15) << 3) + (icT & 7)] =
                        (unsigned short)f2bf(fmaxf(vr[r], 0.f));
                }
            }
        }
    }
}

// ---------------- 1x1 conv via bf16 MFMA from tiled input (FILT path) ----------------
template <int CIN, int OC, bool RELU>
__global__ __launch_bounds__(256) void k_conv1x1_mfma(const unsigned short* __restrict__ inT,
                                                      const bfx8* __restrict__ wr,
                                                      unsigned short* __restrict__ out) {
    constexpr int KB = CIN / 8;
    constexpr int KC = CIN / 32;
    constexpr int NOCT = OC / 16;
    __shared__ short ldsA[256 * CIN] __attribute__((aligned(16)));
    const int tid = threadIdx.x;
    const int l = tid & 63, wv = tid >> 6;
    const int tile = blockIdx.x, b = blockIdx.y;
    const unsigned short* src = inT + ((size_t)(b * 256 + tile) * 256) * CIN;
    constexpr int ITER = (256 * CIN / 8) / 256;
#pragma unroll
    for (int it = 0; it < ITER; ++it) {
        int cc = it * 256 + tid;
        __builtin_amdgcn_global_load_lds(
            (const __attribute__((address_space(1))) void*)(src + (size_t)cc * 8),
            (__attribute__((address_space(3))) void*)((char*)ldsA + (size_t)(it * 256 + wv * 64) * 16),
            16, 0, 0);
    }
    __syncthreads();

    const int lx = l & 15, lq = l >> 4;
    const int x0 = (tile & 15) * 16, y0 = (tile >> 4) * 16;
#pragma unroll
    for (int o4 = 0; o4 < NOCT / 4; ++o4) {
        f32x4 acc[4][4];
#pragma unroll
        for (int i = 0; i < 4; ++i)
#pragma unroll
            for (int j = 0; j < 4; ++j) acc[i][j] = (f32x4){0.f, 0.f, 0.f, 0.f};
#pragma unroll
        for (int c = 0; c < KC; ++c) {
            const int icb = c * 4 + lq;
            bfx8 bf[4];
#pragma unroll
            for (int ot = 0; ot < 4; ++ot)
                bf[ot] = wr[(size_t)(((o4 * 4 + ot) * KB + icb) * 16) + lx];
#pragma unroll
            for (int pg = 0; pg < 4; ++pg) {
                int inner = (wv * 4 + pg) * 16 + lx;
                const bfx8* ap = (const bfx8*)&ldsA[inner * CIN + (((icb + inner) & (KB - 1)) << 3)];
                bfx8 a = *ap;
                acc[pg][0] = __builtin_amdgcn_mfma_f32_16x16x32_bf16(a, bf[0], acc[pg][0], 0, 0, 0);
                acc[pg][1] = __builtin_amdgcn_mfma_f32_16x16x32_bf16(a, bf[1], acc[pg][1], 0, 0, 0);
                acc[pg][2] = __builtin_amdgcn_mfma_f32_16x16x32_bf16(a, bf[2], acc[pg][2], 0, 0, 0);
                acc[pg][3] = __builtin_amdgcn_mfma_f32_16x16x32_bf16(a, bf[3], acc[pg][3], 0, 0, 0);
            }
        }
#pragma unroll
        for (int pg = 0; pg < 4; ++pg)
#pragma unroll
            for (int ot = 0; ot < 4; ++ot) {
                int oc = (o4 * 4 + ot) * 16 + lx;
                unsigned short* op = out + ((size_t)b * OC + oc) * NP
                                         + (size_t)(y0 + wv * 4 + pg) * WH + x0 + lq * 4;
                f32x4 v = acc[pg][ot];
                ushort4 s4;
                s4.x = (unsigned short)f2bf(RELU ? fmaxf(v.x, 0.f) : v.x);
                s4.y = (unsigned short)f2bf(RELU ? fmaxf(v.y, 0.f) : v.y);
                s4.z = (unsigned short)f2bf(RELU ? fmaxf(v.z, 0.f) : v.z);
                s4.w = (unsigned short)f2bf(RELU ? fmaxf(v.w, 0.f) : v.w);
                *(ushort4*)op = s4;
            }
    }
}

// ---------------- fused 1x1-qkv + depthwise 3x3 + v-filter -> planar QKV bf16 ----------------
__global__ __launch_bounds__(256) void k_qkv_fused(const unsigned short* __restrict__ llp,
                                                   const bfx8* __restrict__ wrq,
                                                   const float* __restrict__ wdw,
                                                   const unsigned short* __restrict__ filt,
                                                   unsigned short* __restrict__ qkv) {
    __shared__ short ldsA[336 * 64] __attribute__((aligned(16)));   // halo in, then qkv0 per group
    __shared__ float ldsW[192 * 9];
    const int tid = threadIdx.x;
    const int l = tid & 63, wv = tid >> 6;
    const int tile = blockIdx.x, b = blockIdx.y;
    const int x0 = (tile & 15) * 16, y0 = (tile >> 4) * 16;
    const unsigned short* src = llp + (size_t)b * PPLANE;

    // stage 18x18x64 halo (like gconv): 2592 uint4 chunks
#pragma unroll
    for (int it = 0; it < 10; ++it) {
        int cch = it * 256 + tid;
        unsigned row = (unsigned)cch / 144u, col = (unsigned)cch % 144u;
        const unsigned short* ga = src + (size_t)(y0 + row) * PROW + (size_t)x0 * 64 + (size_t)col * 8;
        __builtin_amdgcn_global_load_lds(
            (const __attribute__((address_space(1))) void*)ga,
            (__attribute__((address_space(3))) void*)((char*)ldsA + (size_t)(it * 256 + wv * 64) * 16),
            16, 0, 0);
    }
    if (tid < 32) {
        int cch = 2560 + tid;
        unsigned row = (unsigned)cch / 144u, col = (unsigned)cch % 144u;
        const unsigned short* ga = src + (size_t)(y0 + row) * PROW + (size_t)x0 * 64 + (size_t)col * 8;
        *(uint4*)((char*)ldsA + (size_t)cch * 16) = *(const uint4*)ga;
    }
    for (int k = tid; k < 1728; k += 256) ldsW[k] = wdw[k];
    __syncthreads();

    // hoist A-frags for my M-tiles into regs (static indexing)
    const int lx = l & 15, lq = l >> 4;
    bfx8 af[6][2];
#pragma unroll
    for (int m = 0; m < 6; ++m) {
        int mt = wv + 4 * m;
        if (mt < 21) {
            int hp = mt * 16 + lx;
            int hy = hp / 18, hx = hp - hy * 18;
#pragma unroll
            for (int kc = 0; kc < 2; ++kc) {
                int icb = kc * 4 + lq;
                af[m][kc] = *(const bfx8*)&ldsA[hp * 64 + (((icb + hx + 2 * hy + 5) & 7) << 3)];
            }
        }
    }
    __syncthreads();   // all input reads done before overwrite

    for (int g3 = 0; g3 < 3; ++g3) {
        // B-frags for this 64-oc group (L2-resident weights)
        bfx8 bw[2][4];
#pragma unroll
        for (int kc = 0; kc < 2; ++kc)
#pragma unroll
            for (int nt = 0; nt < 4; ++nt)
                bw[kc][nt] = wrq[(size_t)(((g3 * 4 + nt) * 8) + kc * 4 + lq) * 16 + lx];
        // MFMA + write qkv0 to LDS [hp][64 swz]
#pragma unroll
        for (int m = 0; m < 6; ++m) {
            int mt = wv + 4 * m;
            if (mt < 21) {
                f32x4 acc[4];
#pragma unroll
                for (int nt = 0; nt < 4; ++nt) acc[nt] = (f32x4){0.f, 0.f, 0.f, 0.f};
#pragma unroll
                for (int kc = 0; kc < 2; ++kc) {
                    bfx8 a = af[m][kc];
#pragma unroll
                    for (int nt = 0; nt < 4; ++nt)
                        acc[nt] = __builtin_amdgcn_mfma_f32_16x16x32_bf16(a, bw[kc][nt], acc[nt], 0, 0, 0);
                }
#pragma unroll
                for (int nt = 0; nt < 4; ++nt) {
                    int ocl = nt * 16 + lx;
                    float vr[4] = {acc[nt].x, acc[nt].y, acc[nt].z, acc[nt].w};
#pragma unroll
                    for (int r = 0; r < 4; ++r) {
                        int hp2 = mt * 16 + lq * 4 + r;
                        int hy2 = hp2 / 18, hx2 = hp2 - hy2 * 18;
                        ldsA[hp2 * 64 + ((((ocl >> 3) + hx2 + 2 * hy2) & 7) << 3) + (ocl & 7)] =
                            f2bf(vr[r]);
                    }
                }
            }
        }
        __syncthreads();
        // depthwise 3x3 (+filt for v): lane = ch, wave = 4-row segment
        {
            const int ch = l, chg = g3 * 64 + ch;
            float w9[9];
#pragma unroll
            for (int t = 0; t < 9; ++t) w9[t] = ldsW[chg * 9 + t];
#pragma unroll
            for (int yy = 0; yy < 4; ++yy) {
                int y = wv * 4 + yy;
                float ln[3][18];
#pragma unroll
                for (int hr = 0; hr < 3; ++hr) {
                    int hy = y + hr;
#pragma unroll
                    for (int hx = 0; hx < 18; ++hx)
                        ln[hr][hx] = bfu((unsigned short)ldsA[(hy * 18 + hx) * 64 +
                                         ((((ch >> 3) + hx + 2 * hy) & 7) << 3) + (ch & 7)]);
                }
                float ox[16];
#pragma unroll
                for (int xx = 0; xx < 16; ++xx) {
                    float s = 0.f;
#pragma unroll
                    for (int hr = 0; hr < 3; ++hr)
#pragma unroll
                        for (int dx = 0; dx < 3; ++dx)
                            s = fmaf(ln[hr][xx + dx], w9[hr * 3 + dx], s);
                    ox[xx] = s;
                }
                if (g3 == 2) {
                    const unsigned short* fp = filt + ((size_t)b * 64 + ch) * NP
                                                    + (size_t)(y0 + y) * WH + x0;
                    u16x8 f0 = *(const u16x8*)fp;
                    u16x8 f1 = *(const u16x8*)(fp + 8);
#pragma unroll
                    for (int k = 0; k < 8; ++k) ox[k]     = fmaf(ox[k],     bfu(f0[k]), ox[k]);
#pragma unroll
                    for (int k = 0; k < 8; ++k) ox[8 + k] = fmaf(ox[8 + k], bfu(f1[k]), ox[8 + k]);
                }
                u16x8 s0, s1;
#pragma unroll
                for (int k = 0; k < 8; ++k) { s0[k] = (unsigned short)f2bf(ox[k]);
                                              s1[k] = (unsigned short)f2bf(ox[8 + k]); }
                unsigned short* op = qkv + ((size_t)b * 192 + chg) * NP + (size_t)(y0 + y) * WH + x0;
                *(u16x8*)op = s0;
                *(u16x8*)(op + 8) = s1;
            }
        }
        __syncthreads();
    }
}

// ---------------- attention dots + sum-of-squares (stage 1, split over n, vectorized) ----------------
__global__ __launch_bounds__(256) void k_attn_dot(const unsigned short* __restrict__ qkv,
                                                  float* __restrict__ praw,
                                                  float* __restrict__ praw2) {
    int bhd = blockIdx.x, sp = blockIdx.y;   // grid (32, 8)
    int b = bhd >> 3, hd = bhd & 7;
    const unsigned short* qb = qkv + ((size_t)b * 192 + hd * 8) * NP;
    const unsigned short* kb = qkv + ((size_t)b * 192 + 64 + hd * 8) * NP;
    float acc[64], acc2[16];
#pragma unroll
    for (int i = 0; i < 64; ++i) acc[i] = 0.f;
#pragma unroll
    for (int i = 0; i < 16; ++i) acc2[i] = 0.f;
    int n0 = sp * (NP / 8);
#pragma unroll 2
    for (int it = 0; it < 4; ++it) {
        int n = n0 + (it * 256 + threadIdx.x) * 8;
        u16x8 q8[8], k8[8];
#pragma unroll
        for (int c2 = 0; c2 < 8; ++c2) q8[c2] = *(const u16x8*)(qb + (size_t)c2 * NP + n);
#pragma unroll
        for (int d2 = 0; d2 < 8; ++d2) k8[d2] = *(const u16x8*)(kb + (size_t)d2 * NP + n);
#pragma unroll
        for (int j = 0; j < 8; ++j) {
            float qv[8], kv[8];
#pragma unroll
            for (int c2 = 0; c2 < 8; ++c2) qv[c2] = bfu(q8[c2][j]);
#pragma unroll
            for (int d2 = 0; d2 < 8; ++d2) kv[d2] = bfu(k8[d2][j]);
#pragma unroll
            for (int c2 = 0; c2 < 8; ++c2) {
                acc2[c2] = fmaf(qv[c2], qv[c2], acc2[c2]);
#pragma unroll
                for (int d2 = 0; d2 < 8; ++d2)
                    acc[c2 * 8 + d2] = fmaf(qv[c2], kv[d2], acc[c2 * 8 + d2]);
            }
#pragma unroll
            for (int d2 = 0; d2 < 8; ++d2) acc2[8 + d2] = fmaf(kv[d2], kv[d2], acc2[8 + d2]);
        }
    }
    __shared__ float red[4][64];
#pragma unroll
    for (int i = 0; i < 64; ++i) {
        float v = acc[i];
#pragma unroll
        for (int off = 32; off; off >>= 1) v += __shfl_down(v, off);
        if ((threadIdx.x & 63) == 0) red[threadIdx.x >> 6][i] = v;
    }
    __syncthreads();
    if (threadIdx.x < 64)
        praw[((size_t)sp * 32 + bhd) * 64 + threadIdx.x] =
            red[0][threadIdx.x] + red[1][threadIdx.x] + red[2][threadIdx.x] + red[3][threadIdx.x];
    __syncthreads();
#pragma unroll
    for (int i = 0; i < 16; ++i) {
        float v = acc2[i];
#pragma unroll
        for (int off = 32; off; off >>= 1) v += __shfl_down(v, off);
        if ((threadIdx.x & 63) == 0) red[threadIdx.x >> 6][i] = v;
    }
    __syncthreads();
    if (threadIdx.x < 16)
        praw2[((size_t)sp * 32 + bhd) * 16 + threadIdx.x] =
            red[0][threadIdx.x] + red[1][threadIdx.x] + red[2][threadIdx.x] + red[3][threadIdx.x];
}

// ---------------- scale (incl. l2norm) + softmax (stage 2) ----------------
__global__ __launch_bounds__(64) void k_attn_soft(const float* __restrict__ praw,
                                                  const float* __restrict__ praw2,
                                                  const float* __restrict__ temp,
                                                  float* __restrict__ attn) {
    int bhd = blockIdx.x;                // 32 blocks, 64 threads
    int hd = bhd & 7;
    int t = threadIdx.x, c = t >> 3, d = t & 7;
    float s = 0.f, sq = 0.f, sk = 0.f;
    for (int sp = 0; sp < 8; ++sp) {
        s  += praw[((size_t)sp * 32 + bhd) * 64 + t];
        sq += praw2[((size_t)sp * 32 + bhd) * 16 + c];
        sk += praw2[((size_t)sp * 32 + bhd) * 16 + 8 + d];
    }
    float nq = fmaxf(sqrtf(sq), 1e-12f);
    float nk = fmaxf(sqrtf(sk), 1e-12f);
    s = s / (nq * nk) * temp[hd];
    __shared__ float sm[64];
    __shared__ float se[64];
    sm[t] = s;
    __syncthreads();
    float mx = -1e30f;
#pragma unroll
    for (int dd = 0; dd < 8; ++dd) mx = fmaxf(mx, sm[c * 8 + dd]);
    float e = __expf(s - mx);
    se[t] = e;
    __syncthreads();
    float sum = 0.f;
#pragma unroll
    for (int dd = 0; dd < 8; ++dd) sum += se[c * 8 + dd];
    attn[(size_t)bhd * 64 + t] = e / sum;
}

// ---------------- M_b = W_proj x blockdiag(attn_b) -> bf16 B-fragments ----------------
// mrep[b][((oct*8 + icb)*16 + o16)*8 + j] = M[oc=oct*16+o16][ic=icb*8+j]
__global__ __launch_bounds__(256) void k_prep_attn(const float* __restrict__ attn,
                                                   const float* __restrict__ wproj,
                                                   short* __restrict__ mrep) {
    int b = blockIdx.x, t = threadIdx.x;
    const float* ab = attn + (size_t)b * 512;
#pragma unroll
    for (int i = 0; i < 16; ++i) {
        int idx = t * 16 + i;
        int j = idx & 7, o16 = (idx >> 3) & 15, icb = (idx >> 7) & 7, oct = idx >> 10;
        int oc = oct * 16 + o16;
        float m = 0.f;
#pragma unroll
        for (int c8 = 0; c8 < 8; ++c8)
            m = fmaf(wproj[(size_t)oc * 64 + icb * 8 + c8], ab[icb * 64 + c8 * 8 + j], m);
        mrep[(size_t)b * 4096 + idx] = f2bf(m);
    }
}

// ---------------- fused (W·attn)·v via MFMA + IDWT -> fp32 out ----------------
// grid (256 tiles, BN), 4 waves. A = v[px][ch] (scalar loads), B = M_b frags, D = [px][oc].
__global__ __launch_bounds__(256) void k_attnout_idwt(const unsigned short* __restrict__ qkv,
                                                      const bfx8* __restrict__ mrep,
                                                      const unsigned short* __restrict__ yht,
                                                      float* __restrict__ out) {
    const int tid = threadIdx.x;
    const int l = tid & 63, wv = tid >> 6;
    const int lx = l & 15, lq = l >> 4;
    const int tile = blockIdx.x, b = blockIdx.y;
    const int x0 = (tile & 15) * 16, y0 = (tile >> 4) * 16;
    const unsigned short* vb = qkv + ((size_t)b * 192 + 128) * NP;
    const bfx8* mb = mrep + (size_t)b * 512;

    bfx8 bw[2][4];
#pragma unroll
    for (int kc = 0; kc < 2; ++kc)
#pragma unroll
        for (int nt = 0; nt < 4; ++nt)
            bw[kc][nt] = mb[(nt * 8 + kc * 4 + lq) * 16 + lx];

    const unsigned short* yb = yht + (size_t)(b * 256 + tile) * 192 * 256;

#pragma unroll
    for (int pg = 0; pg < 4; ++pg) {
        const int mt = wv * 4 + pg;
        const int y = y0 + mt;
        const unsigned short* vrow = vb + (size_t)y * WH + x0 + lx;
        bfx8 a0, a1;
#pragma unroll
        for (int j = 0; j < 8; ++j) a0[j] = (short)vrow[(size_t)(lq * 8 + j) * NP];
#pragma unroll
        for (int j = 0; j < 8; ++j) a1[j] = (short)vrow[(size_t)(32 + lq * 8 + j) * NP];

        f32x4 acc[4];
#pragma unroll
        for (int nt = 0; nt < 4; ++nt) acc[nt] = (f32x4){0.f, 0.f, 0.f, 0.f};
#pragma unroll
        for (int nt = 0; nt < 4; ++nt) {
            acc[nt] = __builtin_amdgcn_mfma_f32_16x16x32_bf16(a0, bw[0][nt], acc[nt], 0, 0, 0);
            acc[nt] = __builtin_amdgcn_mfma_f32_16x16x32_bf16(a1, bw[1][nt], acc[nt], 0, 0, 0);
        }
#pragma unroll
        for (int nt = 0; nt < 4; ++nt) {
            const int oc = nt * 16 + lx;
            const int inner = mt * 16 + lq * 4;
            const unsigned short* yp = yb + (size_t)oc * 256 + inner;
            u16x4 lh4 = *(const u16x4*)yp;
            u16x4 hl4 = *(const u16x4*)(yp + (size_t)64 * 256);
            u16x4 hh4 = *(const u16x4*)(yp + (size_t)128 * 256);
            float e0[8], e1[8];
#pragma unroll
            for (int r = 0; r < 4; ++r) {
                float s  = acc[nt][r];
                float LH = bfu(lh4[r]), HL = bfu(hl4[r]), HHv = bfu(hh4[r]);
                e0[2 * r]     = (s - LH - HL + HHv) * 0.5f;
                e0[2 * r + 1] = (s - LH + HL - HHv) * 0.5f;
                e1[2 * r]     = (s + LH - HL - HHv) * 0.5f;
                e1[2 * r + 1] = (s + LH + HL + HHv) * 0.5f;
            }
            float* o0 = out + ((size_t)(b * 64 + oc) * HF + 2 * y) * WF + 2 * (x0 + lq * 4);
            *(float4*)o0            = *(float4*)&e0[0];
            *(float4*)(o0 + 4)      = *(float4*)&e0[4];
            *(float4*)(o0 + WF)     = *(float4*)&e1[0];
            *(float4*)(o0 + WF + 4) = *(float4*)&e1[4];
        }
    }
}

extern "C" void kernel_launch(void* const* d_in, const int* in_sizes, int n_in,
                              void* d_out, int out_size, void* d_ws, size_t ws_size,
                              hipStream_t stream) {
    const float* x      = (const float*)d_in[0];
    const float* w_hc1  = (const float*)d_in[1];
    const float* w_hc2  = (const float*)d_in[2];
    const float* w_ho   = (const float*)d_in[3];
    const float* w_qkv  = (const float*)d_in[4];
    const float* w_dw   = (const float*)d_in[5];
    const float* w_proj = (const float*)d_in[6];
    const float* temp   = (const float*)d_in[7];
    float* out = (float*)d_out;

    char* base = (char*)d_ws;
    unsigned short* TILED = (unsigned short*)(base + 0);             // 12 padded planes
    unsigned short* LLP   = (unsigned short*)(base + 102242304ULL);  // 4 padded planes (LL)
    unsigned short* YH    = (unsigned short*)(base + 136323072ULL);  // 96 MiB bf16 tile-major
    unsigned short* T1T   = (unsigned short*)(base + 236986368ULL);  // 64 MiB bf16 tiled [..][128]
    unsigned short* FILT  = (unsigned short*)(base + 304095232ULL);  // 32 MiB bf16 [b][64][NP]
    unsigned short* QKV   = (unsigned short*)(base + 337649664ULL);  // 96 MiB bf16 [b][192][NP]
    float*          PRAW  = (float*)(base + 438312960ULL);
    float*          PRAW2 = (float*)(base + 438378496ULL);
    float*          ATTN  = (float*)(base + 438394880ULL);
    short* WREP_HO  = (short*)(base + 438403072ULL);
    short* WREP_HC1 = (short*)(base + 438624256ULL);
    short* WREP_HC2 = (short*)(base + 438771712ULL);
    short* WREP_QKV = (short*)(base + 438788096ULL);
    short* MREP     = (short*)(base + 438812672ULL);                 // BN*4096 bf16

    // 0. merged setup: ring-zero 16 planes + all repacks (816 blocks)
    k_setup<<<816, 256, 0, stream>>>(TILED, w_ho, w_hc1, w_hc2, w_qkv,
                                     WREP_HO, WREP_HC1, WREP_HC2, WREP_QKV);
    // 1. DWT -> padded bf16 LH/HL/HH + LL
    k_dwt<<<dim3(512, BN), 256, 0, stream>>>(x, TILED, LLP);
    // 2. yh = relu(gconv3x3(LH,HL,HH; w_ho, groups=3)) -> tile-major bf16
    k_gconv3x3_mfma<0><<<dim3(256, 3, BN), 256, 0, stream>>>(TILED, (const bfx8*)WREP_HO, YH, 192);
    // 3. t1 = relu(gconv3x3(LH,HL; w_hc1, groups=2)) -> tiled-interleaved bf16
    k_gconv3x3_mfma<1><<<dim3(256, 2, BN), 256, 0, stream>>>(TILED, (const bfx8*)WREP_HC1, T1T, 128);
    // 4. filter_hv = relu(1x1(t1, w_hc2)) -> planar bf16
    k_conv1x1_mfma<128, 64, true><<<dim3(256, BN), 256, 0, stream>>>(T1T, (const bfx8*)WREP_HC2, FILT);
    // 5. qkv = dw3x3(1x1(LL, w_qkv)) with v-filter, fused -> planar bf16
    k_qkv_fused<<<dim3(256, BN), 256, 0, stream>>>(LLP, (const bfx8*)WREP_QKV, w_dw, FILT, QKV);
    // 6-7. attention scores (+sumsq) + softmax (incl. l2norm)
    k_attn_dot<<<dim3(32, 8), 256, 0, stream>>>(QKV, PRAW, PRAW2);
    k_attn_soft<<<32, 64, 0, stream>>>(PRAW, PRAW2, temp, ATTN);
    // 8. M_b = W*blockdiag(attn) -> bf16 fragments
    k_prep_attn<<<BN, 256, 0, stream>>>(ATTN, w_proj, MREP);
    // 9. fused (W*attn)*v via MFMA + IDWT -> fp32 out
    k_attnout_idwt<<<dim3(256, BN), 256, 0, stream>>>(QKV, (const bfx8*)MREP, YH, out);
}

// Round 9
// 563.650 us; speedup vs baseline: 4.9160x; 1.0696x over previous
//
#include <hip/hip_runtime.h>
#include <hip/hip_bf16.h>

#define BN 4
#define DIM 64
#define NHEADS 8
#define HH 256
#define WH 256
#define NP (HH*WH)      // 65536
#define HF 512
#define WF 512

#define PD 258                       // padded dim
#define PROW (PD*64)                 // shorts per padded row
#define PPLANE ((size_t)PD*PD*64)    // shorts per padded plane

typedef __attribute__((ext_vector_type(8))) short bfx8;           // 8 bf16
typedef __attribute__((ext_vector_type(8))) unsigned short u16x8; // 8 bf16 bits
typedef __attribute__((ext_vector_type(4))) unsigned short u16x4; // 4 bf16 bits
typedef __attribute__((ext_vector_type(4))) float f32x4;          // MFMA C/D frag

static __device__ __forceinline__ short f2bf(float f) {
    unsigned u = __float_as_uint(f);
    unsigned r = (u + 0x7FFFu + ((u >> 16) & 1u)) >> 16;   // RNE
    return (short)r;
}
static __device__ __forceinline__ float bfu(unsigned short u) {
    return __uint_as_float((unsigned)u << 16);
}

// ---------------- merged setup: ring-zero 16 planes + all weight repacks ----------------
__global__ __launch_bounds__(256) void k_setup(unsigned short* __restrict__ tiled16,
                                               const float* __restrict__ w_ho,
                                               const float* __restrict__ w_hc1,
                                               const float* __restrict__ w_hc2,
                                               const float* __restrict__ w_qkv,
                                               short* __restrict__ wrHO,
                                               short* __restrict__ wrHC1,
                                               short* __restrict__ wrHC2,
                                               short* __restrict__ wrQKV) {
    int bx = blockIdx.x, tid = threadIdx.x;
    if (bx < 16) {                        // pad-ring zero, 16 planes (12 TILED + 4 LLP)
        char* base = (char*)(tiled16 + (size_t)bx * PPLANE);
        const int ROWB = PROW * 2;
        for (int k = tid; k < 8224; k += 256) {
            char* dst;
            if (k < 2064) dst = base + (size_t)k * 16;
            else if (k < 4128) dst = base + (size_t)257 * ROWB + (size_t)(k - 2064) * 16;
            else if (k < 6176) { int r = (k - 4128) >> 3, s = (k - 4128) & 7;
                dst = base + (size_t)(r + 1) * ROWB + (size_t)s * 16; }
            else { int r = (k - 6176) >> 3, s = (k - 6176) & 7;
                dst = base + (size_t)(r + 1) * ROWB + 257 * 128 + (size_t)s * 16; }
            *(uint4*)dst = (uint4){0, 0, 0, 0};
        }
        return;
    }
    if (bx < 16 + 432 + 288) {            // 3x3 repacks: OIHW -> [g][tap][icb][oc][8]
        const float* w = (bx < 448) ? w_ho : w_hc1;
        short* wrep = (bx < 448) ? wrHO : wrHC1;
        int t = (bx - ((bx < 448) ? 16 : 448)) * 256 + tid;
        unsigned g   = (unsigned)t / 36864u;
        unsigned r1  = (unsigned)t % 36864u;
        unsigned tap = r1 / 4096u;
        unsigned r2  = r1 % 4096u;
        unsigned icb = r2 / 512u;
        unsigned r3  = r2 % 512u;
        unsigned oc  = r3 >> 3;
        unsigned j   = r3 & 7u;
        wrep[t] = f2bf(w[(((size_t)g * 64 + oc) * 64 + icb * 8u + j) * 9 + tap]);
        return;
    }
    if (bx < 16 + 432 + 288 + 32) {       // w_hc2 [64][128] -> [oct][icb][oc16][8]
        int t = (bx - 736) * 256 + tid;
        int j = t & 7, gr = t >> 3, o16 = gr & 15, X = gr >> 4;
        int icb = X % 16, oct = X / 16;
        wrHC2[t] = f2bf(w_hc2[(size_t)(oct * 16 + o16) * 128 + icb * 8 + j]);
        return;
    }
    {                                     // w_qkv [192][64] -> [oct][icb][oc16][8]
        int t = (bx - 768) * 256 + tid;
        int j = t & 7, gr = t >> 3, o16 = gr & 15, X = gr >> 4;
        int icb = X % 8, oct = X / 8;
        wrQKV[t] = f2bf(w_qkv[(size_t)(oct * 16 + o16) * 64 + icb * 8 + j]);
    }
}

// ---------------- DWT -> 4 padded-swizzled bf16 planes (LH/HL/HH in TILED, LL in LLP) ----------------
__global__ __launch_bounds__(256) void k_dwt(const float* __restrict__ x,
                                             unsigned short* __restrict__ tiled,
                                             unsigned short* __restrict__ llp) {
    __shared__ unsigned short lds[3 * 128 * 64] __attribute__((aligned(16)));
    const int tid = threadIdx.x;
    const int pid = blockIdx.x;              // 512 = 32 y-patches x 16 x-patches
    const int b = blockIdx.y;
    const int y0 = (pid >> 4) * 8, x0 = (pid & 15) * 16;
    const int quad = tid & 127;
    const int qy = quad >> 4, qx = quad & 15;
    const int gy = y0 + qy, gx = x0 + qx;
    const int ich = tid >> 7;                // 0/1
    unsigned short* llb = llp + (size_t)b * PPLANE + ((size_t)(gy + 1) * PD + (gx + 1)) * 64;

#pragma unroll 4
    for (int it = 0; it < 16; ++it) {
        int ic = it * 4 + ich * 2;           // handle ic, ic+1 (pair => b32 writes)
        unsigned g = (((unsigned)(ic >> 3)) + (unsigned)gx + 2u * (unsigned)gy) & 7u;
        unsigned swz = (unsigned)quad * 64 + (g << 3) + (unsigned)(ic & 7);
        unsigned pk[3], pll;
#pragma unroll
        for (int s = 0; s < 2; ++s) {
            const float* px = x + (((size_t)(b * 64 + ic + s) * HF) + 2 * gy) * WF + 2 * gx;
            float2 e0 = *(const float2*)px;
            float2 e1 = *(const float2*)(px + WF);
            float a = e0.x, bb = e0.y, c = e1.x, d = e1.y;
            unsigned ll = (unsigned short)f2bf(( a + bb + c + d) * 0.5f);
            unsigned lh = (unsigned short)f2bf((-a - bb + c + d) * 0.5f);
            unsigned hl = (unsigned short)f2bf((-a + bb - c + d) * 0.5f);
            unsigned hh = (unsigned short)f2bf(( a - bb - c + d) * 0.5f);
            if (s == 0) { pll = ll; pk[0] = lh; pk[1] = hl; pk[2] = hh; }
            else { pll |= ll << 16; pk[0] |= lh << 16; pk[1] |= hl << 16; pk[2] |= hh << 16; }
        }
        *(unsigned*)&lds[swz]          = pk[0];
        *(unsigned*)&lds[8192 + swz]   = pk[1];
        *(unsigned*)&lds[16384 + swz]  = pk[2];
        *(unsigned*)&llb[(g << 3) + (unsigned)(ic & 7)] = pll;
    }
    __syncthreads();
#pragma unroll
    for (int it = 0; it < 12; ++it) {
        int cch = tid + it * 256;            // 0..3071 (uint4 chunks)
        int p = cch >> 10, rem = cch & 1023;
        int row = rem >> 7, col = rem & 127;
        unsigned short* dst = tiled + ((size_t)(b * 3 + p) * PD + (y0 + row + 1)) * PROW
                                    + (size_t)(x0 + 1) * 64 + (size_t)col * 8;
        *(uint4*)dst = *(const uint4*)((const char*)lds + (size_t)cch * 16);
    }
}

// ---------------- grouped 3x3 conv (+relu) via bf16 MFMA, padded-layout input ----------------
// LAYOUT 0: tile-major [b][tile][OC][256 inner].  LAYOUT 1: tiled-interleaved [b][tile][256][128swz].
template <int LAYOUT>
__global__ __launch_bounds__(256) void k_gconv3x3_mfma(const unsigned short* __restrict__ tiled,
                                                       const bfx8* __restrict__ wr,
                                                       unsigned short* __restrict__ out, int OC) {
    __shared__ short lds_in[324 * 64] __attribute__((aligned(16)));
    const int tid = threadIdx.x;
    const int l = tid & 63, wv = tid >> 6;
    const int tile = blockIdx.x;
    const int x0 = (tile & 15) * 16, y0 = (tile >> 4) * 16;
    const int g = blockIdx.y, b = blockIdx.z;
    const unsigned short* src = tiled + (size_t)(b * 3 + g) * PPLANE;

#pragma unroll
    for (int it = 0; it < 10; ++it) {
        int cch = it * 256 + tid;
        unsigned row = (unsigned)cch / 144u, col = (unsigned)cch % 144u;
        const unsigned short* ga = src + (size_t)(y0 + row) * PROW + (size_t)x0 * 64 + (size_t)col * 8;
        __builtin_amdgcn_global_load_lds(
            (const __attribute__((address_space(1))) void*)ga,
            (__attribute__((address_space(3))) void*)((char*)lds_in + (size_t)(it * 256 + wv * 64) * 16),
            16, 0, 0);
    }
    if (tid < 32) {
        int cch = 2560 + tid;
        unsigned row = (unsigned)cch / 144u, col = (unsigned)cch % 144u;
        const unsigned short* ga = src + (size_t)(y0 + row) * PROW + (size_t)x0 * 64 + (size_t)col * 8;
        *(uint4*)((char*)lds_in + (size_t)cch * 16) = *(const uint4*)ga;
    }
    __syncthreads();

    f32x4 acc[4][4];
#pragma unroll
    for (int i = 0; i < 4; ++i)
#pragma unroll
        for (int j = 0; j < 4; ++j) acc[i][j] = (f32x4){0.f, 0.f, 0.f, 0.f};

    const int lx = l & 15, lq = l >> 4;
#pragma unroll
    for (int c = 0; c < 2; ++c) {
        const int icb = c * 4 + lq;
#pragma unroll
        for (int tap = 0; tap < 9; ++tap) {
            const int dy = tap / 3, dx = tap % 3;
            const size_t wbase = ((size_t)(g * 9 + tap) * 8 + icb) * 64 + lx;
            bfx8 b0 = wr[wbase];
            bfx8 b1 = wr[wbase + 16];
            bfx8 b2 = wr[wbase + 32];
            bfx8 b3 = wr[wbase + 48];
#pragma unroll
            for (int pg = 0; pg < 4; ++pg) {
                int hy = wv * 4 + pg + dy, hx = lx + dx;
                int hp = hy * 18 + hx;
                const bfx8* ap = (const bfx8*)&lds_in[hp * 64 + (((icb + hx + 2 * hy + 5) & 7) << 3)];
                bfx8 a = *ap;
                acc[pg][0] = __builtin_amdgcn_mfma_f32_16x16x32_bf16(a, b0, acc[pg][0], 0, 0, 0);
                acc[pg][1] = __builtin_amdgcn_mfma_f32_16x16x32_bf16(a, b1, acc[pg][1], 0, 0, 0);
                acc[pg][2] = __builtin_amdgcn_mfma_f32_16x16x32_bf16(a, b2, acc[pg][2], 0, 0, 0);
                acc[pg][3] = __builtin_amdgcn_mfma_f32_16x16x32_bf16(a, b3, acc[pg][3], 0, 0, 0);
            }
        }
    }

#pragma unroll
    for (int pg = 0; pg < 4; ++pg) {
#pragma unroll
        for (int ocg = 0; ocg < 4; ++ocg) {
            f32x4 v = acc[pg][ocg];
            if (LAYOUT == 0) {
                // tile-major: [b][tile][oc][inner], inner = (y-y0)*16 + (x-x0)
                unsigned short* op = out + ((size_t)(b * 256 + tile) * OC + g * 64 + ocg * 16 + lx) * 256
                                         + (wv * 4 + pg) * 16 + lq * 4;
                ushort4 s4;
                s4.x = (unsigned short)f2bf(fmaxf(v.x, 0.f));
                s4.y = (unsigned short)f2bf(fmaxf(v.y, 0.f));
                s4.z = (unsigned short)f2bf(fmaxf(v.z, 0.f));
                s4.w = (unsigned short)f2bf(fmaxf(v.w, 0.f));
                *(ushort4*)op = s4;
            } else {
                int icT = g * 64 + ocg * 16 + lx;
                int g16 = icT >> 3;
                unsigned short* tb = out + ((size_t)(b * 256 + tile) * 256) * 128;
                int innerb = (wv * 4 + pg) * 16 + lq * 4;
                float vr[4] = {v.x, v.y, v.z, v.w};
#pragma unroll
                for (int r = 0; r < 4; ++r) {
                    int inn = innerb + r;
                    tb[(size_t)inn * 128 + (((g16 + inn) & 15) << 3) + (icT & 7)] =
                        (unsigned short)f2bf(fmaxf(vr[r], 0.f));
                }
            }
        }
    }
}

// ---------------- 1x1 conv via bf16 MFMA from tiled input (FILT path) ----------------
template <int CIN, int OC, bool RELU>
__global__ __launch_bounds__(256) void k_conv1x1_mfma(const unsigned short* __restrict__ inT,
                                                      const bfx8* __restrict__ wr,
                                                      unsigned short* __restrict__ out) {
    constexpr int KB = CIN / 8;
    constexpr int KC = CIN / 32;
    constexpr int NOCT = OC / 16;
    __shared__ short ldsA[256 * CIN] __attribute__((aligned(16)));
    const int tid = threadIdx.x;
    const int l = tid & 63, wv = tid >> 6;
    const int tile = blockIdx.x, b = blockIdx.y;
    const unsigned short* src = inT + ((size_t)(b * 256 + tile) * 256) * CIN;
    constexpr int ITER = (256 * CIN / 8) / 256;
#pragma unroll
    for (int it = 0; it < ITER; ++it) {
        int cc = it * 256 + tid;
        __builtin_amdgcn_global_load_lds(
            (const __attribute__((address_space(1))) void*)(src + (size_t)cc * 8),
            (__attribute__((address_space(3))) void*)((char*)ldsA + (size_t)(it * 256 + wv * 64) * 16),
            16, 0, 0);
    }
    __syncthreads();

    const int lx = l & 15, lq = l >> 4;
    const int x0 = (tile & 15) * 16, y0 = (tile >> 4) * 16;
#pragma unroll
    for (int o4 = 0; o4 < NOCT / 4; ++o4) {
        f32x4 acc[4][4];
#pragma unroll
        for (int i = 0; i < 4; ++i)
#pragma unroll
            for (int j = 0; j < 4; ++j) acc[i][j] = (f32x4){0.f, 0.f, 0.f, 0.f};
#pragma unroll
        for (int c = 0; c < KC; ++c) {
            const int icb = c * 4 + lq;
            bfx8 bf[4];
#pragma unroll
            for (int ot = 0; ot < 4; ++ot)
                bf[ot] = wr[(size_t)(((o4 * 4 + ot) * KB + icb) * 16) + lx];
#pragma unroll
            for (int pg = 0; pg < 4; ++pg) {
                int inner = (wv * 4 + pg) * 16 + lx;
                const bfx8* ap = (const bfx8*)&ldsA[inner * CIN + (((icb + inner) & (KB - 1)) << 3)];
                bfx8 a = *ap;
                acc[pg][0] = __builtin_amdgcn_mfma_f32_16x16x32_bf16(a, bf[0], acc[pg][0], 0, 0, 0);
                acc[pg][1] = __builtin_amdgcn_mfma_f32_16x16x32_bf16(a, bf[1], acc[pg][1], 0, 0, 0);
                acc[pg][2] = __builtin_amdgcn_mfma_f32_16x16x32_bf16(a, bf[2], acc[pg][2], 0, 0, 0);
                acc[pg][3] = __builtin_amdgcn_mfma_f32_16x16x32_bf16(a, bf[3], acc[pg][3], 0, 0, 0);
            }
        }
#pragma unroll
        for (int pg = 0; pg < 4; ++pg)
#pragma unroll
            for (int ot = 0; ot < 4; ++ot) {
                int oc = (o4 * 4 + ot) * 16 + lx;
                unsigned short* op = out + ((size_t)b * OC + oc) * NP
                                         + (size_t)(y0 + wv * 4 + pg) * WH + x0 + lq * 4;
                f32x4 v = acc[pg][ot];
                ushort4 s4;
                s4.x = (unsigned short)f2bf(RELU ? fmaxf(v.x, 0.f) : v.x);
                s4.y = (unsigned short)f2bf(RELU ? fmaxf(v.y, 0.f) : v.y);
                s4.z = (unsigned short)f2bf(RELU ? fmaxf(v.z, 0.f) : v.z);
                s4.w = (unsigned short)f2bf(RELU ? fmaxf(v.w, 0.f) : v.w);
                *(ushort4*)op = s4;
            }
    }
}

// ---------------- fused 1x1-qkv + dw3x3 + v-filter + per-tile attention dots ----------------
// outputs: VT [b][tile][256 inner][64 ch] bf16 (v only), praw/praw2 per-tile S partials.
__global__ __launch_bounds__(256) void k_qkv_fused(const unsigned short* __restrict__ llp,
                                                   const bfx8* __restrict__ wrq,
                                                   const float* __restrict__ wdw,
                                                   const unsigned short* __restrict__ filt,
                                                   unsigned short* __restrict__ vt,
                                                   float* __restrict__ praw,
                                                   float* __restrict__ praw2) {
    __shared__ short ldsA[336 * 64] __attribute__((aligned(16)));   // halo/qkv0; 1st 32KB -> kbuf
    __shared__ short qsave[64 * 256] __attribute__((aligned(16)));  // q post-dw; -> sred (f32)
    __shared__ float ssq[2][4][64];
    const int tid = threadIdx.x;
    const int l = tid & 63, wv = tid >> 6;
    const int tile = blockIdx.x, b = blockIdx.y;
    const int x0 = (tile & 15) * 16, y0 = (tile >> 4) * 16;
    const unsigned short* src = llp + (size_t)b * PPLANE;

    // stage 18x18x64 halo: 2592 uint4 chunks
#pragma unroll
    for (int it = 0; it < 10; ++it) {
        int cch = it * 256 + tid;
        unsigned row = (unsigned)cch / 144u, col = (unsigned)cch % 144u;
        const unsigned short* ga = src + (size_t)(y0 + row) * PROW + (size_t)x0 * 64 + (size_t)col * 8;
        __builtin_amdgcn_global_load_lds(
            (const __attribute__((address_space(1))) void*)ga,
            (__attribute__((address_space(3))) void*)((char*)ldsA + (size_t)(it * 256 + wv * 64) * 16),
            16, 0, 0);
    }
    if (tid < 32) {
        int cch = 2560 + tid;
        unsigned row = (unsigned)cch / 144u, col = (unsigned)cch % 144u;
        const unsigned short* ga = src + (size_t)(y0 + row) * PROW + (size_t)x0 * 64 + (size_t)col * 8;
        *(uint4*)((char*)ldsA + (size_t)cch * 16) = *(const uint4*)ga;
    }
    __syncthreads();

    // hoist A-frags for my M-tiles into regs (static indexing)
    const int lx = l & 15, lq = l >> 4;
    bfx8 af[6][2];
#pragma unroll
    for (int m = 0; m < 6; ++m) {
        int mt = wv + 4 * m;
        if (mt < 21) {
            int hp = mt * 16 + lx;
            int hy = hp / 18, hx = hp - hy * 18;
#pragma unroll
            for (int kc = 0; kc < 2; ++kc) {
                int icb = kc * 4 + lq;
                af[m][kc] = *(const bfx8*)&ldsA[hp * 64 + (((icb + hx + 2 * hy + 5) & 7) << 3)];
            }
        }
    }
    __syncthreads();   // all halo reads done before overwrite

    for (int g3 = 0; g3 < 3; ++g3) {
        // B-frags for this 64-oc group (L2-resident weights)
        bfx8 bw[2][4];
#pragma unroll
        for (int kc = 0; kc < 2; ++kc)
#pragma unroll
            for (int nt = 0; nt < 4; ++nt)
                bw[kc][nt] = wrq[(size_t)(((g3 * 4 + nt) * 8) + kc * 4 + lq) * 16 + lx];
        // MFMA + write qkv0 to LDS [hp][64 swz]
#pragma unroll
        for (int m = 0; m < 6; ++m) {
            int mt = wv + 4 * m;
            if (mt < 21) {
                f32x4 acc[4];
#pragma unroll
                for (int nt = 0; nt < 4; ++nt) acc[nt] = (f32x4){0.f, 0.f, 0.f, 0.f};
#pragma unroll
                for (int kc = 0; kc < 2; ++kc) {
                    bfx8 a = af[m][kc];
#pragma unroll
                    for (int nt = 0; nt < 4; ++nt)
                        acc[nt] = __builtin_amdgcn_mfma_f32_16x16x32_bf16(a, bw[kc][nt], acc[nt], 0, 0, 0);
                }
#pragma unroll
                for (int nt = 0; nt < 4; ++nt) {
                    int ocl = nt * 16 + lx;
                    float vr[4] = {acc[nt].x, acc[nt].y, acc[nt].z, acc[nt].w};
#pragma unroll
                    for (int r = 0; r < 4; ++r) {
                        int hp2 = mt * 16 + lq * 4 + r;
                        int hy2 = hp2 / 18, hx2 = hp2 - hy2 * 18;
                        ldsA[hp2 * 64 + ((((ocl >> 3) + hx2 + 2 * hy2) & 7) << 3) + (ocl & 7)] =
                            f2bf(vr[r]);
                    }
                }
            }
        }
        __syncthreads();
        // depthwise 3x3: lane = ch, wave = 4-row segment
        const int ch = l, chg = g3 * 64 + ch;
        float w9[9];
#pragma unroll
        for (int t = 0; t < 9; ++t) w9[t] = wdw[chg * 9 + t];
        float s2 = 0.f;
        u16x8 kpk[4][2];                 // k post-dw (g3==1) held until kbuf write
#pragma unroll
        for (int yy = 0; yy < 4; ++yy) {
            int y = wv * 4 + yy;
            float ln[3][18];
#pragma unroll
            for (int hr = 0; hr < 3; ++hr) {
                int hy = y + hr;
#pragma unroll
                for (int hx = 0; hx < 18; ++hx)
                    ln[hr][hx] = bfu((unsigned short)ldsA[(hy * 18 + hx) * 64 +
                                     ((((ch >> 3) + hx + 2 * hy) & 7) << 3) + (ch & 7)]);
            }
            float ox[16];
#pragma unroll
            for (int xx = 0; xx < 16; ++xx) {
                float s = 0.f;
#pragma unroll
                for (int hr = 0; hr < 3; ++hr)
#pragma unroll
                    for (int dx = 0; dx < 3; ++dx)
                        s = fmaf(ln[hr][xx + dx], w9[hr * 3 + dx], s);
                ox[xx] = s;
            }
            if (g3 == 2) {
                const unsigned short* fp = filt + ((size_t)b * 64 + ch) * NP
                                                + (size_t)(y0 + y) * WH + x0;
                u16x8 f0 = *(const u16x8*)fp;
                u16x8 f1 = *(const u16x8*)(fp + 8);
#pragma unroll
                for (int k = 0; k < 8; ++k) ox[k]     = fmaf(ox[k],     bfu(f0[k]), ox[k]);
#pragma unroll
                for (int k = 0; k < 8; ++k) ox[8 + k] = fmaf(ox[8 + k], bfu(f1[k]), ox[8 + k]);
                // v -> VT [inner][ch]
                unsigned short* vb = vt + ((size_t)(b * 256 + tile) * 256 + (size_t)y * 16) * 64 + ch;
#pragma unroll
                for (int xx = 0; xx < 16; ++xx) vb[xx * 64] = (unsigned short)f2bf(ox[xx]);
            } else {
#pragma unroll
                for (int xx = 0; xx < 16; ++xx) s2 = fmaf(ox[xx], ox[xx], s2);
                if (g3 == 0) {           // q -> qsave [ch][px swz]
#pragma unroll
                    for (int xx = 0; xx < 16; ++xx) {
                        int px = y * 16 + xx;
                        qsave[ch * 256 + ((((px >> 3) + ch) & 31) << 3) + (px & 7)] =
                            f2bf(ox[xx]);
                    }
                } else {                 // k -> regs (kbuf write deferred past barrier)
#pragma unroll
                    for (int xx = 0; xx < 8; ++xx)  kpk[yy][0][xx] = (unsigned short)f2bf(ox[xx]);
#pragma unroll
                    for (int xx = 0; xx < 8; ++xx)  kpk[yy][1][xx] = (unsigned short)f2bf(ox[8 + xx]);
                }
            }
        }
        if (g3 == 0) ssq[0][wv][ch] = s2;
        if (g3 == 1) {
            ssq[1][wv][ch] = s2;
            __syncthreads();             // all ldsA (qkv0-k) reads done
            // k -> kbuf (aliases ldsA) [ch][px swz]
            short* kbuf = ldsA;
#pragma unroll
            for (int yy = 0; yy < 4; ++yy) {
                int y = wv * 4 + yy;
#pragma unroll
                for (int xx = 0; xx < 16; ++xx) {
                    int px = y * 16 + xx;
                    kbuf[ch * 256 + ((((px >> 3) + ch) & 31) << 3) + (px & 7)] =
                        (short)kpk[yy][xx >> 3][xx & 7];
                }
            }
            __syncthreads();             // kbuf + qsave ready
            // S partial via MFMA: wave wv covers K-chunks 2wv, 2wv+1 (its own 64 px)
            f32x4 sacc[4];
#pragma unroll
            for (int t16 = 0; t16 < 4; ++t16) sacc[t16] = (f32x4){0.f, 0.f, 0.f, 0.f};
#pragma unroll
            for (int kc2 = 0; kc2 < 2; ++kc2) {
                int kc = wv * 2 + kc2;
#pragma unroll
                for (int t16 = 0; t16 < 4; ++t16) {
                    int chh = t16 * 16 + lx;
                    int go = chh * 256 + (((kc * 4 + lq + chh) & 31) << 3);
                    bfx8 aq = *(const bfx8*)&qsave[go];
                    bfx8 bk = *(const bfx8*)&kbuf[go];
                    sacc[t16] = __builtin_amdgcn_mfma_f32_16x16x32_bf16(aq, bk, sacc[t16], 0, 0, 0);
                }
            }
            __syncthreads();             // qsave/kbuf reads done
            float* sred = (float*)qsave; // alias
#pragma unroll
            for (int t16 = 0; t16 < 4; ++t16)
                *(f32x4*)&sred[((wv * 4 + t16) * 64 + l) * 4] = sacc[t16];
            __syncthreads();
            {   // cross-wave reduce -> praw; sumsq -> praw2
                int t16r = tid >> 6, lr = tid & 63;
                f32x4 s0 = *(const f32x4*)&sred[((0 * 4 + t16r) * 64 + lr) * 4];
                f32x4 s1 = *(const f32x4*)&sred[((1 * 4 + t16r) * 64 + lr) * 4];
                f32x4 s2r = *(const f32x4*)&sred[((2 * 4 + t16r) * 64 + lr) * 4];
                f32x4 s3 = *(const f32x4*)&sred[((3 * 4 + t16r) * 64 + lr) * 4];
                f32x4 sum = s0 + s1 + s2r + s3;
                *(f32x4*)&praw[(((size_t)(b * 256 + tile) * 4 + t16r) * 64 + lr) * 4] = sum;
                if (tid < 128) {
                    int which = tid >> 6, chh = tid & 63;
                    praw2[(size_t)(b * 256 + tile) * 128 + tid] =
                        ssq[which][0][chh] + ssq[which][1][chh] +
                        ssq[which][2][chh] + ssq[which][3][chh];
                }
            }
        }
        __syncthreads();
    }
}

// ---------------- scale (incl. l2norm) + softmax over per-tile partials ----------------
__global__ __launch_bounds__(64) void k_attn_soft(const float* __restrict__ praw,
                                                  const float* __restrict__ praw2,
                                                  const float* __restrict__ temp,
                                                  float* __restrict__ attn) {
    int bhd = blockIdx.x;                // 32 blocks, 64 threads
    int b = bhd >> 3, hd = bhd & 7;
    int t = threadIdx.x, c = t >> 3, d = t & 7;
    int t16 = hd >> 1, half = hd & 1;
    int cl = half * 8 + c, dl = half * 8 + d;
    const float* pb = praw + ((size_t)(b * 256) * 4 + t16) * 256 + ((cl >> 2) * 16 + dl) * 4 + (cl & 3);
    const float* p2 = praw2 + (size_t)(b * 256) * 128;
    float s = 0.f, sq = 0.f, sk = 0.f;
    for (int tile = 0; tile < 256; ++tile) {
        s  += pb[(size_t)tile * 1024];
        sq += p2[(size_t)tile * 128 + hd * 8 + c];
        sk += p2[(size_t)tile * 128 + 64 + hd * 8 + d];
    }
    float nq = fmaxf(sqrtf(sq), 1e-12f);
    float nk = fmaxf(sqrtf(sk), 1e-12f);
    s = s / (nq * nk) * temp[hd];
    __shared__ float sm[64];
    __shared__ float se[64];
    sm[t] = s;
    __syncthreads();
    float mx = -1e30f;
#pragma unroll
    for (int dd = 0; dd < 8; ++dd) mx = fmaxf(mx, sm[c * 8 + dd]);
    float e = __expf(s - mx);
    se[t] = e;
    __syncthreads();
    float sum = 0.f;
#pragma unroll
    for (int dd = 0; dd < 8; ++dd) sum += se[c * 8 + dd];
    attn[(size_t)bhd * 64 + t] = e / sum;
}

// ---------------- M_b = W_proj x blockdiag(attn_b) -> bf16 B-fragments ----------------
__global__ __launch_bounds__(256) void k_prep_attn(const float* __restrict__ attn,
                                                   const float* __restrict__ wproj,
                                                   short* __restrict__ mrep) {
    int b = blockIdx.x, t = threadIdx.x;
    const float* ab = attn + (size_t)b * 512;
#pragma unroll
    for (int i = 0; i < 16; ++i) {
        int idx = t * 16 + i;
        int j = idx & 7, o16 = (idx >> 3) & 15, icb = (idx >> 7) & 7, oct = idx >> 10;
        int oc = oct * 16 + o16;
        float m = 0.f;
#pragma unroll
        for (int c8 = 0; c8 < 8; ++c8)
            m = fmaf(wproj[(size_t)oc * 64 + icb * 8 + c8], ab[icb * 64 + c8 * 8 + j], m);
        mrep[(size_t)b * 4096 + idx] = f2bf(m);
    }
}

// ---------------- fused (W·attn)·v via MFMA + IDWT -> fp32 out ----------------
__global__ __launch_bounds__(256) void k_attnout_idwt(const unsigned short* __restrict__ vt,
                                                      const bfx8* __restrict__ mrep,
                                                      const unsigned short* __restrict__ yht,
                                                      float* __restrict__ out) {
    const int tid = threadIdx.x;
    const int l = tid & 63, wv = tid >> 6;
    const int lx = l & 15, lq = l >> 4;
    const int tile = blockIdx.x, b = blockIdx.y;
    const int x0 = (tile & 15) * 16, y0 = (tile >> 4) * 16;
    const bfx8* vtb = (const bfx8*)(vt + (size_t)(b * 256 + tile) * 256 * 64);
    const bfx8* mb = mrep + (size_t)b * 512;

    bfx8 bw[2][4];
#pragma unroll
    for (int kc = 0; kc < 2; ++kc)
#pragma unroll
        for (int nt = 0; nt < 4; ++nt)
            bw[kc][nt] = mb[(nt * 8 + kc * 4 + lq) * 16 + lx];

    const unsigned short* yb = yht + (size_t)(b * 256 + tile) * 192 * 256;

#pragma unroll
    for (int pg = 0; pg < 4; ++pg) {
        const int mt = wv * 4 + pg;
        const int y = y0 + mt;
        bfx8 a0 = vtb[(mt * 16 + lx) * 8 + lq];
        bfx8 a1 = vtb[(mt * 16 + lx) * 8 + 4 + lq];

        f32x4 acc[4];
#pragma unroll
        for (int nt = 0; nt < 4; ++nt) acc[nt] = (f32x4){0.f, 0.f, 0.f, 0.f};
#pragma unroll
        for (int nt = 0; nt < 4; ++nt) {
            acc[nt] = __builtin_amdgcn_mfma_f32_16x16x32_bf16(a0, bw[0][nt], acc[nt], 0, 0, 0);
            acc[nt] = __builtin_amdgcn_mfma_f32_16x16x32_bf16(a1, bw[1][nt], acc[nt], 0, 0, 0);
        }
#pragma unroll
        for (int nt = 0; nt < 4; ++nt) {
            const int oc = nt * 16 + lx;
            const int inner = mt * 16 + lq * 4;
            const unsigned short* yp = yb + (size_t)oc * 256 + inner;
            u16x4 lh4 = *(const u16x4*)yp;
            u16x4 hl4 = *(const u16x4*)(yp + (size_t)64 * 256);
            u16x4 hh4 = *(const u16x4*)(yp + (size_t)128 * 256);
            float e0[8], e1[8];
#pragma unroll
            for (int r = 0; r < 4; ++r) {
                float s  = acc[nt][r];
                float LH = bfu(lh4[r]), HL = bfu(hl4[r]), HHv = bfu(hh4[r]);
                e0[2 * r]     = (s - LH - HL + HHv) * 0.5f;
                e0[2 * r + 1] = (s - LH + HL - HHv) * 0.5f;
                e1[2 * r]     = (s + LH - HL - HHv) * 0.5f;
                e1[2 * r + 1] = (s + LH + HL + HHv) * 0.5f;
            }
            float* o0 = out + ((size_t)(b * 64 + oc) * HF + 2 * y) * WF + 2 * (x0 + lq * 4);
            *(float4*)o0            = *(float4*)&e0[0];
            *(float4*)(o0 + 4)      = *(float4*)&e0[4];
            *(float4*)(o0 + WF)     = *(float4*)&e1[0];
            *(float4*)(o0 + WF + 4) = *(float4*)&e1[4];
        }
    }
}

extern "C" void kernel_launch(void* const* d_in, const int* in_sizes, int n_in,
                              void* d_out, int out_size, void* d_ws, size_t ws_size,
                              hipStream_t stream) {
    const float* x      = (const float*)d_in[0];
    const float* w_hc1  = (const float*)d_in[1];
    const float* w_hc2  = (const float*)d_in[2];
    const float* w_ho   = (const float*)d_in[3];
    const float* w_qkv  = (const float*)d_in[4];
    const float* w_dw   = (const float*)d_in[5];
    const float* w_proj = (const float*)d_in[6];
    const float* temp   = (const float*)d_in[7];
    float* out = (float*)d_out;

    char* base = (char*)d_ws;
    unsigned short* TILED = (unsigned short*)(base + 0);             // 12 padded planes
    unsigned short* LLP   = (unsigned short*)(base + 102242304ULL);  // 4 padded planes (LL)
    unsigned short* YH    = (unsigned short*)(base + 136323072ULL);  // 96 MiB bf16 tile-major
    unsigned short* T1T   = (unsigned short*)(base + 236986368ULL);  // 64 MiB bf16 tiled [..][128]
    unsigned short* FILT  = (unsigned short*)(base + 304095232ULL);  // 32 MiB bf16 [b][64][NP]
    unsigned short* VT    = (unsigned short*)(base + 337649664ULL);  // 32 MiB bf16 v tile-major
    float*          PRAW  = (float*)(base + 371204096ULL);           // 4 MiB per-tile S partials
    float*          PRAW2 = (float*)(base + 375398400ULL);           // 512 KiB sumsq partials
    float*          ATTN  = (float*)(base + 375922688ULL);
    short* WREP_HO  = (short*)(base + 375930880ULL);
    short* WREP_HC1 = (short*)(base + 376152064ULL);
    short* WREP_HC2 = (short*)(base + 376299520ULL);
    short* WREP_QKV = (short*)(base + 376315904ULL);
    short* MREP     = (short*)(base + 376340480ULL);                 // BN*4096 bf16

    // 0. merged setup: ring-zero 16 planes + all repacks (816 blocks)
    k_setup<<<816, 256, 0, stream>>>(TILED, w_ho, w_hc1, w_hc2, w_qkv,
                                     WREP_HO, WREP_HC1, WREP_HC2, WREP_QKV);
    // 1. DWT -> padded bf16 LH/HL/HH + LL
    k_dwt<<<dim3(512, BN), 256, 0, stream>>>(x, TILED, LLP);
    // 2. yh = relu(gconv3x3(LH,HL,HH; w_ho, groups=3)) -> tile-major bf16
    k_gconv3x3_mfma<0><<<dim3(256, 3, BN), 256, 0, stream>>>(TILED, (const bfx8*)WREP_HO, YH, 192);
    // 3. t1 = relu(gconv3x3(LH,HL; w_hc1, groups=2)) -> tiled-interleaved bf16
    k_gconv3x3_mfma<1><<<dim3(256, 2, BN), 256, 0, stream>>>(TILED, (const bfx8*)WREP_HC1, T1T, 128);
    // 4. filter_hv = relu(1x1(t1, w_hc2)) -> planar bf16
    k_conv1x1_mfma<128, 64, true><<<dim3(256, BN), 256, 0, stream>>>(T1T, (const bfx8*)WREP_HC2, FILT);
    // 5. qkv fused: 1x1 + dw3x3 + v-filter + per-tile attention dots -> VT, PRAW, PRAW2
    k_qkv_fused<<<dim3(256, BN), 256, 0, stream>>>(LLP, (const bfx8*)WREP_QKV, w_dw, FILT,
                                                   VT, PRAW, PRAW2);
    // 6. softmax (incl. l2norm) over per-tile partials
    k_attn_soft<<<32, 64, 0, stream>>>(PRAW, PRAW2, temp, ATTN);
    // 7. M_b = W*blockdiag(attn) -> bf16 fragments
    k_prep_attn<<<BN, 256, 0, stream>>>(ATTN, w_proj, MREP);
    // 8. fused (W*attn)*v via MFMA + IDWT -> fp32 out
    k_attnout_idwt<<<dim3(256, BN), 256, 0, stream>>>(VT, (const bfx8*)MREP, YH, out);
}